// Round 15
// baseline (126.771 us; speedup 1.0000x reference)
//
#include <hip/hip_runtime.h>
#include <hip/hip_bf16.h>
#include <math.h>

#define TSEQ 2048
#define CDIM 1024
#define NHEADS 16
#define DHEAD 64
#define BSZ 2
#define MROWS (BSZ * TSEQ)  // 4096
#define SCALE_Q 0.18033688f  // 0.125 * log2(e): softmax becomes exp2(s)

typedef __attribute__((ext_vector_type(8))) short short8;
typedef __attribute__((ext_vector_type(4))) short short4v;
typedef __attribute__((ext_vector_type(4))) float f32x4;

__device__ inline f32x4 mfma16(short8 a, short8 b, f32x4 c) {
    return __builtin_amdgcn_mfma_f32_16x16x32_bf16(a, b, c, 0, 0, 0);
}

__device__ inline short f2bf(float f) {
    __hip_bfloat16 h = __float2bfloat16(f);
    return __builtin_bit_cast(short, h);
}

// ---------------------------------------------------------------------------
// convx: f32 -> bf16 for x (4M elems).
// ---------------------------------------------------------------------------
__global__ __launch_bounds__(256) void convx_kernel(const float* __restrict__ x,
                                                    short* __restrict__ xb) {
    size_t off = (size_t)(blockIdx.x * 256 + threadIdx.x) * 8;
    float4 a = *(const float4*)(x + off);
    float4 b = *(const float4*)(x + off + 4);
    short8 h;
    h[0] = f2bf(a.x); h[1] = f2bf(a.y); h[2] = f2bf(a.z); h[3] = f2bf(a.w);
    h[4] = f2bf(b.x); h[5] = f2bf(b.y); h[6] = f2bf(b.z); h[7] = f2bf(b.w);
    *(short8*)(xb + off) = h;
}

// ---------------------------------------------------------------------------
// Fused QKV GEMM (unchanged from r14): BM=128, BN=128, BK=64, 4 waves,
// acc[4][4], T14 prefetch, XCD-swizzled (768=8*96). Q scaled by SCALE_Q.
// V transposed [B*N,D,T].
// ---------------------------------------------------------------------------
__global__ __launch_bounds__(256, 3) void gemm_qkv(
    const short* __restrict__ xb, const float* __restrict__ Wq,
    const float* __restrict__ Wk, const float* __restrict__ Wv,
    const float* __restrict__ bq, const float* __restrict__ bk,
    const float* __restrict__ bv, short* __restrict__ qws,
    short* __restrict__ kws, short* __restrict__ vtws) {
    __shared__ __attribute__((aligned(16))) short a_lds[128][72];
    __shared__ __attribute__((aligned(16))) short b_lds[128][72];

    const int tid = threadIdx.x;
    const int lane = tid & 63;
    const int wv = tid >> 6;
    const int wr = wv >> 1, wc = wv & 1;
    const int l15 = lane & 15, l4 = lane >> 4;

    const int hw = blockIdx.x + 32 * blockIdx.y;   // 0..767
    const int work = (hw & 7) * 96 + (hw >> 3);
    const int mbase = (work & 31) * 128;
    const int wy = work >> 5;                       // 0..23
    const int which = wy >> 3;
    const int nbase = (wy & 7) * 128;
    const float* Wf = which == 0 ? Wq : (which == 1 ? Wk : Wv);
    const float* bias = which == 0 ? bq : (which == 1 ? bk : bv);

    f32x4 acc[4][4];
#pragma unroll
    for (int i = 0; i < 4; ++i)
#pragma unroll
        for (int j = 0; j < 4; ++j) acc[i][j] = f32x4{0.f, 0.f, 0.f, 0.f};

    const int ar = tid >> 3;          // 0..31 (+32*it)
    const int ag = (tid & 7) * 8;
    const int br = tid >> 4;          // 0..15 (+16*it)
    const int bg = (tid & 15) * 4;
    const short* aptr = xb + (size_t)(mbase + ar) * CDIM + ag;
    const float* bptr = Wf + (size_t)(nbase + br) * CDIM + bg;

    short8 apre[4];
    float4 bpre[8];
#pragma unroll
    for (int it = 0; it < 4; ++it)
        apre[it] = *(const short8*)(aptr + (size_t)(32 * it) * CDIM);
#pragma unroll
    for (int it = 0; it < 8; ++it)
        bpre[it] = *(const float4*)(bptr + (size_t)(16 * it) * CDIM);

    for (int k0 = 0; k0 < CDIM; k0 += 64) {
        __syncthreads();
#pragma unroll
        for (int it = 0; it < 4; ++it)
            *(short8*)&a_lds[ar + 32 * it][ag] = apre[it];
#pragma unroll
        for (int it = 0; it < 8; ++it) {
            short4v h;
            h.x = f2bf(bpre[it].x); h.y = f2bf(bpre[it].y);
            h.z = f2bf(bpre[it].z); h.w = f2bf(bpre[it].w);
            *(short4v*)&b_lds[br + 16 * it][bg] = h;
        }
        __syncthreads();
        if (k0 + 64 < CDIM) {
#pragma unroll
            for (int it = 0; it < 4; ++it)
                apre[it] = *(const short8*)(aptr + (size_t)(32 * it) * CDIM + k0 + 64);
#pragma unroll
            for (int it = 0; it < 8; ++it)
                bpre[it] = *(const float4*)(bptr + (size_t)(16 * it) * CDIM + k0 + 64);
        }

#pragma unroll
        for (int kk = 0; kk < 2; ++kk) {
            short8 af[4], bfr[4];
#pragma unroll
            for (int i = 0; i < 4; ++i)
                af[i] = *(const short8*)&a_lds[wr * 64 + i * 16 + l15][kk * 32 + l4 * 8];
#pragma unroll
            for (int j = 0; j < 4; ++j)
                bfr[j] = *(const short8*)&b_lds[wc * 64 + j * 16 + l15][kk * 32 + l4 * 8];
#pragma unroll
            for (int i = 0; i < 4; ++i)
#pragma unroll
                for (int j = 0; j < 4; ++j)
                    acc[i][j] = mfma16(af[i], bfr[j], acc[i][j]);
        }
    }

    if (which < 2) {
        short* dst = which == 0 ? qws : kws;
        const float scale = which == 0 ? SCALE_Q : 1.0f;
#pragma unroll
        for (int i = 0; i < 4; ++i) {
            int mrow = mbase + wr * 64 + i * 16 + l4 * 4;
#pragma unroll
            for (int j = 0; j < 4; ++j) {
                int o = nbase + wc * 64 + j * 16 + l15;
                int n = o >> 6, d = o & 63;
                float bval = bias[o];
#pragma unroll
                for (int r = 0; r < 4; ++r) {
                    int mm = mrow + r;
                    int bb = mm >> 11;
                    int t = mm & (TSEQ - 1);
                    dst[(((size_t)bb * NHEADS + n) * TSEQ + t) * DHEAD + d] =
                        f2bf((acc[i][j][r] + bval) * scale);
                }
            }
        }
    } else {
#pragma unroll
        for (int i = 0; i < 4; ++i) {
            int mrow = mbase + wr * 64 + i * 16 + l4 * 4;
            int bb = mrow >> 11;
            int t = mrow & (TSEQ - 1);
#pragma unroll
            for (int j = 0; j < 4; ++j) {
                int o = nbase + wc * 64 + j * 16 + l15;
                int n = o >> 6, d = o & 63;
                float bval = bias[o];
                short4v h4;
#pragma unroll
                for (int r = 0; r < 4; ++r) h4[r] = f2bf(acc[i][j][r] + bval);
                *(short4v*)&vtws[(((size_t)bb * NHEADS + n) * DHEAD + d) * TSEQ + t] = h4;
            }
        }
    }
}

// ---------------------------------------------------------------------------
// Output projection GEMM (unchanged from r14): BM=64, BN=128, BK=32,
// T14 prefetch, XCD-swizzled (512=8*64).
// ---------------------------------------------------------------------------
__global__ __launch_bounds__(256) void gemm_p(
    const short* __restrict__ attn, const float* __restrict__ Wp,
    const float* __restrict__ bp, float* __restrict__ out) {
    __shared__ __attribute__((aligned(16))) short a_lds[64][40];
    __shared__ __attribute__((aligned(16))) short b_lds[128][40];

    const int tid = threadIdx.x;
    const int lane = tid & 63;
    const int wv = tid >> 6;
    const int wr = wv >> 1, wc = wv & 1;
    const int l15 = lane & 15, l4 = lane >> 4;

    const int hw = blockIdx.x + 64 * blockIdx.y;   // 0..511
    const int work = (hw & 7) * 64 + (hw >> 3);
    const int mbase = (work & 63) * 64;
    const int nbase = (work >> 6) * 128;

    f32x4 acc[2][4];
#pragma unroll
    for (int i = 0; i < 2; ++i)
#pragma unroll
        for (int j = 0; j < 4; ++j) acc[i][j] = f32x4{0.f, 0.f, 0.f, 0.f};

    const int arow = tid >> 2;
    const int acol = (tid & 3) * 8;
    const int brow = tid >> 3;
    const int bcol = (tid & 7) * 4;
    const short* aptr = attn + (size_t)(mbase + arow) * CDIM + acol;
    const float* bptr = Wp + (size_t)(nbase + brow) * CDIM + bcol;

    short8 apre;
    float4 bpre[4];
    apre = *(const short8*)(aptr);
#pragma unroll
    for (int it = 0; it < 4; ++it)
        bpre[it] = *(const float4*)(bptr + (size_t)(it * 32) * CDIM);

    for (int k0 = 0; k0 < CDIM; k0 += 32) {
        __syncthreads();
        *(short8*)&a_lds[arow][acol] = apre;
#pragma unroll
        for (int it = 0; it < 4; ++it) {
            short4v h;
            h.x = f2bf(bpre[it].x); h.y = f2bf(bpre[it].y);
            h.z = f2bf(bpre[it].z); h.w = f2bf(bpre[it].w);
            *(short4v*)&b_lds[brow + it * 32][bcol] = h;
        }
        __syncthreads();
        if (k0 + 32 < CDIM) {
            apre = *(const short8*)(aptr + k0 + 32);
#pragma unroll
            for (int it = 0; it < 4; ++it)
                bpre[it] = *(const float4*)(bptr + (size_t)(it * 32) * CDIM + k0 + 32);
        }

        short8 af[2], bfr[4];
#pragma unroll
        for (int i = 0; i < 2; ++i)
            af[i] = *(const short8*)&a_lds[wr * 32 + i * 16 + l15][l4 * 8];
#pragma unroll
        for (int j = 0; j < 4; ++j)
            bfr[j] = *(const short8*)&b_lds[wc * 64 + j * 16 + l15][l4 * 8];
#pragma unroll
        for (int i = 0; i < 2; ++i)
#pragma unroll
            for (int j = 0; j < 4; ++j)
                acc[i][j] = mfma16(af[i], bfr[j], acc[i][j]);
    }

#pragma unroll
    for (int i = 0; i < 2; ++i) {
        int mrow = mbase + wr * 32 + i * 16 + l4 * 4;
#pragma unroll
        for (int j = 0; j < 4; ++j) {
            int o = nbase + wc * 64 + j * 16 + l15;
            float bval = bp[o];
#pragma unroll
            for (int r = 0; r < 4; ++r)
                out[(size_t)(mrow + r) * CDIM + o] = acc[i][j][r] + bval;
        }
    }
}

// ---------------------------------------------------------------------------
// Flash attention v4: QBLK=128 (4 waves x 32 q-rows), KVBLK=64. Halves
// staging volume & barriers per output row vs QBLK=64. No-max softmax via
// native exp2 (q pre-scaled), truncated bf16 P (l from truncated bits),
// deferred l-reduction, K/V reg-prefetch into XOR-swizzled LDS.
// q,k [B*N,T,D]; vt [B*N,D,T]. Grid (head, reversed qtile).
// ---------------------------------------------------------------------------
__global__ __launch_bounds__(256) void attn_kernel(
    const short* __restrict__ q, const short* __restrict__ k,
    const short* __restrict__ vt, short* __restrict__ attn_out) {
    __shared__ __attribute__((aligned(16))) short k_lds[64][64];
    __shared__ __attribute__((aligned(16))) short vt_lds[64][64];
    __shared__ __attribute__((aligned(16))) short p_lds[4][32][80];

    const int tid = threadIdx.x;
    const int w = tid >> 6;
    const int lane = tid & 63;
    const int l15 = lane & 15;
    const int l4 = lane >> 4;
    const int h = blockIdx.x;
    const int qtile = gridDim.y - 1 - blockIdx.y;   // heaviest first
    const int qb = qtile * 128;
    const int wrow0 = qb + w * 32;

    short8 qf[2][2];
#pragma unroll
    for (int rt = 0; rt < 2; ++rt)
#pragma unroll
        for (int kh = 0; kh < 2; ++kh)
            qf[rt][kh] = *(const short8*)(q + ((size_t)h * TSEQ + wrow0 + rt * 16 + l15) * DHEAD +
                                          kh * 32 + l4 * 8);

    float l_run[2][4];
    f32x4 o_acc[2][4];
#pragma unroll
    for (int rt = 0; rt < 2; ++rt)
#pragma unroll
        for (int r = 0; r < 4; ++r) l_run[rt][r] = 0.f;
#pragma unroll
    for (int rt = 0; rt < 2; ++rt)
#pragma unroll
        for (int dt = 0; dt < 4; ++dt) o_acc[rt][dt] = f32x4{0.f, 0.f, 0.f, 0.f};

    const int ntiles = 2 * qtile + 2;
    const int srow = tid >> 3;
    const int sgrp = tid & 7;

    short8 kpre[2], vpre[2];
#pragma unroll
    for (int it = 0; it < 2; ++it) {
        int row = srow + it * 32;
        kpre[it] = *(const short8*)(k + ((size_t)h * TSEQ + row) * DHEAD + sgrp * 8);
        vpre[it] = *(const short8*)(vt + ((size_t)h * DHEAD + row) * TSEQ + sgrp * 8);
    }

    for (int kvt = 0; kvt < ntiles; ++kvt) {
        const int kvbase = kvt * 64;
        __syncthreads();
#pragma unroll
        for (int it = 0; it < 2; ++it) {
            int row = srow + it * 32;
            int gs = sgrp ^ (row & 7);
            *(short8*)&k_lds[row][gs * 8] = kpre[it];
            *(short8*)&vt_lds[row][gs * 8] = vpre[it];
        }
        __syncthreads();
        if (kvt + 1 < ntiles) {
            int kvb2 = kvbase + 64;
#pragma unroll
            for (int it = 0; it < 2; ++it) {
                int row = srow + it * 32;
                kpre[it] = *(const short8*)(k + ((size_t)h * TSEQ + kvb2 + row) * DHEAD + sgrp * 8);
                vpre[it] = *(const short8*)(vt + ((size_t)h * DHEAD + row) * TSEQ + kvb2 + sgrp * 8);
            }
        }
        if (kvbase > wrow0 + 31) continue;  // fully masked for this wave

        // S = Q K^T  (32 q-rows x 64 kv per wave)
        f32x4 s[2][4];
#pragma unroll
        for (int jt = 0; jt < 4; ++jt) {
            int row = jt * 16 + l15;
            int sw = row & 7;
            short8 kf0 = *(const short8*)&k_lds[row][(l4 ^ sw) * 8];
            short8 kf1 = *(const short8*)&k_lds[row][((4 + l4) ^ sw) * 8];
#pragma unroll
            for (int rt = 0; rt < 2; ++rt) {
                f32x4 a = f32x4{0.f, 0.f, 0.f, 0.f};
                a = mfma16(qf[rt][0], kf0, a);
                a = mfma16(qf[rt][1], kf1, a);
                s[rt][jt] = a;
            }
        }

        // softmax: p = native exp2(s); truncated bf16 store; l from truncated
        const bool needmask = (kvbase + 63 > wrow0);
#pragma unroll
        for (int rt = 0; rt < 2; ++rt) {
#pragma unroll
            for (int r = 0; r < 4; ++r) {
                int qrow = wrow0 + rt * 16 + l4 * 4 + r;
                float lp = 0.f;
#pragma unroll
                for (int jt = 0; jt < 4; ++jt) {
                    float x = s[rt][jt][r];
                    if (needmask && (kvbase + jt * 16 + l15 > qrow)) x = -INFINITY;
                    float e = __builtin_amdgcn_exp2f(x);
                    unsigned int eb = __builtin_bit_cast(unsigned int, e);
                    p_lds[w][rt * 16 + l4 * 4 + r][jt * 16 + l15] = (short)(eb >> 16);
                    lp += __builtin_bit_cast(float, eb & 0xffff0000u);
                }
                l_run[rt][r] += lp;
            }
        }

        // O += P @ V
        short8 pa[2][2];
#pragma unroll
        for (int rt = 0; rt < 2; ++rt) {
            pa[rt][0] = *(const short8*)&p_lds[w][rt * 16 + l15][l4 * 8];
            pa[rt][1] = *(const short8*)&p_lds[w][rt * 16 + l15][32 + l4 * 8];
        }
#pragma unroll
        for (int dt = 0; dt < 4; ++dt) {
            int row = dt * 16 + l15;
            int sw = row & 7;
            short8 vf0 = *(const short8*)&vt_lds[row][(l4 ^ sw) * 8];
            short8 vf1 = *(const short8*)&vt_lds[row][((4 + l4) ^ sw) * 8];
#pragma unroll
            for (int rt = 0; rt < 2; ++rt) {
                o_acc[rt][dt] = mfma16(pa[rt][0], vf0, o_acc[rt][dt]);
                o_acc[rt][dt] = mfma16(pa[rt][1], vf1, o_acc[rt][dt]);
            }
        }
    }

    // epilogue: one l-reduction, then divide and store
    const int b = h >> 4, n = h & 15;
#pragma unroll
    for (int rt = 0; rt < 2; ++rt) {
#pragma unroll
        for (int r = 0; r < 4; ++r) {
            float l = l_run[rt][r];
#pragma unroll
            for (int mk = 1; mk < 16; mk <<= 1) l += __shfl_xor(l, mk);
            l_run[rt][r] = 1.0f / l;
        }
#pragma unroll
        for (int dt = 0; dt < 4; ++dt) {
#pragma unroll
            for (int r = 0; r < 4; ++r) {
                int t = wrow0 + rt * 16 + l4 * 4 + r;
                attn_out[((size_t)b * TSEQ + t) * CDIM + n * DHEAD + dt * 16 + l15] =
                    f2bf(o_acc[rt][dt][r] * l_run[rt][r]);
            }
        }
    }
}

extern "C" void kernel_launch(void* const* d_in, const int* in_sizes, int n_in,
                              void* d_out, int out_size, void* d_ws, size_t ws_size,
                              hipStream_t stream) {
    const float* x  = (const float*)d_in[0];
    const float* Wq = (const float*)d_in[1];
    const float* bq = (const float*)d_in[2];
    const float* Wk = (const float*)d_in[3];
    const float* bk = (const float*)d_in[4];
    const float* Wv = (const float*)d_in[5];
    const float* bv = (const float*)d_in[6];
    const float* Wp = (const float*)d_in[7];
    const float* bp = (const float*)d_in[8];

    char* ws = (char*)d_ws;
    const size_t SZ = (size_t)MROWS * CDIM * sizeof(short);  // 8 MB
    short* qws  = (short*)(ws);             // slot 0
    short* kws  = (short*)(ws + SZ);        // slot 1
    short* vtws = (short*)(ws + 2 * SZ);    // slot 2
    short* xb   = (short*)(ws + 3 * SZ);    // slot 3; reused for attn out
    short* attn = xb;                        // alias: xb dead after QKV GEMM

    convx_kernel<<<2048, 256, 0, stream>>>(x, xb);
    gemm_qkv<<<dim3(MROWS / 128, 24), 256, 0, stream>>>(xb, Wq, Wk, Wv, bq, bk, bv,
                                                         qws, kws, vtws);
    attn_kernel<<<dim3(BSZ * NHEADS, TSEQ / 128), 256, 0, stream>>>(qws, kws, vtws, attn);
    gemm_p<<<dim3(MROWS / 64, CDIM / 128), 256, 0, stream>>>(attn, Wp, bp, (float*)d_out);
}

// Round 16
// 122.436 us; speedup vs baseline: 1.0354x; 1.0354x over previous
//
#include <hip/hip_runtime.h>
#include <hip/hip_bf16.h>
#include <math.h>

#define TSEQ 2048
#define CDIM 1024
#define NHEADS 16
#define DHEAD 64
#define BSZ 2
#define MROWS (BSZ * TSEQ)  // 4096
#define SCALE_Q 0.18033688f  // 0.125 * log2(e): softmax becomes exp2(s)

typedef __attribute__((ext_vector_type(8))) short short8;
typedef __attribute__((ext_vector_type(4))) short short4v;
typedef __attribute__((ext_vector_type(4))) float f32x4;

__device__ inline f32x4 mfma16(short8 a, short8 b, f32x4 c) {
    return __builtin_amdgcn_mfma_f32_16x16x32_bf16(a, b, c, 0, 0, 0);
}

__device__ inline short f2bf(float f) {
    __hip_bfloat16 h = __float2bfloat16(f);
    return __builtin_bit_cast(short, h);
}

// ---------------------------------------------------------------------------
// convx: f32 -> bf16 for x (4M elems).
// ---------------------------------------------------------------------------
__global__ __launch_bounds__(256) void convx_kernel(const float* __restrict__ x,
                                                    short* __restrict__ xb) {
    size_t off = (size_t)(blockIdx.x * 256 + threadIdx.x) * 8;
    float4 a = *(const float4*)(x + off);
    float4 b = *(const float4*)(x + off + 4);
    short8 h;
    h[0] = f2bf(a.x); h[1] = f2bf(a.y); h[2] = f2bf(a.z); h[3] = f2bf(a.w);
    h[4] = f2bf(b.x); h[5] = f2bf(b.y); h[6] = f2bf(b.z); h[7] = f2bf(b.w);
    *(short8*)(xb + off) = h;
}

// ---------------------------------------------------------------------------
// Fused QKV GEMM v2: BM=128, BN=128, BK=64, 4 waves, acc[4][4],
// DOUBLE-BUFFERED LDS (one barrier per K-step; tile t+1 loads hide under
// tile t compute), T14 reg-prefetch, XCD-swizzled (768=8*96).
// Q scaled by SCALE_Q. V transposed [B*N,D,T].
// ---------------------------------------------------------------------------
__global__ __launch_bounds__(256, 2) void gemm_qkv(
    const short* __restrict__ xb, const float* __restrict__ Wq,
    const float* __restrict__ Wk, const float* __restrict__ Wv,
    const float* __restrict__ bq, const float* __restrict__ bk,
    const float* __restrict__ bv, short* __restrict__ qws,
    short* __restrict__ kws, short* __restrict__ vtws) {
    __shared__ __attribute__((aligned(16))) short a_lds[2][128][72];
    __shared__ __attribute__((aligned(16))) short b_lds[2][128][72];

    const int tid = threadIdx.x;
    const int lane = tid & 63;
    const int wv = tid >> 6;
    const int wr = wv >> 1, wc = wv & 1;
    const int l15 = lane & 15, l4 = lane >> 4;

    const int hw = blockIdx.x + 32 * blockIdx.y;   // 0..767
    const int work = (hw & 7) * 96 + (hw >> 3);
    const int mbase = (work & 31) * 128;
    const int wy = work >> 5;                       // 0..23
    const int which = wy >> 3;
    const int nbase = (wy & 7) * 128;
    const float* Wf = which == 0 ? Wq : (which == 1 ? Wk : Wv);
    const float* bias = which == 0 ? bq : (which == 1 ? bk : bv);

    f32x4 acc[4][4];
#pragma unroll
    for (int i = 0; i < 4; ++i)
#pragma unroll
        for (int j = 0; j < 4; ++j) acc[i][j] = f32x4{0.f, 0.f, 0.f, 0.f};

    const int ar = tid >> 3;          // 0..31 (+32*it)
    const int ag = (tid & 7) * 8;
    const int br = tid >> 4;          // 0..15 (+16*it)
    const int bg = (tid & 15) * 4;
    const short* aptr = xb + (size_t)(mbase + ar) * CDIM + ag;
    const float* bptr = Wf + (size_t)(nbase + br) * CDIM + bg;

    short8 apre[4];
    float4 bpre[8];
    // prologue: tile 0 -> regs -> buf 0
#pragma unroll
    for (int it = 0; it < 4; ++it)
        apre[it] = *(const short8*)(aptr + (size_t)(32 * it) * CDIM);
#pragma unroll
    for (int it = 0; it < 8; ++it)
        bpre[it] = *(const float4*)(bptr + (size_t)(16 * it) * CDIM);
#pragma unroll
    for (int it = 0; it < 4; ++it)
        *(short8*)&a_lds[0][ar + 32 * it][ag] = apre[it];
#pragma unroll
    for (int it = 0; it < 8; ++it) {
        short4v h;
        h.x = f2bf(bpre[it].x); h.y = f2bf(bpre[it].y);
        h.z = f2bf(bpre[it].z); h.w = f2bf(bpre[it].w);
        *(short4v*)&b_lds[0][br + 16 * it][bg] = h;
    }
    __syncthreads();

    int cur = 0;
    for (int k0 = 0; k0 < CDIM; k0 += 64) {
        const bool more = (k0 + 64 < CDIM);
        if (more) {  // issue next-tile loads; latency hides under compute
#pragma unroll
            for (int it = 0; it < 4; ++it)
                apre[it] = *(const short8*)(aptr + (size_t)(32 * it) * CDIM + k0 + 64);
#pragma unroll
            for (int it = 0; it < 8; ++it)
                bpre[it] = *(const float4*)(bptr + (size_t)(16 * it) * CDIM + k0 + 64);
        }

#pragma unroll
        for (int kk = 0; kk < 2; ++kk) {
            short8 af[4], bfr[4];
#pragma unroll
            for (int i = 0; i < 4; ++i)
                af[i] = *(const short8*)&a_lds[cur][wr * 64 + i * 16 + l15][kk * 32 + l4 * 8];
#pragma unroll
            for (int j = 0; j < 4; ++j)
                bfr[j] = *(const short8*)&b_lds[cur][wc * 64 + j * 16 + l15][kk * 32 + l4 * 8];
#pragma unroll
            for (int i = 0; i < 4; ++i)
#pragma unroll
                for (int j = 0; j < 4; ++j)
                    acc[i][j] = mfma16(af[i], bfr[j], acc[i][j]);
        }

        if (more) {  // write next tile to alternate buffer; single barrier
#pragma unroll
            for (int it = 0; it < 4; ++it)
                *(short8*)&a_lds[cur ^ 1][ar + 32 * it][ag] = apre[it];
#pragma unroll
            for (int it = 0; it < 8; ++it) {
                short4v h;
                h.x = f2bf(bpre[it].x); h.y = f2bf(bpre[it].y);
                h.z = f2bf(bpre[it].z); h.w = f2bf(bpre[it].w);
                *(short4v*)&b_lds[cur ^ 1][br + 16 * it][bg] = h;
            }
            __syncthreads();
            cur ^= 1;
        }
    }

    if (which < 2) {
        short* dst = which == 0 ? qws : kws;
        const float scale = which == 0 ? SCALE_Q : 1.0f;
#pragma unroll
        for (int i = 0; i < 4; ++i) {
            int mrow = mbase + wr * 64 + i * 16 + l4 * 4;
#pragma unroll
            for (int j = 0; j < 4; ++j) {
                int o = nbase + wc * 64 + j * 16 + l15;
                int n = o >> 6, d = o & 63;
                float bval = bias[o];
#pragma unroll
                for (int r = 0; r < 4; ++r) {
                    int mm = mrow + r;
                    int bb = mm >> 11;
                    int t = mm & (TSEQ - 1);
                    dst[(((size_t)bb * NHEADS + n) * TSEQ + t) * DHEAD + d] =
                        f2bf((acc[i][j][r] + bval) * scale);
                }
            }
        }
    } else {
#pragma unroll
        for (int i = 0; i < 4; ++i) {
            int mrow = mbase + wr * 64 + i * 16 + l4 * 4;
            int bb = mrow >> 11;
            int t = mrow & (TSEQ - 1);
#pragma unroll
            for (int j = 0; j < 4; ++j) {
                int o = nbase + wc * 64 + j * 16 + l15;
                int n = o >> 6, d = o & 63;
                float bval = bias[o];
                short4v h4;
#pragma unroll
                for (int r = 0; r < 4; ++r) h4[r] = f2bf(acc[i][j][r] + bval);
                *(short4v*)&vtws[(((size_t)bb * NHEADS + n) * DHEAD + d) * TSEQ + t] = h4;
            }
        }
    }
}

// ---------------------------------------------------------------------------
// Output projection GEMM (unchanged): BM=64, BN=128, BK=32, T14 prefetch,
// XCD-swizzled (512=8*64).
// ---------------------------------------------------------------------------
__global__ __launch_bounds__(256) void gemm_p(
    const short* __restrict__ attn, const float* __restrict__ Wp,
    const float* __restrict__ bp, float* __restrict__ out) {
    __shared__ __attribute__((aligned(16))) short a_lds[64][40];
    __shared__ __attribute__((aligned(16))) short b_lds[128][40];

    const int tid = threadIdx.x;
    const int lane = tid & 63;
    const int wv = tid >> 6;
    const int wr = wv >> 1, wc = wv & 1;
    const int l15 = lane & 15, l4 = lane >> 4;

    const int hw = blockIdx.x + 64 * blockIdx.y;   // 0..511
    const int work = (hw & 7) * 64 + (hw >> 3);
    const int mbase = (work & 63) * 64;
    const int nbase = (work >> 6) * 128;

    f32x4 acc[2][4];
#pragma unroll
    for (int i = 0; i < 2; ++i)
#pragma unroll
        for (int j = 0; j < 4; ++j) acc[i][j] = f32x4{0.f, 0.f, 0.f, 0.f};

    const int arow = tid >> 2;
    const int acol = (tid & 3) * 8;
    const int brow = tid >> 3;
    const int bcol = (tid & 7) * 4;
    const short* aptr = attn + (size_t)(mbase + arow) * CDIM + acol;
    const float* bptr = Wp + (size_t)(nbase + brow) * CDIM + bcol;

    short8 apre;
    float4 bpre[4];
    apre = *(const short8*)(aptr);
#pragma unroll
    for (int it = 0; it < 4; ++it)
        bpre[it] = *(const float4*)(bptr + (size_t)(it * 32) * CDIM);

    for (int k0 = 0; k0 < CDIM; k0 += 32) {
        __syncthreads();
        *(short8*)&a_lds[arow][acol] = apre;
#pragma unroll
        for (int it = 0; it < 4; ++it) {
            short4v h;
            h.x = f2bf(bpre[it].x); h.y = f2bf(bpre[it].y);
            h.z = f2bf(bpre[it].z); h.w = f2bf(bpre[it].w);
            *(short4v*)&b_lds[brow + it * 32][bcol] = h;
        }
        __syncthreads();
        if (k0 + 32 < CDIM) {
            apre = *(const short8*)(aptr + k0 + 32);
#pragma unroll
            for (int it = 0; it < 4; ++it)
                bpre[it] = *(const float4*)(bptr + (size_t)(it * 32) * CDIM + k0 + 32);
        }

        short8 af[2], bfr[4];
#pragma unroll
        for (int i = 0; i < 2; ++i)
            af[i] = *(const short8*)&a_lds[wr * 32 + i * 16 + l15][l4 * 8];
#pragma unroll
        for (int j = 0; j < 4; ++j)
            bfr[j] = *(const short8*)&b_lds[wc * 64 + j * 16 + l15][l4 * 8];
#pragma unroll
        for (int i = 0; i < 2; ++i)
#pragma unroll
            for (int j = 0; j < 4; ++j)
                acc[i][j] = mfma16(af[i], bfr[j], acc[i][j]);
    }

#pragma unroll
    for (int i = 0; i < 2; ++i) {
        int mrow = mbase + wr * 32 + i * 16 + l4 * 4;
#pragma unroll
        for (int j = 0; j < 4; ++j) {
            int o = nbase + wc * 64 + j * 16 + l15;
            float bval = bp[o];
#pragma unroll
            for (int r = 0; r < 4; ++r)
                out[(size_t)(mrow + r) * CDIM + o] = acc[i][j][r] + bval;
        }
    }
}

// ---------------------------------------------------------------------------
// Flash attention (reverted to r14-passing version): causal, QBLK=64
// (4 waves x 16 q-rows), KVBLK=64, no-max softmax via native exp2
// (q pre-scaled by 0.125*log2e), truncated bf16 P (l from truncated bits),
// deferred l-reduction, K/V reg-prefetch into XOR-swizzled LDS.
// q,k [B*N,T,D]; vt [B*N,D,T].
// ---------------------------------------------------------------------------
__global__ __launch_bounds__(256) void attn_kernel(
    const short* __restrict__ q, const short* __restrict__ k,
    const short* __restrict__ vt, short* __restrict__ attn_out) {
    __shared__ __attribute__((aligned(16))) short k_lds[64][64];
    __shared__ __attribute__((aligned(16))) short vt_lds[64][64];
    __shared__ __attribute__((aligned(16))) short p_lds[4][16][80];

    const int tid = threadIdx.x;
    const int w = tid >> 6;
    const int lane = tid & 63;
    const int l15 = lane & 15;
    const int l4 = lane >> 4;
    const int h = blockIdx.x;
    const int qtile = gridDim.y - 1 - blockIdx.y;
    const int qb = qtile * 64;
    const int wrow0 = qb + w * 16;

    short8 qf[2];
#pragma unroll
    for (int kh = 0; kh < 2; ++kh)
        qf[kh] = *(const short8*)(q + ((size_t)h * TSEQ + wrow0 + l15) * DHEAD +
                                  kh * 32 + l4 * 8);

    float l_run[4];
    f32x4 o_acc[4];
#pragma unroll
    for (int r = 0; r < 4; ++r) l_run[r] = 0.f;
#pragma unroll
    for (int dt = 0; dt < 4; ++dt) o_acc[dt] = f32x4{0.f, 0.f, 0.f, 0.f};

    const int ntiles = qtile + 1;
    const int srow = tid >> 3;
    const int sgrp = tid & 7;

    short8 kpre[2], vpre[2];
#pragma unroll
    for (int it = 0; it < 2; ++it) {
        int row = srow + it * 32;
        kpre[it] = *(const short8*)(k + ((size_t)h * TSEQ + row) * DHEAD + sgrp * 8);
        vpre[it] = *(const short8*)(vt + ((size_t)h * DHEAD + row) * TSEQ + sgrp * 8);
    }

    for (int kvt = 0; kvt < ntiles; ++kvt) {
        const int kvbase = kvt * 64;
        __syncthreads();
#pragma unroll
        for (int it = 0; it < 2; ++it) {
            int row = srow + it * 32;
            int gs = sgrp ^ (row & 7);
            *(short8*)&k_lds[row][gs * 8] = kpre[it];
            *(short8*)&vt_lds[row][gs * 8] = vpre[it];
        }
        __syncthreads();
        if (kvt + 1 < ntiles) {
            int kvb2 = kvbase + 64;
#pragma unroll
            for (int it = 0; it < 2; ++it) {
                int row = srow + it * 32;
                kpre[it] = *(const short8*)(k + ((size_t)h * TSEQ + kvb2 + row) * DHEAD + sgrp * 8);
                vpre[it] = *(const short8*)(vt + ((size_t)h * DHEAD + row) * TSEQ + kvb2 + sgrp * 8);
            }
        }

        f32x4 s[4];
#pragma unroll
        for (int jt = 0; jt < 4; ++jt) {
            int row = jt * 16 + l15;
            int sw = row & 7;
            short8 kf0 = *(const short8*)&k_lds[row][(l4 ^ sw) * 8];
            short8 kf1 = *(const short8*)&k_lds[row][((4 + l4) ^ sw) * 8];
            f32x4 a = f32x4{0.f, 0.f, 0.f, 0.f};
            a = mfma16(qf[0], kf0, a);
            a = mfma16(qf[1], kf1, a);
            s[jt] = a;
        }

        // softmax: p = native exp2(s); truncated bf16 store; l from truncated
        const bool needmask = (kvbase + 63 > wrow0);
#pragma unroll
        for (int r = 0; r < 4; ++r) {
            int qrow = wrow0 + l4 * 4 + r;
            float lp = 0.f;
#pragma unroll
            for (int jt = 0; jt < 4; ++jt) {
                float x = s[jt][r];
                if (needmask && (kvbase + jt * 16 + l15 > qrow)) x = -INFINITY;
                float e = __builtin_amdgcn_exp2f(x);
                unsigned int eb = __builtin_bit_cast(unsigned int, e);
                p_lds[w][l4 * 4 + r][jt * 16 + l15] = (short)(eb >> 16);
                lp += __builtin_bit_cast(float, eb & 0xffff0000u);
            }
            l_run[r] += lp;
        }

        short8 pa0 = *(const short8*)&p_lds[w][l15][l4 * 8];
        short8 pa1 = *(const short8*)&p_lds[w][l15][32 + l4 * 8];
#pragma unroll
        for (int dt = 0; dt < 4; ++dt) {
            int row = dt * 16 + l15;
            int sw = row & 7;
            short8 vf0 = *(const short8*)&vt_lds[row][(l4 ^ sw) * 8];
            short8 vf1 = *(const short8*)&vt_lds[row][((4 + l4) ^ sw) * 8];
            o_acc[dt] = mfma16(pa0, vf0, o_acc[dt]);
            o_acc[dt] = mfma16(pa1, vf1, o_acc[dt]);
        }
    }

#pragma unroll
    for (int r = 0; r < 4; ++r) {
        float l = l_run[r];
#pragma unroll
        for (int mk = 1; mk < 16; mk <<= 1) l += __shfl_xor(l, mk);
        l_run[r] = 1.0f / l;
    }
    const int b = h >> 4, n = h & 15;
#pragma unroll
    for (int dt = 0; dt < 4; ++dt) {
#pragma unroll
        for (int r = 0; r < 4; ++r) {
            int t = wrow0 + l4 * 4 + r;
            attn_out[((size_t)b * TSEQ + t) * CDIM + n * DHEAD + dt * 16 + l15] =
                f2bf(o_acc[dt][r] * l_run[r]);
        }
    }
}

extern "C" void kernel_launch(void* const* d_in, const int* in_sizes, int n_in,
                              void* d_out, int out_size, void* d_ws, size_t ws_size,
                              hipStream_t stream) {
    const float* x  = (const float*)d_in[0];
    const float* Wq = (const float*)d_in[1];
    const float* bq = (const float*)d_in[2];
    const float* Wk = (const float*)d_in[3];
    const float* bk = (const float*)d_in[4];
    const float* Wv = (const float*)d_in[5];
    const float* bv = (const float*)d_in[6];
    const float* Wp = (const float*)d_in[7];
    const float* bp = (const float*)d_in[8];

    char* ws = (char*)d_ws;
    const size_t SZ = (size_t)MROWS * CDIM * sizeof(short);  // 8 MB
    short* qws  = (short*)(ws);             // slot 0
    short* kws  = (short*)(ws + SZ);        // slot 1
    short* vtws = (short*)(ws + 2 * SZ);    // slot 2
    short* xb   = (short*)(ws + 3 * SZ);    // slot 3; reused for attn out
    short* attn = xb;                        // alias: xb dead after QKV GEMM

    convx_kernel<<<2048, 256, 0, stream>>>(x, xb);
    gemm_qkv<<<dim3(MROWS / 128, 24), 256, 0, stream>>>(xb, Wq, Wk, Wv, bq, bk, bv,
                                                         qws, kws, vtws);
    attn_kernel<<<dim3(BSZ * NHEADS, TSEQ / 64), 256, 0, stream>>>(qws, kws, vtws, attn);
    gemm_p<<<dim3(MROWS / 64, CDIM / 128), 256, 0, stream>>>(attn, Wp, bp, (float*)d_out);
}

// Round 17
// 117.318 us; speedup vs baseline: 1.0806x; 1.0436x over previous
//
#include <hip/hip_runtime.h>
#include <hip/hip_bf16.h>
#include <math.h>

#define TSEQ 2048
#define CDIM 1024
#define NHEADS 16
#define DHEAD 64
#define BSZ 2
#define MROWS (BSZ * TSEQ)  // 4096
#define SCALE_Q 0.18033688f  // 0.125 * log2(e): softmax becomes exp2(s)

typedef __attribute__((ext_vector_type(8))) short short8;
typedef __attribute__((ext_vector_type(4))) short short4v;
typedef __attribute__((ext_vector_type(4))) float f32x4;

__device__ inline f32x4 mfma16(short8 a, short8 b, f32x4 c) {
    return __builtin_amdgcn_mfma_f32_16x16x32_bf16(a, b, c, 0, 0, 0);
}

__device__ inline short f2bf(float f) {
    __hip_bfloat16 h = __float2bfloat16(f);
    return __builtin_bit_cast(short, h);
}

// ---------------------------------------------------------------------------
// convx: f32 -> bf16 for x (4M elems).
// ---------------------------------------------------------------------------
__global__ __launch_bounds__(256) void convx_kernel(const float* __restrict__ x,
                                                    short* __restrict__ xb) {
    size_t off = (size_t)(blockIdx.x * 256 + threadIdx.x) * 8;
    float4 a = *(const float4*)(x + off);
    float4 b = *(const float4*)(x + off + 4);
    short8 h;
    h[0] = f2bf(a.x); h[1] = f2bf(a.y); h[2] = f2bf(a.z); h[3] = f2bf(a.w);
    h[4] = f2bf(b.x); h[5] = f2bf(b.y); h[6] = f2bf(b.z); h[7] = f2bf(b.w);
    *(short8*)(xb + off) = h;
}

// ---------------------------------------------------------------------------
// Fused QKV GEMM (r12-proven structure): BM=128, BN=128, BK=64, 4 waves,
// acc[4][4], SINGLE-buffer LDS, T14 reg-prefetch, no XCD swizzle.
// Q epilogue scaled by SCALE_Q (0.125*log2e) so attn uses exp2 directly.
// V transposed [B*N,D,T].
// ---------------------------------------------------------------------------
__global__ __launch_bounds__(256, 3) void gemm_qkv(
    const short* __restrict__ xb, const float* __restrict__ Wq,
    const float* __restrict__ Wk, const float* __restrict__ Wv,
    const float* __restrict__ bq, const float* __restrict__ bk,
    const float* __restrict__ bv, short* __restrict__ qws,
    short* __restrict__ kws, short* __restrict__ vtws) {
    __shared__ __attribute__((aligned(16))) short a_lds[128][72];
    __shared__ __attribute__((aligned(16))) short b_lds[128][72];

    const int tid = threadIdx.x;
    const int lane = tid & 63;
    const int wv = tid >> 6;
    const int wr = wv >> 1, wc = wv & 1;
    const int l15 = lane & 15, l4 = lane >> 4;
    const int mbase = blockIdx.x * 128;
    const int which = blockIdx.y >> 3;
    const int nbase = (blockIdx.y & 7) * 128;
    const float* Wf = which == 0 ? Wq : (which == 1 ? Wk : Wv);
    const float* bias = which == 0 ? bq : (which == 1 ? bk : bv);

    f32x4 acc[4][4];
#pragma unroll
    for (int i = 0; i < 4; ++i)
#pragma unroll
        for (int j = 0; j < 4; ++j) acc[i][j] = f32x4{0.f, 0.f, 0.f, 0.f};

    const int ar = tid >> 3;          // 0..31 (+32*it)
    const int ag = (tid & 7) * 8;
    const int br = tid >> 4;          // 0..15 (+16*it)
    const int bg = (tid & 15) * 4;
    const short* aptr = xb + (size_t)(mbase + ar) * CDIM + ag;
    const float* bptr = Wf + (size_t)(nbase + br) * CDIM + bg;

    short8 apre[4];
    float4 bpre[8];
#pragma unroll
    for (int it = 0; it < 4; ++it)
        apre[it] = *(const short8*)(aptr + (size_t)(32 * it) * CDIM);
#pragma unroll
    for (int it = 0; it < 8; ++it)
        bpre[it] = *(const float4*)(bptr + (size_t)(16 * it) * CDIM);

    for (int k0 = 0; k0 < CDIM; k0 += 64) {
        __syncthreads();  // prev iteration's ds_reads done
#pragma unroll
        for (int it = 0; it < 4; ++it)
            *(short8*)&a_lds[ar + 32 * it][ag] = apre[it];
#pragma unroll
        for (int it = 0; it < 8; ++it) {
            short4v h;
            h.x = f2bf(bpre[it].x); h.y = f2bf(bpre[it].y);
            h.z = f2bf(bpre[it].z); h.w = f2bf(bpre[it].w);
            *(short4v*)&b_lds[br + 16 * it][bg] = h;
        }
        __syncthreads();  // tile visible
        if (k0 + 64 < CDIM) {
#pragma unroll
            for (int it = 0; it < 4; ++it)
                apre[it] = *(const short8*)(aptr + (size_t)(32 * it) * CDIM + k0 + 64);
#pragma unroll
            for (int it = 0; it < 8; ++it)
                bpre[it] = *(const float4*)(bptr + (size_t)(16 * it) * CDIM + k0 + 64);
        }

#pragma unroll
        for (int kk = 0; kk < 2; ++kk) {
            short8 af[4], bfr[4];
#pragma unroll
            for (int i = 0; i < 4; ++i)
                af[i] = *(const short8*)&a_lds[wr * 64 + i * 16 + l15][kk * 32 + l4 * 8];
#pragma unroll
            for (int j = 0; j < 4; ++j)
                bfr[j] = *(const short8*)&b_lds[wc * 64 + j * 16 + l15][kk * 32 + l4 * 8];
#pragma unroll
            for (int i = 0; i < 4; ++i)
#pragma unroll
                for (int j = 0; j < 4; ++j)
                    acc[i][j] = mfma16(af[i], bfr[j], acc[i][j]);
        }
    }

    if (which < 2) {
        short* dst = which == 0 ? qws : kws;
        const float scale = which == 0 ? SCALE_Q : 1.0f;
#pragma unroll
        for (int i = 0; i < 4; ++i) {
            int mrow = mbase + wr * 64 + i * 16 + l4 * 4;
#pragma unroll
            for (int j = 0; j < 4; ++j) {
                int o = nbase + wc * 64 + j * 16 + l15;
                int n = o >> 6, d = o & 63;
                float bval = bias[o];
#pragma unroll
                for (int r = 0; r < 4; ++r) {
                    int mm = mrow + r;
                    int bb = mm >> 11;
                    int t = mm & (TSEQ - 1);
                    dst[(((size_t)bb * NHEADS + n) * TSEQ + t) * DHEAD + d] =
                        f2bf((acc[i][j][r] + bval) * scale);
                }
            }
        }
    } else {
#pragma unroll
        for (int i = 0; i < 4; ++i) {
            int mrow = mbase + wr * 64 + i * 16 + l4 * 4;
            int bb = mrow >> 11;
            int t = mrow & (TSEQ - 1);
#pragma unroll
            for (int j = 0; j < 4; ++j) {
                int o = nbase + wc * 64 + j * 16 + l15;
                int n = o >> 6, d = o & 63;
                float bval = bias[o];
                short4v h4;
#pragma unroll
                for (int r = 0; r < 4; ++r) h4[r] = f2bf(acc[i][j][r] + bval);
                *(short4v*)&vtws[(((size_t)bb * NHEADS + n) * DHEAD + d) * TSEQ + t] = h4;
            }
        }
    }
}

// ---------------------------------------------------------------------------
// Output projection GEMM (r12-proven): BM=64, BN=128, BK=32, T14 prefetch,
// no XCD swizzle.
// ---------------------------------------------------------------------------
__global__ __launch_bounds__(256) void gemm_p(
    const short* __restrict__ attn, const float* __restrict__ Wp,
    const float* __restrict__ bp, float* __restrict__ out) {
    __shared__ __attribute__((aligned(16))) short a_lds[64][40];
    __shared__ __attribute__((aligned(16))) short b_lds[128][40];

    const int tid = threadIdx.x;
    const int lane = tid & 63;
    const int wv = tid >> 6;
    const int wr = wv >> 1, wc = wv & 1;
    const int l15 = lane & 15, l4 = lane >> 4;
    const int mbase = blockIdx.x * 64;
    const int nbase = blockIdx.y * 128;

    f32x4 acc[2][4];
#pragma unroll
    for (int i = 0; i < 2; ++i)
#pragma unroll
        for (int j = 0; j < 4; ++j) acc[i][j] = f32x4{0.f, 0.f, 0.f, 0.f};

    const int arow = tid >> 2;
    const int acol = (tid & 3) * 8;
    const int brow = tid >> 3;
    const int bcol = (tid & 7) * 4;
    const short* aptr = attn + (size_t)(mbase + arow) * CDIM + acol;
    const float* bptr = Wp + (size_t)(nbase + brow) * CDIM + bcol;

    short8 apre;
    float4 bpre[4];
    apre = *(const short8*)(aptr);
#pragma unroll
    for (int it = 0; it < 4; ++it)
        bpre[it] = *(const float4*)(bptr + (size_t)(it * 32) * CDIM);

    for (int k0 = 0; k0 < CDIM; k0 += 32) {
        __syncthreads();
        *(short8*)&a_lds[arow][acol] = apre;
#pragma unroll
        for (int it = 0; it < 4; ++it) {
            short4v h;
            h.x = f2bf(bpre[it].x); h.y = f2bf(bpre[it].y);
            h.z = f2bf(bpre[it].z); h.w = f2bf(bpre[it].w);
            *(short4v*)&b_lds[brow + it * 32][bcol] = h;
        }
        __syncthreads();
        if (k0 + 32 < CDIM) {
            apre = *(const short8*)(aptr + k0 + 32);
#pragma unroll
            for (int it = 0; it < 4; ++it)
                bpre[it] = *(const float4*)(bptr + (size_t)(it * 32) * CDIM + k0 + 32);
        }

        short8 af[2], bfr[4];
#pragma unroll
        for (int i = 0; i < 2; ++i)
            af[i] = *(const short8*)&a_lds[wr * 32 + i * 16 + l15][l4 * 8];
#pragma unroll
        for (int j = 0; j < 4; ++j)
            bfr[j] = *(const short8*)&b_lds[wc * 64 + j * 16 + l15][l4 * 8];
#pragma unroll
        for (int i = 0; i < 2; ++i)
#pragma unroll
            for (int j = 0; j < 4; ++j)
                acc[i][j] = mfma16(af[i], bfr[j], acc[i][j]);
    }

#pragma unroll
    for (int i = 0; i < 2; ++i) {
        int mrow = mbase + wr * 32 + i * 16 + l4 * 4;
#pragma unroll
        for (int j = 0; j < 4; ++j) {
            int o = nbase + wc * 64 + j * 16 + l15;
            float bval = bp[o];
#pragma unroll
            for (int r = 0; r < 4; ++r)
                out[(size_t)(mrow + r) * CDIM + o] = acc[i][j][r] + bval;
        }
    }
}

// ---------------------------------------------------------------------------
// Flash attention (r12-proven structure, minimal softmax): causal, QBLK=64
// (4 waves x 16 q-rows), KVBLK=64, no-max softmax via native exp2
// (q pre-scaled by 0.125*log2e in gemm_qkv; no clamp needed), RNE bf16 P
// with l accumulated from full-precision e (r12-validated), deferred
// l-reduction, K/V reg-prefetch into XOR-swizzled LDS.
// q,k [B*N,T,D]; vt [B*N,D,T].
// ---------------------------------------------------------------------------
__global__ __launch_bounds__(256) void attn_kernel(
    const short* __restrict__ q, const short* __restrict__ k,
    const short* __restrict__ vt, short* __restrict__ attn_out) {
    __shared__ __attribute__((aligned(16))) short k_lds[64][64];
    __shared__ __attribute__((aligned(16))) short vt_lds[64][64];
    __shared__ __attribute__((aligned(16))) short p_lds[4][16][80];

    const int tid = threadIdx.x;
    const int w = tid >> 6;
    const int lane = tid & 63;
    const int l15 = lane & 15;
    const int l4 = lane >> 4;
    const int h = blockIdx.x;
    const int qtile = gridDim.y - 1 - blockIdx.y;
    const int qb = qtile * 64;
    const int wrow0 = qb + w * 16;

    short8 qf[2];
#pragma unroll
    for (int kh = 0; kh < 2; ++kh)
        qf[kh] = *(const short8*)(q + ((size_t)h * TSEQ + wrow0 + l15) * DHEAD +
                                  kh * 32 + l4 * 8);

    float l_run[4];
    f32x4 o_acc[4];
#pragma unroll
    for (int r = 0; r < 4; ++r) l_run[r] = 0.f;
#pragma unroll
    for (int dt = 0; dt < 4; ++dt) o_acc[dt] = f32x4{0.f, 0.f, 0.f, 0.f};

    const int ntiles = qtile + 1;
    const int srow = tid >> 3;
    const int sgrp = tid & 7;

    short8 kpre[2], vpre[2];
#pragma unroll
    for (int it = 0; it < 2; ++it) {
        int row = srow + it * 32;
        kpre[it] = *(const short8*)(k + ((size_t)h * TSEQ + row) * DHEAD + sgrp * 8);
        vpre[it] = *(const short8*)(vt + ((size_t)h * DHEAD + row) * TSEQ + sgrp * 8);
    }

    for (int kvt = 0; kvt < ntiles; ++kvt) {
        const int kvbase = kvt * 64;
        __syncthreads();
#pragma unroll
        for (int it = 0; it < 2; ++it) {
            int row = srow + it * 32;
            int gs = sgrp ^ (row & 7);
            *(short8*)&k_lds[row][gs * 8] = kpre[it];
            *(short8*)&vt_lds[row][gs * 8] = vpre[it];
        }
        __syncthreads();
        if (kvt + 1 < ntiles) {
            int kvb2 = kvbase + 64;
#pragma unroll
            for (int it = 0; it < 2; ++it) {
                int row = srow + it * 32;
                kpre[it] = *(const short8*)(k + ((size_t)h * TSEQ + kvb2 + row) * DHEAD + sgrp * 8);
                vpre[it] = *(const short8*)(vt + ((size_t)h * DHEAD + row) * TSEQ + kvb2 + sgrp * 8);
            }
        }

        f32x4 s[4];
#pragma unroll
        for (int jt = 0; jt < 4; ++jt) {
            int row = jt * 16 + l15;
            int sw = row & 7;
            short8 kf0 = *(const short8*)&k_lds[row][(l4 ^ sw) * 8];
            short8 kf1 = *(const short8*)&k_lds[row][((4 + l4) ^ sw) * 8];
            f32x4 a = f32x4{0.f, 0.f, 0.f, 0.f};
            a = mfma16(qf[0], kf0, a);
            a = mfma16(qf[1], kf1, a);
            s[jt] = a;
        }

        // softmax: p = native exp2(s); RNE bf16 store; l from full-prec e
        const bool needmask = (kvbase + 63 > wrow0);
#pragma unroll
        for (int r = 0; r < 4; ++r) {
            int qrow = wrow0 + l4 * 4 + r;
            float lp = 0.f;
#pragma unroll
            for (int jt = 0; jt < 4; ++jt) {
                float x = s[jt][r];
                if (needmask && (kvbase + jt * 16 + l15 > qrow)) x = -INFINITY;
                float e = __builtin_amdgcn_exp2f(x);
                lp += e;
                p_lds[w][l4 * 4 + r][jt * 16 + l15] = f2bf(e);
            }
            l_run[r] += lp;
        }

        short8 pa0 = *(const short8*)&p_lds[w][l15][l4 * 8];
        short8 pa1 = *(const short8*)&p_lds[w][l15][32 + l4 * 8];
#pragma unroll
        for (int dt = 0; dt < 4; ++dt) {
            int row = dt * 16 + l15;
            int sw = row & 7;
            short8 vf0 = *(const short8*)&vt_lds[row][(l4 ^ sw) * 8];
            short8 vf1 = *(const short8*)&vt_lds[row][((4 + l4) ^ sw) * 8];
            o_acc[dt] = mfma16(pa0, vf0, o_acc[dt]);
            o_acc[dt] = mfma16(pa1, vf1, o_acc[dt]);
        }
    }

#pragma unroll
    for (int r = 0; r < 4; ++r) {
        float l = l_run[r];
#pragma unroll
        for (int mk = 1; mk < 16; mk <<= 1) l += __shfl_xor(l, mk);
        l_run[r] = 1.0f / l;
    }
    const int b = h >> 4, n = h & 15;
#pragma unroll
    for (int dt = 0; dt < 4; ++dt) {
#pragma unroll
        for (int r = 0; r < 4; ++r) {
            int t = wrow0 + l4 * 4 + r;
            attn_out[((size_t)b * TSEQ + t) * CDIM + n * DHEAD + dt * 16 + l15] =
                f2bf(o_acc[dt][r] * l_run[r]);
        }
    }
}

extern "C" void kernel_launch(void* const* d_in, const int* in_sizes, int n_in,
                              void* d_out, int out_size, void* d_ws, size_t ws_size,
                              hipStream_t stream) {
    const float* x  = (const float*)d_in[0];
    const float* Wq = (const float*)d_in[1];
    const float* bq = (const float*)d_in[2];
    const float* Wk = (const float*)d_in[3];
    const float* bk = (const float*)d_in[4];
    const float* Wv = (const float*)d_in[5];
    const float* bv = (const float*)d_in[6];
    const float* Wp = (const float*)d_in[7];
    const float* bp = (const float*)d_in[8];

    char* ws = (char*)d_ws;
    const size_t SZ = (size_t)MROWS * CDIM * sizeof(short);  // 8 MB
    short* qws  = (short*)(ws);             // slot 0
    short* kws  = (short*)(ws + SZ);        // slot 1
    short* vtws = (short*)(ws + 2 * SZ);    // slot 2
    short* xb   = (short*)(ws + 3 * SZ);    // slot 3; reused for attn out
    short* attn = xb;                        // alias: xb dead after QKV GEMM

    convx_kernel<<<2048, 256, 0, stream>>>(x, xb);
    gemm_qkv<<<dim3(MROWS / 128, 24), 256, 0, stream>>>(xb, Wq, Wk, Wv, bq, bk, bv,
                                                         qws, kws, vtws);
    attn_kernel<<<dim3(BSZ * NHEADS, TSEQ / 64), 256, 0, stream>>>(qws, kws, vtws, attn);
    gemm_p<<<dim3(MROWS / 64, CDIM / 128), 256, 0, stream>>>(attn, Wp, bp, (float*)d_out);
}

// Round 18
// 112.919 us; speedup vs baseline: 1.1227x; 1.0390x over previous
//
#include <hip/hip_runtime.h>
#include <hip/hip_bf16.h>
#include <math.h>

#define TSEQ 2048
#define CDIM 1024
#define NHEADS 16
#define DHEAD 64
#define BSZ 2
#define MROWS (BSZ * TSEQ)  // 4096
#define SCALE_Q 0.18033688f  // 0.125 * log2(e): softmax becomes exp2(s)

typedef __attribute__((ext_vector_type(8))) short short8;
typedef __attribute__((ext_vector_type(4))) short short4v;
typedef __attribute__((ext_vector_type(4))) float f32x4;

__device__ inline f32x4 mfma16(short8 a, short8 b, f32x4 c) {
    return __builtin_amdgcn_mfma_f32_16x16x32_bf16(a, b, c, 0, 0, 0);
}

__device__ inline short f2bf(float f) {
    __hip_bfloat16 h = __float2bfloat16(f);
    return __builtin_bit_cast(short, h);
}

// ---------------------------------------------------------------------------
// conv f32 -> bf16, 8 elems/thread (used for x with 2048 blocks, Wp with 512).
// ---------------------------------------------------------------------------
__global__ __launch_bounds__(256) void convx_kernel(const float* __restrict__ x,
                                                    short* __restrict__ xb) {
    size_t off = (size_t)(blockIdx.x * 256 + threadIdx.x) * 8;
    float4 a = *(const float4*)(x + off);
    float4 b = *(const float4*)(x + off + 4);
    short8 h;
    h[0] = f2bf(a.x); h[1] = f2bf(a.y); h[2] = f2bf(a.z); h[3] = f2bf(a.w);
    h[4] = f2bf(b.x); h[5] = f2bf(b.y); h[6] = f2bf(b.z); h[7] = f2bf(b.w);
    *(short8*)(xb + off) = h;
}

// ---------------------------------------------------------------------------
// Fused QKV GEMM (r12-proven structure, frozen): BM=128, BN=128, BK=64,
// 4 waves, acc[4][4], single-buffer LDS, T14 reg-prefetch.
// Q epilogue scaled by SCALE_Q. V transposed [B*N,D,T].
// ---------------------------------------------------------------------------
__global__ __launch_bounds__(256, 3) void gemm_qkv(
    const short* __restrict__ xb, const float* __restrict__ Wq,
    const float* __restrict__ Wk, const float* __restrict__ Wv,
    const float* __restrict__ bq, const float* __restrict__ bk,
    const float* __restrict__ bv, short* __restrict__ qws,
    short* __restrict__ kws, short* __restrict__ vtws) {
    __shared__ __attribute__((aligned(16))) short a_lds[128][72];
    __shared__ __attribute__((aligned(16))) short b_lds[128][72];

    const int tid = threadIdx.x;
    const int lane = tid & 63;
    const int wv = tid >> 6;
    const int wr = wv >> 1, wc = wv & 1;
    const int l15 = lane & 15, l4 = lane >> 4;
    const int mbase = blockIdx.x * 128;
    const int which = blockIdx.y >> 3;
    const int nbase = (blockIdx.y & 7) * 128;
    const float* Wf = which == 0 ? Wq : (which == 1 ? Wk : Wv);
    const float* bias = which == 0 ? bq : (which == 1 ? bk : bv);

    f32x4 acc[4][4];
#pragma unroll
    for (int i = 0; i < 4; ++i)
#pragma unroll
        for (int j = 0; j < 4; ++j) acc[i][j] = f32x4{0.f, 0.f, 0.f, 0.f};

    const int ar = tid >> 3;
    const int ag = (tid & 7) * 8;
    const int br = tid >> 4;
    const int bg = (tid & 15) * 4;
    const short* aptr = xb + (size_t)(mbase + ar) * CDIM + ag;
    const float* bptr = Wf + (size_t)(nbase + br) * CDIM + bg;

    short8 apre[4];
    float4 bpre[8];
#pragma unroll
    for (int it = 0; it < 4; ++it)
        apre[it] = *(const short8*)(aptr + (size_t)(32 * it) * CDIM);
#pragma unroll
    for (int it = 0; it < 8; ++it)
        bpre[it] = *(const float4*)(bptr + (size_t)(16 * it) * CDIM);

    for (int k0 = 0; k0 < CDIM; k0 += 64) {
        __syncthreads();
#pragma unroll
        for (int it = 0; it < 4; ++it)
            *(short8*)&a_lds[ar + 32 * it][ag] = apre[it];
#pragma unroll
        for (int it = 0; it < 8; ++it) {
            short4v h;
            h.x = f2bf(bpre[it].x); h.y = f2bf(bpre[it].y);
            h.z = f2bf(bpre[it].z); h.w = f2bf(bpre[it].w);
            *(short4v*)&b_lds[br + 16 * it][bg] = h;
        }
        __syncthreads();
        if (k0 + 64 < CDIM) {
#pragma unroll
            for (int it = 0; it < 4; ++it)
                apre[it] = *(const short8*)(aptr + (size_t)(32 * it) * CDIM + k0 + 64);
#pragma unroll
            for (int it = 0; it < 8; ++it)
                bpre[it] = *(const float4*)(bptr + (size_t)(16 * it) * CDIM + k0 + 64);
        }

#pragma unroll
        for (int kk = 0; kk < 2; ++kk) {
            short8 af[4], bfr[4];
#pragma unroll
            for (int i = 0; i < 4; ++i)
                af[i] = *(const short8*)&a_lds[wr * 64 + i * 16 + l15][kk * 32 + l4 * 8];
#pragma unroll
            for (int j = 0; j < 4; ++j)
                bfr[j] = *(const short8*)&b_lds[wc * 64 + j * 16 + l15][kk * 32 + l4 * 8];
#pragma unroll
            for (int i = 0; i < 4; ++i)
#pragma unroll
                for (int j = 0; j < 4; ++j)
                    acc[i][j] = mfma16(af[i], bfr[j], acc[i][j]);
        }
    }

    if (which < 2) {
        short* dst = which == 0 ? qws : kws;
        const float scale = which == 0 ? SCALE_Q : 1.0f;
#pragma unroll
        for (int i = 0; i < 4; ++i) {
            int mrow = mbase + wr * 64 + i * 16 + l4 * 4;
#pragma unroll
            for (int j = 0; j < 4; ++j) {
                int o = nbase + wc * 64 + j * 16 + l15;
                int n = o >> 6, d = o & 63;
                float bval = bias[o];
#pragma unroll
                for (int r = 0; r < 4; ++r) {
                    int mm = mrow + r;
                    int bb = mm >> 11;
                    int t = mm & (TSEQ - 1);
                    dst[(((size_t)bb * NHEADS + n) * TSEQ + t) * DHEAD + d] =
                        f2bf((acc[i][j][r] + bval) * scale);
                }
            }
        }
    } else {
#pragma unroll
        for (int i = 0; i < 4; ++i) {
            int mrow = mbase + wr * 64 + i * 16 + l4 * 4;
            int bb = mrow >> 11;
            int t = mrow & (TSEQ - 1);
#pragma unroll
            for (int j = 0; j < 4; ++j) {
                int o = nbase + wc * 64 + j * 16 + l15;
                int n = o >> 6, d = o & 63;
                float bval = bias[o];
                short4v h4;
#pragma unroll
                for (int r = 0; r < 4; ++r) h4[r] = f2bf(acc[i][j][r] + bval);
                *(short4v*)&vtws[(((size_t)bb * NHEADS + n) * DHEAD + d) * TSEQ + t] = h4;
            }
        }
    }
}

// ---------------------------------------------------------------------------
// Output projection GEMM: BM=64, BN=128, BK=32, T14 prefetch.
// B = PRE-CONVERTED bf16 Wp (wpb): pure short8 staging, no in-loop cvt.
// ---------------------------------------------------------------------------
__global__ __launch_bounds__(256) void gemm_p(
    const short* __restrict__ attn, const short* __restrict__ wpb,
    const float* __restrict__ bp, float* __restrict__ out) {
    __shared__ __attribute__((aligned(16))) short a_lds[64][40];
    __shared__ __attribute__((aligned(16))) short b_lds[128][40];

    const int tid = threadIdx.x;
    const int lane = tid & 63;
    const int wv = tid >> 6;
    const int wr = wv >> 1, wc = wv & 1;
    const int l15 = lane & 15, l4 = lane >> 4;
    const int mbase = blockIdx.x * 64;
    const int nbase = blockIdx.y * 128;

    f32x4 acc[2][4];
#pragma unroll
    for (int i = 0; i < 2; ++i)
#pragma unroll
        for (int j = 0; j < 4; ++j) acc[i][j] = f32x4{0.f, 0.f, 0.f, 0.f};

    const int arow = tid >> 2;        // 0..63
    const int acol = (tid & 3) * 8;
    const short* aptr = attn + (size_t)(mbase + arow) * CDIM + acol;
    const short* bptr = wpb + (size_t)(nbase + arow) * CDIM + acol;  // rows 0..63 (+64)

    short8 apre, bpre[2];
    apre = *(const short8*)(aptr);
    bpre[0] = *(const short8*)(bptr);
    bpre[1] = *(const short8*)(bptr + (size_t)64 * CDIM);

    for (int k0 = 0; k0 < CDIM; k0 += 32) {
        __syncthreads();
        *(short8*)&a_lds[arow][acol] = apre;
        *(short8*)&b_lds[arow][acol] = bpre[0];
        *(short8*)&b_lds[arow + 64][acol] = bpre[1];
        __syncthreads();
        if (k0 + 32 < CDIM) {
            apre = *(const short8*)(aptr + k0 + 32);
            bpre[0] = *(const short8*)(bptr + k0 + 32);
            bpre[1] = *(const short8*)(bptr + (size_t)64 * CDIM + k0 + 32);
        }

        short8 af[2], bfr[4];
#pragma unroll
        for (int i = 0; i < 2; ++i)
            af[i] = *(const short8*)&a_lds[wr * 32 + i * 16 + l15][l4 * 8];
#pragma unroll
        for (int j = 0; j < 4; ++j)
            bfr[j] = *(const short8*)&b_lds[wc * 64 + j * 16 + l15][l4 * 8];
#pragma unroll
        for (int i = 0; i < 2; ++i)
#pragma unroll
            for (int j = 0; j < 4; ++j)
                acc[i][j] = mfma16(af[i], bfr[j], acc[i][j]);
    }

#pragma unroll
    for (int i = 0; i < 2; ++i) {
        int mrow = mbase + wr * 32 + i * 16 + l4 * 4;
#pragma unroll
        for (int j = 0; j < 4; ++j) {
            int o = nbase + wc * 64 + j * 16 + l15;
            float bval = bp[o];
#pragma unroll
            for (int r = 0; r < 4; ++r)
                out[(size_t)(mrow + r) * CDIM + o] = acc[i][j][r] + bval;
        }
    }
}

// ---------------------------------------------------------------------------
// Flash attention v5: QBLK=64 (4 waves x 16 q-rows), KVBLK=128 (half the
// barriers/stages per kv-col vs KVBLK=64). No-max softmax via native exp2
// (q pre-scaled), deferred l-reduction, K/V reg-prefetch into XOR-swizzled
// LDS (K: grp^=row&7 on [128][64]; V^T: grp^=row&15 on [64][128]).
// q,k [B*N,T,D]; vt [B*N,D,T]. Grid (head, reversed qtile64).
// ---------------------------------------------------------------------------
__global__ __launch_bounds__(256) void attn_kernel(
    const short* __restrict__ q, const short* __restrict__ k,
    const short* __restrict__ vt, short* __restrict__ attn_out) {
    __shared__ __attribute__((aligned(16))) short k_lds[128][64];
    __shared__ __attribute__((aligned(16))) short vt_lds[64][128];
    __shared__ __attribute__((aligned(16))) short p_lds[4][16][136];

    const int tid = threadIdx.x;
    const int w = tid >> 6;
    const int lane = tid & 63;
    const int l15 = lane & 15;
    const int l4 = lane >> 4;
    const int h = blockIdx.x;
    const int qtile = gridDim.y - 1 - blockIdx.y;   // 64-row units, heaviest first
    const int wrow0 = qtile * 64 + w * 16;

    short8 qf[2];
#pragma unroll
    for (int kh = 0; kh < 2; ++kh)
        qf[kh] = *(const short8*)(q + ((size_t)h * TSEQ + wrow0 + l15) * DHEAD +
                                  kh * 32 + l4 * 8);

    float l_run[4];
    f32x4 o_acc[4];
#pragma unroll
    for (int r = 0; r < 4; ++r) l_run[r] = 0.f;
#pragma unroll
    for (int dt = 0; dt < 4; ++dt) o_acc[dt] = f32x4{0.f, 0.f, 0.f, 0.f};

    const int ntiles = (qtile + 2) >> 1;   // 128-wide tiles covering qb+64 rows
    const size_t kbase = (size_t)h * TSEQ * DHEAD;
    const size_t vbase = (size_t)h * DHEAD * TSEQ;

    // staging decomposition
    const int ksrow = tid >> 3, ksg = tid & 7;     // K: 128 rows x 8 groups
    const int vsrow = tid >> 4, vsg = tid & 15;    // V: 64 rows x 16 groups

    short8 kpre[4], vpre[4];
#pragma unroll
    for (int it = 0; it < 4; ++it) {
        kpre[it] = *(const short8*)(k + kbase + (size_t)(ksrow + it * 32) * DHEAD + ksg * 8);
        vpre[it] = *(const short8*)(vt + vbase + (size_t)(vsrow + it * 16) * TSEQ + vsg * 8);
    }

    for (int kvt = 0; kvt < ntiles; ++kvt) {
        const int kvbase = kvt * 128;
        __syncthreads();
#pragma unroll
        for (int it = 0; it < 4; ++it) {
            int krow = ksrow + it * 32;
            *(short8*)&k_lds[krow][(ksg ^ (krow & 7)) * 8] = kpre[it];
            int vrow = vsrow + it * 16;
            *(short8*)&vt_lds[vrow][((vsg ^ (vrow & 15))) * 8] = vpre[it];
        }
        __syncthreads();
        if (kvt + 1 < ntiles) {
            int kvb2 = kvbase + 128;
#pragma unroll
            for (int it = 0; it < 4; ++it) {
                kpre[it] = *(const short8*)(k + kbase + (size_t)(kvb2 + ksrow + it * 32) * DHEAD + ksg * 8);
                vpre[it] = *(const short8*)(vt + vbase + (size_t)(vsrow + it * 16) * TSEQ + kvb2 + vsg * 8);
            }
        }

        // S = Q K^T  (16 q-rows x 128 kv per wave)
        f32x4 s[8];
#pragma unroll
        for (int jt = 0; jt < 8; ++jt) {
            int row = jt * 16 + l15;
            int sw = row & 7;
            short8 kf0 = *(const short8*)&k_lds[row][(l4 ^ sw) * 8];
            short8 kf1 = *(const short8*)&k_lds[row][((4 + l4) ^ sw) * 8];
            f32x4 a = f32x4{0.f, 0.f, 0.f, 0.f};
            a = mfma16(qf[0], kf0, a);
            a = mfma16(qf[1], kf1, a);
            s[jt] = a;
        }

        // softmax: p = native exp2(s); RNE bf16 store; l from full-prec e
        const bool needmask = (kvbase + 127 > wrow0);
#pragma unroll
        for (int r = 0; r < 4; ++r) {
            int qrow = wrow0 + l4 * 4 + r;
            float lp = 0.f;
#pragma unroll
            for (int jt = 0; jt < 8; ++jt) {
                float x = s[jt][r];
                if (needmask && (kvbase + jt * 16 + l15 > qrow)) x = -INFINITY;
                float e = __builtin_amdgcn_exp2f(x);
                lp += e;
                p_lds[w][l4 * 4 + r][jt * 16 + l15] = f2bf(e);
            }
            l_run[r] += lp;
        }

        // O += P @ V  (p_lds wave-private; K=128 -> 4 k-slots)
        short8 pa[4];
#pragma unroll
        for (int ks = 0; ks < 4; ++ks)
            pa[ks] = *(const short8*)&p_lds[w][l15][ks * 32 + l4 * 8];
#pragma unroll
        for (int dt = 0; dt < 4; ++dt) {
            int row = dt * 16 + l15;
            int sw = row & 15;
#pragma unroll
            for (int ks = 0; ks < 4; ++ks) {
                short8 vf = *(const short8*)&vt_lds[row][((ks * 4 + l4) ^ sw) * 8];
                o_acc[dt] = mfma16(pa[ks], vf, o_acc[dt]);
            }
        }
    }

#pragma unroll
    for (int r = 0; r < 4; ++r) {
        float l = l_run[r];
#pragma unroll
        for (int mk = 1; mk < 16; mk <<= 1) l += __shfl_xor(l, mk);
        l_run[r] = 1.0f / l;
    }
    const int b = h >> 4, n = h & 15;
#pragma unroll
    for (int dt = 0; dt < 4; ++dt) {
#pragma unroll
        for (int r = 0; r < 4; ++r) {
            int t = wrow0 + l4 * 4 + r;
            attn_out[((size_t)b * TSEQ + t) * CDIM + n * DHEAD + dt * 16 + l15] =
                f2bf(o_acc[dt][r] * l_run[r]);
        }
    }
}

extern "C" void kernel_launch(void* const* d_in, const int* in_sizes, int n_in,
                              void* d_out, int out_size, void* d_ws, size_t ws_size,
                              hipStream_t stream) {
    const float* x  = (const float*)d_in[0];
    const float* Wq = (const float*)d_in[1];
    const float* bq = (const float*)d_in[2];
    const float* Wk = (const float*)d_in[3];
    const float* bk = (const float*)d_in[4];
    const float* Wv = (const float*)d_in[5];
    const float* bv = (const float*)d_in[6];
    const float* Wp = (const float*)d_in[7];
    const float* bp = (const float*)d_in[8];

    char* ws = (char*)d_ws;
    const size_t SZ = (size_t)MROWS * CDIM * sizeof(short);  // 8 MB
    short* qws  = (short*)(ws);             // slot 0; reused for Wp bf16 after attn
    short* kws  = (short*)(ws + SZ);        // slot 1
    short* vtws = (short*)(ws + 2 * SZ);    // slot 2
    short* xb   = (short*)(ws + 3 * SZ);    // slot 3; reused for attn out
    short* attn = xb;                        // alias: xb dead after QKV GEMM
    short* wpb  = qws;                       // alias: qws dead after attn

    convx_kernel<<<2048, 256, 0, stream>>>(x, xb);
    gemm_qkv<<<dim3(MROWS / 128, 24), 256, 0, stream>>>(xb, Wq, Wk, Wv, bq, bk, bv,
                                                         qws, kws, vtws);
    attn_kernel<<<dim3(BSZ * NHEADS, TSEQ / 64), 256, 0, stream>>>(qws, kws, vtws, attn);
    convx_kernel<<<512, 256, 0, stream>>>(Wp, wpb);
    gemm_p<<<dim3(MROWS / 64, CDIM / 128), 256, 0, stream>>>(attn, wpb, bp, (float*)d_out);
}

// Round 19
// 112.735 us; speedup vs baseline: 1.1245x; 1.0016x over previous
//
#include <hip/hip_runtime.h>
#include <hip/hip_bf16.h>
#include <math.h>

#define TSEQ 2048
#define CDIM 1024
#define NHEADS 16
#define DHEAD 64
#define BSZ 2
#define MROWS (BSZ * TSEQ)  // 4096
#define SCALE_Q 0.18033688f  // 0.125 * log2(e): softmax becomes exp2(s)

typedef __attribute__((ext_vector_type(8))) short short8;
typedef __attribute__((ext_vector_type(4))) short short4v;
typedef __attribute__((ext_vector_type(4))) float f32x4;

__device__ inline f32x4 mfma16(short8 a, short8 b, f32x4 c) {
    return __builtin_amdgcn_mfma_f32_16x16x32_bf16(a, b, c, 0, 0, 0);
}

__device__ inline short f2bf(float f) {
    __hip_bfloat16 h = __float2bfloat16(f);
    return __builtin_bit_cast(short, h);
}

__device__ inline void gl_lds16(const short* g, short* l) {
    __builtin_amdgcn_global_load_lds(
        (const __attribute__((address_space(1))) void*)g,
        (__attribute__((address_space(3))) void*)l, 16, 0, 0);
}

// ---------------------------------------------------------------------------
// conv f32 -> bf16, 8 elems/thread.
// ---------------------------------------------------------------------------
__global__ __launch_bounds__(256) void convx_kernel(const float* __restrict__ x,
                                                    short* __restrict__ xb) {
    size_t off = (size_t)(blockIdx.x * 256 + threadIdx.x) * 8;
    float4 a = *(const float4*)(x + off);
    float4 b = *(const float4*)(x + off + 4);
    short8 h;
    h[0] = f2bf(a.x); h[1] = f2bf(a.y); h[2] = f2bf(a.z); h[3] = f2bf(a.w);
    h[4] = f2bf(b.x); h[5] = f2bf(b.y); h[6] = f2bf(b.z); h[7] = f2bf(b.w);
    *(short8*)(xb + off) = h;
}

// conv 3 weight matrices (1M elems each) -> bf16
__global__ __launch_bounds__(256) void conv3_kernel(
    const float* __restrict__ swq, const float* __restrict__ swk,
    const float* __restrict__ swv, short* __restrict__ wqb,
    short* __restrict__ wkb, short* __restrict__ wvb) {
    int chunk = blockIdx.x >> 9;               // 0..2 (512 blocks each)
    size_t off = (size_t)((blockIdx.x & 511) * 256 + threadIdx.x) * 8;
    const float* s = chunk == 0 ? swq : (chunk == 1 ? swk : swv);
    short* d = chunk == 0 ? wqb : (chunk == 1 ? wkb : wvb);
    float4 a = *(const float4*)(s + off);
    float4 b = *(const float4*)(s + off + 4);
    short8 h;
    h[0] = f2bf(a.x); h[1] = f2bf(a.y); h[2] = f2bf(a.z); h[3] = f2bf(a.w);
    h[4] = f2bf(b.x); h[5] = f2bf(b.y); h[6] = f2bf(b.z); h[7] = f2bf(b.w);
    *(short8*)(d + off) = h;
}

// ---------------------------------------------------------------------------
// Fused QKV GEMM, gl_lds path (m97 structure): BM=128, BN=128, BK=64,
// 4 waves, acc[4][4]. Both operands bf16 via global_load_lds width-16 with
// PRE-SWIZZLED per-lane global source (LDS[row][s] = elem[row][s^(row&7)]);
// ds_read at slot g^(row&7) -> <=2-way banks. LDS linear 32 KB.
// Q epilogue scaled by SCALE_Q. V transposed [B*N,D,T].
// ---------------------------------------------------------------------------
__global__ __launch_bounds__(256, 3) void gemm_qkv_g(
    const short* __restrict__ xb, const short* __restrict__ wqb,
    const short* __restrict__ wkb, const short* __restrict__ wvb,
    const float* __restrict__ bq, const float* __restrict__ bk,
    const float* __restrict__ bv, short* __restrict__ qws,
    short* __restrict__ kws, short* __restrict__ vtws) {
    __shared__ __attribute__((aligned(16))) short a_lds[128 * 64];
    __shared__ __attribute__((aligned(16))) short b_lds[128 * 64];

    const int tid = threadIdx.x;
    const int lane = tid & 63;
    const int wv = tid >> 6;
    const int wr = wv >> 1, wc = wv & 1;
    const int l15 = lane & 15, l4 = lane >> 4;
    const int mbase = blockIdx.x * 128;
    const int which = blockIdx.y >> 3;
    const int nbase = (blockIdx.y & 7) * 128;
    const short* Wb = which == 0 ? wqb : (which == 1 ? wkb : wvb);
    const float* bias = which == 0 ? bq : (which == 1 ? bk : bv);

    f32x4 acc[4][4];
#pragma unroll
    for (int i = 0; i < 4; ++i)
#pragma unroll
        for (int j = 0; j < 4; ++j) acc[i][j] = f32x4{0.f, 0.f, 0.f, 0.f};

    // staging: call it covers rows it*32..+31; thread -> (row=tid>>3, slot=tid&7)
    // source column group pre-swizzled: gcol = (tid&7) ^ ((tid>>3)&7)
    const int srow = tid >> 3;
    const int gcol = (tid & 7) ^ (srow & 7);
    const short* asrc = xb + (size_t)(mbase + srow) * CDIM + gcol * 8;
    const short* bsrc = Wb + (size_t)(nbase + srow) * CDIM + gcol * 8;
    short* adst = &a_lds[tid * 8];
    short* bdst = &b_lds[tid * 8];

    for (int k0 = 0; k0 < CDIM; k0 += 64) {
        __syncthreads();  // prev iteration's ds_reads done
#pragma unroll
        for (int it = 0; it < 4; ++it) {
            gl_lds16(asrc + (size_t)(it * 32) * CDIM + k0, adst + it * 2048);
            gl_lds16(bsrc + (size_t)(it * 32) * CDIM + k0, bdst + it * 2048);
        }
        __syncthreads();  // implicit vmcnt(0) drain: tile visible

#pragma unroll
        for (int kk = 0; kk < 2; ++kk) {
            short8 af[4], bfr[4];
#pragma unroll
            for (int i = 0; i < 4; ++i) {
                int R = wr * 64 + i * 16 + l15;
                af[i] = *(const short8*)&a_lds[R * 64 + ((kk * 4 + l4) ^ (R & 7)) * 8];
            }
#pragma unroll
            for (int j = 0; j < 4; ++j) {
                int R = wc * 64 + j * 16 + l15;
                bfr[j] = *(const short8*)&b_lds[R * 64 + ((kk * 4 + l4) ^ (R & 7)) * 8];
            }
#pragma unroll
            for (int i = 0; i < 4; ++i)
#pragma unroll
                for (int j = 0; j < 4; ++j)
                    acc[i][j] = mfma16(af[i], bfr[j], acc[i][j]);
        }
    }

    if (which < 2) {
        short* dst = which == 0 ? qws : kws;
        const float scale = which == 0 ? SCALE_Q : 1.0f;
#pragma unroll
        for (int i = 0; i < 4; ++i) {
            int mrow = mbase + wr * 64 + i * 16 + l4 * 4;
#pragma unroll
            for (int j = 0; j < 4; ++j) {
                int o = nbase + wc * 64 + j * 16 + l15;
                int n = o >> 6, d = o & 63;
                float bval = bias[o];
#pragma unroll
                for (int r = 0; r < 4; ++r) {
                    int mm = mrow + r;
                    int bb = mm >> 11;
                    int t = mm & (TSEQ - 1);
                    dst[(((size_t)bb * NHEADS + n) * TSEQ + t) * DHEAD + d] =
                        f2bf((acc[i][j][r] + bval) * scale);
                }
            }
        }
    } else {
#pragma unroll
        for (int i = 0; i < 4; ++i) {
            int mrow = mbase + wr * 64 + i * 16 + l4 * 4;
            int bb = mrow >> 11;
            int t = mrow & (TSEQ - 1);
#pragma unroll
            for (int j = 0; j < 4; ++j) {
                int o = nbase + wc * 64 + j * 16 + l15;
                int n = o >> 6, d = o & 63;
                float bval = bias[o];
                short4v h4;
#pragma unroll
                for (int r = 0; r < 4; ++r) h4[r] = f2bf(acc[i][j][r] + bval);
                *(short4v*)&vtws[(((size_t)bb * NHEADS + n) * DHEAD + d) * TSEQ + t] = h4;
            }
        }
    }
}

// ---------------------------------------------------------------------------
// Fused QKV GEMM, fallback path (r18-proven): f32 weights, reg staging.
// ---------------------------------------------------------------------------
__global__ __launch_bounds__(256, 3) void gemm_qkv(
    const short* __restrict__ xb, const float* __restrict__ Wq,
    const float* __restrict__ Wk, const float* __restrict__ Wv,
    const float* __restrict__ bq, const float* __restrict__ bk,
    const float* __restrict__ bv, short* __restrict__ qws,
    short* __restrict__ kws, short* __restrict__ vtws) {
    __shared__ __attribute__((aligned(16))) short a_lds[128][72];
    __shared__ __attribute__((aligned(16))) short b_lds[128][72];

    const int tid = threadIdx.x;
    const int lane = tid & 63;
    const int wv = tid >> 6;
    const int wr = wv >> 1, wc = wv & 1;
    const int l15 = lane & 15, l4 = lane >> 4;
    const int mbase = blockIdx.x * 128;
    const int which = blockIdx.y >> 3;
    const int nbase = (blockIdx.y & 7) * 128;
    const float* Wf = which == 0 ? Wq : (which == 1 ? Wk : Wv);
    const float* bias = which == 0 ? bq : (which == 1 ? bk : bv);

    f32x4 acc[4][4];
#pragma unroll
    for (int i = 0; i < 4; ++i)
#pragma unroll
        for (int j = 0; j < 4; ++j) acc[i][j] = f32x4{0.f, 0.f, 0.f, 0.f};

    const int ar = tid >> 3;
    const int ag = (tid & 7) * 8;
    const int br = tid >> 4;
    const int bg = (tid & 15) * 4;
    const short* aptr = xb + (size_t)(mbase + ar) * CDIM + ag;
    const float* bptr = Wf + (size_t)(nbase + br) * CDIM + bg;

    short8 apre[4];
    float4 bpre[8];
#pragma unroll
    for (int it = 0; it < 4; ++it)
        apre[it] = *(const short8*)(aptr + (size_t)(32 * it) * CDIM);
#pragma unroll
    for (int it = 0; it < 8; ++it)
        bpre[it] = *(const float4*)(bptr + (size_t)(16 * it) * CDIM);

    for (int k0 = 0; k0 < CDIM; k0 += 64) {
        __syncthreads();
#pragma unroll
        for (int it = 0; it < 4; ++it)
            *(short8*)&a_lds[ar + 32 * it][ag] = apre[it];
#pragma unroll
        for (int it = 0; it < 8; ++it) {
            short4v h;
            h.x = f2bf(bpre[it].x); h.y = f2bf(bpre[it].y);
            h.z = f2bf(bpre[it].z); h.w = f2bf(bpre[it].w);
            *(short4v*)&b_lds[br + 16 * it][bg] = h;
        }
        __syncthreads();
        if (k0 + 64 < CDIM) {
#pragma unroll
            for (int it = 0; it < 4; ++it)
                apre[it] = *(const short8*)(aptr + (size_t)(32 * it) * CDIM + k0 + 64);
#pragma unroll
            for (int it = 0; it < 8; ++it)
                bpre[it] = *(const float4*)(bptr + (size_t)(16 * it) * CDIM + k0 + 64);
        }

#pragma unroll
        for (int kk = 0; kk < 2; ++kk) {
            short8 af[4], bfr[4];
#pragma unroll
            for (int i = 0; i < 4; ++i)
                af[i] = *(const short8*)&a_lds[wr * 64 + i * 16 + l15][kk * 32 + l4 * 8];
#pragma unroll
            for (int j = 0; j < 4; ++j)
                bfr[j] = *(const short8*)&b_lds[wc * 64 + j * 16 + l15][kk * 32 + l4 * 8];
#pragma unroll
            for (int i = 0; i < 4; ++i)
#pragma unroll
                for (int j = 0; j < 4; ++j)
                    acc[i][j] = mfma16(af[i], bfr[j], acc[i][j]);
        }
    }

    if (which < 2) {
        short* dst = which == 0 ? qws : kws;
        const float scale = which == 0 ? SCALE_Q : 1.0f;
#pragma unroll
        for (int i = 0; i < 4; ++i) {
            int mrow = mbase + wr * 64 + i * 16 + l4 * 4;
#pragma unroll
            for (int j = 0; j < 4; ++j) {
                int o = nbase + wc * 64 + j * 16 + l15;
                int n = o >> 6, d = o & 63;
                float bval = bias[o];
#pragma unroll
                for (int r = 0; r < 4; ++r) {
                    int mm = mrow + r;
                    int bb = mm >> 11;
                    int t = mm & (TSEQ - 1);
                    dst[(((size_t)bb * NHEADS + n) * TSEQ + t) * DHEAD + d] =
                        f2bf((acc[i][j][r] + bval) * scale);
                }
            }
        }
    } else {
#pragma unroll
        for (int i = 0; i < 4; ++i) {
            int mrow = mbase + wr * 64 + i * 16 + l4 * 4;
            int bb = mrow >> 11;
            int t = mrow & (TSEQ - 1);
#pragma unroll
            for (int j = 0; j < 4; ++j) {
                int o = nbase + wc * 64 + j * 16 + l15;
                int n = o >> 6, d = o & 63;
                float bval = bias[o];
                short4v h4;
#pragma unroll
                for (int r = 0; r < 4; ++r) h4[r] = f2bf(acc[i][j][r] + bval);
                *(short4v*)&vtws[(((size_t)bb * NHEADS + n) * DHEAD + d) * TSEQ + t] = h4;
            }
        }
    }
}

// ---------------------------------------------------------------------------
// Output projection GEMM (r18-proven): BM=64, BN=128, BK=32, T14 prefetch,
// B = pre-converted bf16 Wp.
// ---------------------------------------------------------------------------
__global__ __launch_bounds__(256) void gemm_p(
    const short* __restrict__ attn, const short* __restrict__ wpb,
    const float* __restrict__ bp, float* __restrict__ out) {
    __shared__ __attribute__((aligned(16))) short a_lds[64][40];
    __shared__ __attribute__((aligned(16))) short b_lds[128][40];

    const int tid = threadIdx.x;
    const int lane = tid & 63;
    const int wv = tid >> 6;
    const int wr = wv >> 1, wc = wv & 1;
    const int l15 = lane & 15, l4 = lane >> 4;
    const int mbase = blockIdx.x * 64;
    const int nbase = blockIdx.y * 128;

    f32x4 acc[2][4];
#pragma unroll
    for (int i = 0; i < 2; ++i)
#pragma unroll
        for (int j = 0; j < 4; ++j) acc[i][j] = f32x4{0.f, 0.f, 0.f, 0.f};

    const int arow = tid >> 2;
    const int acol = (tid & 3) * 8;
    const short* aptr = attn + (size_t)(mbase + arow) * CDIM + acol;
    const short* bptr = wpb + (size_t)(nbase + arow) * CDIM + acol;

    short8 apre, bpre[2];
    apre = *(const short8*)(aptr);
    bpre[0] = *(const short8*)(bptr);
    bpre[1] = *(const short8*)(bptr + (size_t)64 * CDIM);

    for (int k0 = 0; k0 < CDIM; k0 += 32) {
        __syncthreads();
        *(short8*)&a_lds[arow][acol] = apre;
        *(short8*)&b_lds[arow][acol] = bpre[0];
        *(short8*)&b_lds[arow + 64][acol] = bpre[1];
        __syncthreads();
        if (k0 + 32 < CDIM) {
            apre = *(const short8*)(aptr + k0 + 32);
            bpre[0] = *(const short8*)(bptr + k0 + 32);
            bpre[1] = *(const short8*)(bptr + (size_t)64 * CDIM + k0 + 32);
        }

        short8 af[2], bfr[4];
#pragma unroll
        for (int i = 0; i < 2; ++i)
            af[i] = *(const short8*)&a_lds[wr * 32 + i * 16 + l15][l4 * 8];
#pragma unroll
        for (int j = 0; j < 4; ++j)
            bfr[j] = *(const short8*)&b_lds[wc * 64 + j * 16 + l15][l4 * 8];
#pragma unroll
        for (int i = 0; i < 2; ++i)
#pragma unroll
            for (int j = 0; j < 4; ++j)
                acc[i][j] = mfma16(af[i], bfr[j], acc[i][j]);
    }

#pragma unroll
    for (int i = 0; i < 2; ++i) {
        int mrow = mbase + wr * 32 + i * 16 + l4 * 4;
#pragma unroll
        for (int j = 0; j < 4; ++j) {
            int o = nbase + wc * 64 + j * 16 + l15;
            float bval = bp[o];
#pragma unroll
            for (int r = 0; r < 4; ++r)
                out[(size_t)(mrow + r) * CDIM + o] = acc[i][j][r] + bval;
        }
    }
}

// ---------------------------------------------------------------------------
// Flash attention (r18-proven): QBLK=64 (4 waves x 16 q-rows), KVBLK=128,
// no-max softmax via native exp2 (q pre-scaled), deferred l-reduction,
// K/V reg-prefetch into XOR-swizzled LDS (K: ^row&7; V^T: ^row&15).
// q,k [B*N,T,D]; vt [B*N,D,T].
// ---------------------------------------------------------------------------
__global__ __launch_bounds__(256) void attn_kernel(
    const short* __restrict__ q, const short* __restrict__ k,
    const short* __restrict__ vt, short* __restrict__ attn_out) {
    __shared__ __attribute__((aligned(16))) short k_lds[128][64];
    __shared__ __attribute__((aligned(16))) short vt_lds[64][128];
    __shared__ __attribute__((aligned(16))) short p_lds[4][16][136];

    const int tid = threadIdx.x;
    const int w = tid >> 6;
    const int lane = tid & 63;
    const int l15 = lane & 15;
    const int l4 = lane >> 4;
    const int h = blockIdx.x;
    const int qtile = gridDim.y - 1 - blockIdx.y;
    const int wrow0 = qtile * 64 + w * 16;

    short8 qf[2];
#pragma unroll
    for (int kh = 0; kh < 2; ++kh)
        qf[kh] = *(const short8*)(q + ((size_t)h * TSEQ + wrow0 + l15) * DHEAD +
                                  kh * 32 + l4 * 8);

    float l_run[4];
    f32x4 o_acc[4];
#pragma unroll
    for (int r = 0; r < 4; ++r) l_run[r] = 0.f;
#pragma unroll
    for (int dt = 0; dt < 4; ++dt) o_acc[dt] = f32x4{0.f, 0.f, 0.f, 0.f};

    const int ntiles = (qtile + 2) >> 1;
    const size_t kbase = (size_t)h * TSEQ * DHEAD;
    const size_t vbase = (size_t)h * DHEAD * TSEQ;

    const int ksrow = tid >> 3, ksg = tid & 7;
    const int vsrow = tid >> 4, vsg = tid & 15;

    short8 kpre[4], vpre[4];
#pragma unroll
    for (int it = 0; it < 4; ++it) {
        kpre[it] = *(const short8*)(k + kbase + (size_t)(ksrow + it * 32) * DHEAD + ksg * 8);
        vpre[it] = *(const short8*)(vt + vbase + (size_t)(vsrow + it * 16) * TSEQ + vsg * 8);
    }

    for (int kvt = 0; kvt < ntiles; ++kvt) {
        const int kvbase = kvt * 128;
        __syncthreads();
#pragma unroll
        for (int it = 0; it < 4; ++it) {
            int krow = ksrow + it * 32;
            *(short8*)&k_lds[krow][(ksg ^ (krow & 7)) * 8] = kpre[it];
            int vrow = vsrow + it * 16;
            *(short8*)&vt_lds[vrow][((vsg ^ (vrow & 15))) * 8] = vpre[it];
        }
        __syncthreads();
        if (kvt + 1 < ntiles) {
            int kvb2 = kvbase + 128;
#pragma unroll
            for (int it = 0; it < 4; ++it) {
                kpre[it] = *(const short8*)(k + kbase + (size_t)(kvb2 + ksrow + it * 32) * DHEAD + ksg * 8);
                vpre[it] = *(const short8*)(vt + vbase + (size_t)(vsrow + it * 16) * TSEQ + kvb2 + vsg * 8);
            }
        }

        f32x4 s[8];
#pragma unroll
        for (int jt = 0; jt < 8; ++jt) {
            int row = jt * 16 + l15;
            int sw = row & 7;
            short8 kf0 = *(const short8*)&k_lds[row][(l4 ^ sw) * 8];
            short8 kf1 = *(const short8*)&k_lds[row][((4 + l4) ^ sw) * 8];
            f32x4 a = f32x4{0.f, 0.f, 0.f, 0.f};
            a = mfma16(qf[0], kf0, a);
            a = mfma16(qf[1], kf1, a);
            s[jt] = a;
        }

        const bool needmask = (kvbase + 127 > wrow0);
#pragma unroll
        for (int r = 0; r < 4; ++r) {
            int qrow = wrow0 + l4 * 4 + r;
            float lp = 0.f;
#pragma unroll
            for (int jt = 0; jt < 8; ++jt) {
                float x = s[jt][r];
                if (needmask && (kvbase + jt * 16 + l15 > qrow)) x = -INFINITY;
                float e = __builtin_amdgcn_exp2f(x);
                lp += e;
                p_lds[w][l4 * 4 + r][jt * 16 + l15] = f2bf(e);
            }
            l_run[r] += lp;
        }

        short8 pa[4];
#pragma unroll
        for (int ks = 0; ks < 4; ++ks)
            pa[ks] = *(const short8*)&p_lds[w][l15][ks * 32 + l4 * 8];
#pragma unroll
        for (int dt = 0; dt < 4; ++dt) {
            int row = dt * 16 + l15;
            int sw = row & 15;
#pragma unroll
            for (int ks = 0; ks < 4; ++ks) {
                short8 vf = *(const short8*)&vt_lds[row][((ks * 4 + l4) ^ sw) * 8];
                o_acc[dt] = mfma16(pa[ks], vf, o_acc[dt]);
            }
        }
    }

#pragma unroll
    for (int r = 0; r < 4; ++r) {
        float l = l_run[r];
#pragma unroll
        for (int mk = 1; mk < 16; mk <<= 1) l += __shfl_xor(l, mk);
        l_run[r] = 1.0f / l;
    }
    const int b = h >> 4, n = h & 15;
#pragma unroll
    for (int dt = 0; dt < 4; ++dt) {
#pragma unroll
        for (int r = 0; r < 4; ++r) {
            int t = wrow0 + l4 * 4 + r;
            attn_out[((size_t)b * TSEQ + t) * CDIM + n * DHEAD + dt * 16 + l15] =
                f2bf(o_acc[dt][r] * l_run[r]);
        }
    }
}

extern "C" void kernel_launch(void* const* d_in, const int* in_sizes, int n_in,
                              void* d_out, int out_size, void* d_ws, size_t ws_size,
                              hipStream_t stream) {
    const float* x  = (const float*)d_in[0];
    const float* Wq = (const float*)d_in[1];
    const float* bq = (const float*)d_in[2];
    const float* Wk = (const float*)d_in[3];
    const float* bk = (const float*)d_in[4];
    const float* Wv = (const float*)d_in[5];
    const float* bv = (const float*)d_in[6];
    const float* Wp = (const float*)d_in[7];
    const float* bp = (const float*)d_in[8];

    char* ws = (char*)d_ws;
    const size_t SZ = (size_t)MROWS * CDIM * sizeof(short);  // 8 MB
    short* qws  = (short*)(ws);             // slot 0; reused for Wp bf16 after attn
    short* kws  = (short*)(ws + SZ);        // slot 1
    short* vtws = (short*)(ws + 2 * SZ);    // slot 2
    short* xb   = (short*)(ws + 3 * SZ);    // slot 3; reused for attn out
    short* attn = xb;                        // alias: xb dead after QKV GEMM
    short* wpb  = qws;                       // alias: qws dead after attn

    convx_kernel<<<2048, 256, 0, stream>>>(x, xb);

    const size_t WSZ = (size_t)CDIM * CDIM * sizeof(short);  // 2 MB
    if (ws_size >= 4 * SZ + 3 * WSZ) {
        // bf16 weight stash in extra workspace + gl_lds GEMM
        short* wqb = (short*)(ws + 4 * SZ);
        short* wkb = wqb + (size_t)CDIM * CDIM;
        short* wvb = wkb + (size_t)CDIM * CDIM;
        conv3_kernel<<<1536, 256, 0, stream>>>(Wq, Wk, Wv, wqb, wkb, wvb);
        gemm_qkv_g<<<dim3(MROWS / 128, 24), 256, 0, stream>>>(
            xb, wqb, wkb, wvb, bq, bk, bv, qws, kws, vtws);
    } else {
        gemm_qkv<<<dim3(MROWS / 128, 24), 256, 0, stream>>>(
            xb, Wq, Wk, Wv, bq, bk, bv, qws, kws, vtws);
    }

    attn_kernel<<<dim3(BSZ * NHEADS, TSEQ / 64), 256, 0, stream>>>(qws, kws, vtws, attn);
    convx_kernel<<<512, 256, 0, stream>>>(Wp, wpb);
    gemm_p<<<dim3(MROWS / 64, CDIM / 128), 256, 0, stream>>>(attn, wpb, bp, (float*)d_out);
}

// Round 20
// 108.131 us; speedup vs baseline: 1.1724x; 1.0426x over previous
//
#include <hip/hip_runtime.h>
#include <hip/hip_bf16.h>
#include <math.h>

#define TSEQ 2048
#define CDIM 1024
#define NHEADS 16
#define DHEAD 64
#define BSZ 2
#define MROWS (BSZ * TSEQ)  // 4096
#define SCALE_Q 0.18033688f  // 0.125 * log2(e): softmax becomes exp2(s)

typedef __attribute__((ext_vector_type(8))) short short8;
typedef __attribute__((ext_vector_type(4))) short short4v;
typedef __attribute__((ext_vector_type(4))) float f32x4;

__device__ inline f32x4 mfma16(short8 a, short8 b, f32x4 c) {
    return __builtin_amdgcn_mfma_f32_16x16x32_bf16(a, b, c, 0, 0, 0);
}

__device__ inline short f2bf(float f) {
    __hip_bfloat16 h = __float2bfloat16(f);
    return __builtin_bit_cast(short, h);
}

__device__ inline void gl_lds16(const short* g, short* l) {
    __builtin_amdgcn_global_load_lds(
        (const __attribute__((address_space(1))) void*)g,
        (__attribute__((address_space(3))) void*)l, 16, 0, 0);
}

// ---------------------------------------------------------------------------
// conv f32 -> bf16, 8 elems/thread.
// ---------------------------------------------------------------------------
__global__ __launch_bounds__(256) void convx_kernel(const float* __restrict__ x,
                                                    short* __restrict__ xb) {
    size_t off = (size_t)(blockIdx.x * 256 + threadIdx.x) * 8;
    float4 a = *(const float4*)(x + off);
    float4 b = *(const float4*)(x + off + 4);
    short8 h;
    h[0] = f2bf(a.x); h[1] = f2bf(a.y); h[2] = f2bf(a.z); h[3] = f2bf(a.w);
    h[4] = f2bf(b.x); h[5] = f2bf(b.y); h[6] = f2bf(b.z); h[7] = f2bf(b.w);
    *(short8*)(xb + off) = h;
}

// conv 3 weight matrices (1M elems each) -> bf16
__global__ __launch_bounds__(256) void conv3_kernel(
    const float* __restrict__ swq, const float* __restrict__ swk,
    const float* __restrict__ swv, short* __restrict__ wqb,
    short* __restrict__ wkb, short* __restrict__ wvb) {
    int chunk = blockIdx.x >> 9;               // 0..2 (512 blocks each)
    size_t off = (size_t)((blockIdx.x & 511) * 256 + threadIdx.x) * 8;
    const float* s = chunk == 0 ? swq : (chunk == 1 ? swk : swv);
    short* d = chunk == 0 ? wqb : (chunk == 1 ? wkb : wvb);
    float4 a = *(const float4*)(s + off);
    float4 b = *(const float4*)(s + off + 4);
    short8 h;
    h[0] = f2bf(a.x); h[1] = f2bf(a.y); h[2] = f2bf(a.z); h[3] = f2bf(a.w);
    h[4] = f2bf(b.x); h[5] = f2bf(b.y); h[6] = f2bf(b.z); h[7] = f2bf(b.w);
    *(short8*)(d + off) = h;
}

// ---------------------------------------------------------------------------
// Fused QKV GEMM, gl_lds path (m97 structure), used when workspace allows.
// ---------------------------------------------------------------------------
__global__ __launch_bounds__(256, 3) void gemm_qkv_g(
    const short* __restrict__ xb, const short* __restrict__ wqb,
    const short* __restrict__ wkb, const short* __restrict__ wvb,
    const float* __restrict__ bq, const float* __restrict__ bk,
    const float* __restrict__ bv, short* __restrict__ qws,
    short* __restrict__ kws, short* __restrict__ vtws) {
    __shared__ __attribute__((aligned(16))) short a_lds[128 * 64];
    __shared__ __attribute__((aligned(16))) short b_lds[128 * 64];

    const int tid = threadIdx.x;
    const int lane = tid & 63;
    const int wv = tid >> 6;
    const int wr = wv >> 1, wc = wv & 1;
    const int l15 = lane & 15, l4 = lane >> 4;
    const int mbase = blockIdx.x * 128;
    const int which = blockIdx.y >> 3;
    const int nbase = (blockIdx.y & 7) * 128;
    const short* Wb = which == 0 ? wqb : (which == 1 ? wkb : wvb);
    const float* bias = which == 0 ? bq : (which == 1 ? bk : bv);

    f32x4 acc[4][4];
#pragma unroll
    for (int i = 0; i < 4; ++i)
#pragma unroll
        for (int j = 0; j < 4; ++j) acc[i][j] = f32x4{0.f, 0.f, 0.f, 0.f};

    const int srow = tid >> 3;
    const int gcol = (tid & 7) ^ (srow & 7);
    const short* asrc = xb + (size_t)(mbase + srow) * CDIM + gcol * 8;
    const short* bsrc = Wb + (size_t)(nbase + srow) * CDIM + gcol * 8;
    short* adst = &a_lds[tid * 8];
    short* bdst = &b_lds[tid * 8];

    for (int k0 = 0; k0 < CDIM; k0 += 64) {
        __syncthreads();
#pragma unroll
        for (int it = 0; it < 4; ++it) {
            gl_lds16(asrc + (size_t)(it * 32) * CDIM + k0, adst + it * 2048);
            gl_lds16(bsrc + (size_t)(it * 32) * CDIM + k0, bdst + it * 2048);
        }
        __syncthreads();

#pragma unroll
        for (int kk = 0; kk < 2; ++kk) {
            short8 af[4], bfr[4];
#pragma unroll
            for (int i = 0; i < 4; ++i) {
                int R = wr * 64 + i * 16 + l15;
                af[i] = *(const short8*)&a_lds[R * 64 + ((kk * 4 + l4) ^ (R & 7)) * 8];
            }
#pragma unroll
            for (int j = 0; j < 4; ++j) {
                int R = wc * 64 + j * 16 + l15;
                bfr[j] = *(const short8*)&b_lds[R * 64 + ((kk * 4 + l4) ^ (R & 7)) * 8];
            }
#pragma unroll
            for (int i = 0; i < 4; ++i)
#pragma unroll
                for (int j = 0; j < 4; ++j)
                    acc[i][j] = mfma16(af[i], bfr[j], acc[i][j]);
        }
    }

    if (which < 2) {
        short* dst = which == 0 ? qws : kws;
        const float scale = which == 0 ? SCALE_Q : 1.0f;
#pragma unroll
        for (int i = 0; i < 4; ++i) {
            int mrow = mbase + wr * 64 + i * 16 + l4 * 4;
#pragma unroll
            for (int j = 0; j < 4; ++j) {
                int o = nbase + wc * 64 + j * 16 + l15;
                int n = o >> 6, d = o & 63;
                float bval = bias[o];
#pragma unroll
                for (int r = 0; r < 4; ++r) {
                    int mm = mrow + r;
                    int bb = mm >> 11;
                    int t = mm & (TSEQ - 1);
                    dst[(((size_t)bb * NHEADS + n) * TSEQ + t) * DHEAD + d] =
                        f2bf((acc[i][j][r] + bval) * scale);
                }
            }
        }
    } else {
#pragma unroll
        for (int i = 0; i < 4; ++i) {
            int mrow = mbase + wr * 64 + i * 16 + l4 * 4;
            int bb = mrow >> 11;
            int t = mrow & (TSEQ - 1);
#pragma unroll
            for (int j = 0; j < 4; ++j) {
                int o = nbase + wc * 64 + j * 16 + l15;
                int n = o >> 6, d = o & 63;
                float bval = bias[o];
                short4v h4;
#pragma unroll
                for (int r = 0; r < 4; ++r) h4[r] = f2bf(acc[i][j][r] + bval);
                *(short4v*)&vtws[(((size_t)bb * NHEADS + n) * DHEAD + d) * TSEQ + t] = h4;
            }
        }
    }
}

// ---------------------------------------------------------------------------
// Fused QKV GEMM, fallback path (r18-proven): f32 weights, reg staging.
// ---------------------------------------------------------------------------
__global__ __launch_bounds__(256, 3) void gemm_qkv(
    const short* __restrict__ xb, const float* __restrict__ Wq,
    const float* __restrict__ Wk, const float* __restrict__ Wv,
    const float* __restrict__ bq, const float* __restrict__ bk,
    const float* __restrict__ bv, short* __restrict__ qws,
    short* __restrict__ kws, short* __restrict__ vtws) {
    __shared__ __attribute__((aligned(16))) short a_lds[128][72];
    __shared__ __attribute__((aligned(16))) short b_lds[128][72];

    const int tid = threadIdx.x;
    const int lane = tid & 63;
    const int wv = tid >> 6;
    const int wr = wv >> 1, wc = wv & 1;
    const int l15 = lane & 15, l4 = lane >> 4;
    const int mbase = blockIdx.x * 128;
    const int which = blockIdx.y >> 3;
    const int nbase = (blockIdx.y & 7) * 128;
    const float* Wf = which == 0 ? Wq : (which == 1 ? Wk : Wv);
    const float* bias = which == 0 ? bq : (which == 1 ? bk : bv);

    f32x4 acc[4][4];
#pragma unroll
    for (int i = 0; i < 4; ++i)
#pragma unroll
        for (int j = 0; j < 4; ++j) acc[i][j] = f32x4{0.f, 0.f, 0.f, 0.f};

    const int ar = tid >> 3;
    const int ag = (tid & 7) * 8;
    const int br = tid >> 4;
    const int bg = (tid & 15) * 4;
    const short* aptr = xb + (size_t)(mbase + ar) * CDIM + ag;
    const float* bptr = Wf + (size_t)(nbase + br) * CDIM + bg;

    short8 apre[4];
    float4 bpre[8];
#pragma unroll
    for (int it = 0; it < 4; ++it)
        apre[it] = *(const short8*)(aptr + (size_t)(32 * it) * CDIM);
#pragma unroll
    for (int it = 0; it < 8; ++it)
        bpre[it] = *(const float4*)(bptr + (size_t)(16 * it) * CDIM);

    for (int k0 = 0; k0 < CDIM; k0 += 64) {
        __syncthreads();
#pragma unroll
        for (int it = 0; it < 4; ++it)
            *(short8*)&a_lds[ar + 32 * it][ag] = apre[it];
#pragma unroll
        for (int it = 0; it < 8; ++it) {
            short4v h;
            h.x = f2bf(bpre[it].x); h.y = f2bf(bpre[it].y);
            h.z = f2bf(bpre[it].z); h.w = f2bf(bpre[it].w);
            *(short4v*)&b_lds[br + 16 * it][bg] = h;
        }
        __syncthreads();
        if (k0 + 64 < CDIM) {
#pragma unroll
            for (int it = 0; it < 4; ++it)
                apre[it] = *(const short8*)(aptr + (size_t)(32 * it) * CDIM + k0 + 64);
#pragma unroll
            for (int it = 0; it < 8; ++it)
                bpre[it] = *(const float4*)(bptr + (size_t)(16 * it) * CDIM + k0 + 64);
        }

#pragma unroll
        for (int kk = 0; kk < 2; ++kk) {
            short8 af[4], bfr[4];
#pragma unroll
            for (int i = 0; i < 4; ++i)
                af[i] = *(const short8*)&a_lds[wr * 64 + i * 16 + l15][kk * 32 + l4 * 8];
#pragma unroll
            for (int j = 0; j < 4; ++j)
                bfr[j] = *(const short8*)&b_lds[wc * 64 + j * 16 + l15][kk * 32 + l4 * 8];
#pragma unroll
            for (int i = 0; i < 4; ++i)
#pragma unroll
                for (int j = 0; j < 4; ++j)
                    acc[i][j] = mfma16(af[i], bfr[j], acc[i][j]);
        }
    }

    if (which < 2) {
        short* dst = which == 0 ? qws : kws;
        const float scale = which == 0 ? SCALE_Q : 1.0f;
#pragma unroll
        for (int i = 0; i < 4; ++i) {
            int mrow = mbase + wr * 64 + i * 16 + l4 * 4;
#pragma unroll
            for (int j = 0; j < 4; ++j) {
                int o = nbase + wc * 64 + j * 16 + l15;
                int n = o >> 6, d = o & 63;
                float bval = bias[o];
#pragma unroll
                for (int r = 0; r < 4; ++r) {
                    int mm = mrow + r;
                    int bb = mm >> 11;
                    int t = mm & (TSEQ - 1);
                    dst[(((size_t)bb * NHEADS + n) * TSEQ + t) * DHEAD + d] =
                        f2bf((acc[i][j][r] + bval) * scale);
                }
            }
        }
    } else {
#pragma unroll
        for (int i = 0; i < 4; ++i) {
            int mrow = mbase + wr * 64 + i * 16 + l4 * 4;
            int bb = mrow >> 11;
            int t = mrow & (TSEQ - 1);
#pragma unroll
            for (int j = 0; j < 4; ++j) {
                int o = nbase + wc * 64 + j * 16 + l15;
                int n = o >> 6, d = o & 63;
                float bval = bias[o];
                short4v h4;
#pragma unroll
                for (int r = 0; r < 4; ++r) h4[r] = f2bf(acc[i][j][r] + bval);
                *(short4v*)&vtws[(((size_t)bb * NHEADS + n) * DHEAD + d) * TSEQ + t] = h4;
            }
        }
    }
}

// ---------------------------------------------------------------------------
// Output projection GEMM (r18-proven): BM=64, BN=128, BK=32, T14 prefetch,
// B = pre-converted bf16 Wp.
// ---------------------------------------------------------------------------
__global__ __launch_bounds__(256) void gemm_p(
    const short* __restrict__ attn, const short* __restrict__ wpb,
    const float* __restrict__ bp, float* __restrict__ out) {
    __shared__ __attribute__((aligned(16))) short a_lds[64][40];
    __shared__ __attribute__((aligned(16))) short b_lds[128][40];

    const int tid = threadIdx.x;
    const int lane = tid & 63;
    const int wv = tid >> 6;
    const int wr = wv >> 1, wc = wv & 1;
    const int l15 = lane & 15, l4 = lane >> 4;
    const int mbase = blockIdx.x * 64;
    const int nbase = blockIdx.y * 128;

    f32x4 acc[2][4];
#pragma unroll
    for (int i = 0; i < 2; ++i)
#pragma unroll
        for (int j = 0; j < 4; ++j) acc[i][j] = f32x4{0.f, 0.f, 0.f, 0.f};

    const int arow = tid >> 2;
    const int acol = (tid & 3) * 8;
    const short* aptr = attn + (size_t)(mbase + arow) * CDIM + acol;
    const short* bptr = wpb + (size_t)(nbase + arow) * CDIM + acol;

    short8 apre, bpre[2];
    apre = *(const short8*)(aptr);
    bpre[0] = *(const short8*)(bptr);
    bpre[1] = *(const short8*)(bptr + (size_t)64 * CDIM);

    for (int k0 = 0; k0 < CDIM; k0 += 32) {
        __syncthreads();
        *(short8*)&a_lds[arow][acol] = apre;
        *(short8*)&b_lds[arow][acol] = bpre[0];
        *(short8*)&b_lds[arow + 64][acol] = bpre[1];
        __syncthreads();
        if (k0 + 32 < CDIM) {
            apre = *(const short8*)(aptr + k0 + 32);
            bpre[0] = *(const short8*)(bptr + k0 + 32);
            bpre[1] = *(const short8*)(bptr + (size_t)64 * CDIM + k0 + 32);
        }

        short8 af[2], bfr[4];
#pragma unroll
        for (int i = 0; i < 2; ++i)
            af[i] = *(const short8*)&a_lds[wr * 32 + i * 16 + l15][l4 * 8];
#pragma unroll
        for (int j = 0; j < 4; ++j)
            bfr[j] = *(const short8*)&b_lds[wc * 64 + j * 16 + l15][l4 * 8];
#pragma unroll
        for (int i = 0; i < 2; ++i)
#pragma unroll
            for (int j = 0; j < 4; ++j)
                acc[i][j] = mfma16(af[i], bfr[j], acc[i][j]);
    }

#pragma unroll
    for (int i = 0; i < 2; ++i) {
        int mrow = mbase + wr * 32 + i * 16 + l4 * 4;
#pragma unroll
        for (int j = 0; j < 4; ++j) {
            int o = nbase + wc * 64 + j * 16 + l15;
            float bval = bp[o];
#pragma unroll
            for (int r = 0; r < 4; ++r)
                out[(size_t)(mrow + r) * CDIM + o] = acc[i][j][r] + bval;
        }
    }
}

// ---------------------------------------------------------------------------
// Flash attention v6: QBLK=64 (4 waves x 16 q-rows), KVBLK=128. No-max
// softmax via native exp2 (q pre-scaled). NEW: l computed via MFMA with a
// constant "ones-row" B-fragment (l = P @ 1) -> no lp-adds, no l_run state,
// epilogue reduce replaced by one shfl broadcast. K/V reg-prefetch into
// XOR-swizzled LDS. q,k [B*N,T,D]; vt [B*N,D,T].
// ---------------------------------------------------------------------------
__global__ __launch_bounds__(256) void attn_kernel(
    const short* __restrict__ q, const short* __restrict__ k,
    const short* __restrict__ vt, short* __restrict__ attn_out) {
    __shared__ __attribute__((aligned(16))) short k_lds[128][64];
    __shared__ __attribute__((aligned(16))) short vt_lds[64][128];
    __shared__ __attribute__((aligned(16))) short p_lds[4][16][136];

    const int tid = threadIdx.x;
    const int w = tid >> 6;
    const int lane = tid & 63;
    const int l15 = lane & 15;
    const int l4 = lane >> 4;
    const int h = blockIdx.x;
    const int qtile = gridDim.y - 1 - blockIdx.y;
    const int wrow0 = qtile * 64 + w * 16;

    short8 qf[2];
#pragma unroll
    for (int kh = 0; kh < 2; ++kh)
        qf[kh] = *(const short8*)(q + ((size_t)h * TSEQ + wrow0 + l15) * DHEAD +
                                  kh * 32 + l4 * 8);

    // constant ones-row B-fragment: B[d-row l15][*] = 1 iff l15==0
    const short onebf = (short)0x3F80;  // bf16(1.0)
    short8 vf_ones;
#pragma unroll
    for (int e = 0; e < 8; ++e) vf_ones[e] = (l15 == 0) ? onebf : (short)0;

    f32x4 o_acc[4];
    f32x4 o5 = f32x4{0.f, 0.f, 0.f, 0.f};  // l accumulator (valid in lanes l15==0)
#pragma unroll
    for (int dt = 0; dt < 4; ++dt) o_acc[dt] = f32x4{0.f, 0.f, 0.f, 0.f};

    const int ntiles = (qtile + 2) >> 1;
    const size_t kbase = (size_t)h * TSEQ * DHEAD;
    const size_t vbase = (size_t)h * DHEAD * TSEQ;

    const int ksrow = tid >> 3, ksg = tid & 7;
    const int vsrow = tid >> 4, vsg = tid & 15;

    short8 kpre[4], vpre[4];
#pragma unroll
    for (int it = 0; it < 4; ++it) {
        kpre[it] = *(const short8*)(k + kbase + (size_t)(ksrow + it * 32) * DHEAD + ksg * 8);
        vpre[it] = *(const short8*)(vt + vbase + (size_t)(vsrow + it * 16) * TSEQ + vsg * 8);
    }

    for (int kvt = 0; kvt < ntiles; ++kvt) {
        const int kvbase = kvt * 128;
        __syncthreads();
#pragma unroll
        for (int it = 0; it < 4; ++it) {
            int krow = ksrow + it * 32;
            *(short8*)&k_lds[krow][(ksg ^ (krow & 7)) * 8] = kpre[it];
            int vrow = vsrow + it * 16;
            *(short8*)&vt_lds[vrow][((vsg ^ (vrow & 15))) * 8] = vpre[it];
        }
        __syncthreads();
        if (kvt + 1 < ntiles) {
            int kvb2 = kvbase + 128;
#pragma unroll
            for (int it = 0; it < 4; ++it) {
                kpre[it] = *(const short8*)(k + kbase + (size_t)(kvb2 + ksrow + it * 32) * DHEAD + ksg * 8);
                vpre[it] = *(const short8*)(vt + vbase + (size_t)(vsrow + it * 16) * TSEQ + kvb2 + vsg * 8);
            }
        }

        f32x4 s[8];
#pragma unroll
        for (int jt = 0; jt < 8; ++jt) {
            int row = jt * 16 + l15;
            int sw = row & 7;
            short8 kf0 = *(const short8*)&k_lds[row][(l4 ^ sw) * 8];
            short8 kf1 = *(const short8*)&k_lds[row][((4 + l4) ^ sw) * 8];
            f32x4 a = f32x4{0.f, 0.f, 0.f, 0.f};
            a = mfma16(qf[0], kf0, a);
            a = mfma16(qf[1], kf1, a);
            s[jt] = a;
        }

        // softmax: p = native exp2(s); RNE bf16 store (l comes from PV MFMA)
        const bool needmask = (kvbase + 127 > wrow0);
#pragma unroll
        for (int r = 0; r < 4; ++r) {
            int qrow = wrow0 + l4 * 4 + r;
#pragma unroll
            for (int jt = 0; jt < 8; ++jt) {
                float x = s[jt][r];
                if (needmask && (kvbase + jt * 16 + l15 > qrow)) x = -INFINITY;
                p_lds[w][l4 * 4 + r][jt * 16 + l15] = f2bf(__builtin_amdgcn_exp2f(x));
            }
        }

        short8 pa[4];
#pragma unroll
        for (int ks = 0; ks < 4; ++ks)
            pa[ks] = *(const short8*)&p_lds[w][l15][ks * 32 + l4 * 8];
#pragma unroll
        for (int dt = 0; dt < 4; ++dt) {
            int row = dt * 16 + l15;
            int sw = row & 15;
#pragma unroll
            for (int ks = 0; ks < 4; ++ks) {
                short8 vf = *(const short8*)&vt_lds[row][((ks * 4 + l4) ^ sw) * 8];
                o_acc[dt] = mfma16(pa[ks], vf, o_acc[dt]);
            }
        }
        // l row: o5 += P @ ones (constant fragment, matrix pipe)
#pragma unroll
        for (int ks = 0; ks < 4; ++ks)
            o5 = mfma16(pa[ks], vf_ones, o5);
    }

    // epilogue: l lives in lanes l15==0 (lane = l4*16); broadcast + divide
    float inv[4];
#pragma unroll
    for (int r = 0; r < 4; ++r)
        inv[r] = 1.0f / __shfl(o5[r], lane & 48);
    const int b = h >> 4, n = h & 15;
#pragma unroll
    for (int dt = 0; dt < 4; ++dt) {
#pragma unroll
        for (int r = 0; r < 4; ++r) {
            int t = wrow0 + l4 * 4 + r;
            attn_out[((size_t)b * TSEQ + t) * CDIM + n * DHEAD + dt * 16 + l15] =
                f2bf(o_acc[dt][r] * inv[r]);
        }
    }
}

extern "C" void kernel_launch(void* const* d_in, const int* in_sizes, int n_in,
                              void* d_out, int out_size, void* d_ws, size_t ws_size,
                              hipStream_t stream) {
    const float* x  = (const float*)d_in[0];
    const float* Wq = (const float*)d_in[1];
    const float* bq = (const float*)d_in[2];
    const float* Wk = (const float*)d_in[3];
    const float* bk = (const float*)d_in[4];
    const float* Wv = (const float*)d_in[5];
    const float* bv = (const float*)d_in[6];
    const float* Wp = (const float*)d_in[7];
    const float* bp = (const float*)d_in[8];

    char* ws = (char*)d_ws;
    const size_t SZ = (size_t)MROWS * CDIM * sizeof(short);  // 8 MB
    short* qws  = (short*)(ws);             // slot 0; reused for Wp bf16 after attn
    short* kws  = (short*)(ws + SZ);        // slot 1
    short* vtws = (short*)(ws + 2 * SZ);    // slot 2
    short* xb   = (short*)(ws + 3 * SZ);    // slot 3; reused for attn out
    short* attn = xb;                        // alias: xb dead after QKV GEMM
    short* wpb  = qws;                       // alias: qws dead after attn

    convx_kernel<<<2048, 256, 0, stream>>>(x, xb);

    const size_t WSZ = (size_t)CDIM * CDIM * sizeof(short);  // 2 MB
    if (ws_size >= 4 * SZ + 3 * WSZ) {
        short* wqb = (short*)(ws + 4 * SZ);
        short* wkb = wqb + (size_t)CDIM * CDIM;
        short* wvb = wkb + (size_t)CDIM * CDIM;
        conv3_kernel<<<1536, 256, 0, stream>>>(Wq, Wk, Wv, wqb, wkb, wvb);
        gemm_qkv_g<<<dim3(MROWS / 128, 24), 256, 0, stream>>>(
            xb, wqb, wkb, wvb, bq, bk, bv, qws, kws, vtws);
    } else {
        gemm_qkv<<<dim3(MROWS / 128, 24), 256, 0, stream>>>(
            xb, Wq, Wk, Wv, bq, bk, bv, qws, kws, vtws);
    }

    attn_kernel<<<dim3(BSZ * NHEADS, TSEQ / 64), 256, 0, stream>>>(qws, kws, vtws, attn);
    convx_kernel<<<512, 256, 0, stream>>>(Wp, wpb);
    gemm_p<<<dim3(MROWS / 64, CDIM / 128), 256, 0, stream>>>(attn, wpb, bp, (float*)d_out);
}

// Round 21
// 102.337 us; speedup vs baseline: 1.2388x; 1.0566x over previous
//
#include <hip/hip_runtime.h>
#include <hip/hip_bf16.h>
#include <math.h>

#define TSEQ 2048
#define CDIM 1024
#define NHEADS 16
#define DHEAD 64
#define BSZ 2
#define MROWS (BSZ * TSEQ)  // 4096
#define SCALE_Q 0.18033688f  // 0.125 * log2(e): softmax becomes exp2(s)

typedef __attribute__((ext_vector_type(8))) short short8;
typedef __attribute__((ext_vector_type(4))) short short4v;
typedef __attribute__((ext_vector_type(4))) float f32x4;

__device__ inline f32x4 mfma16(short8 a, short8 b, f32x4 c) {
    return __builtin_amdgcn_mfma_f32_16x16x32_bf16(a, b, c, 0, 0, 0);
}

__device__ inline short f2bf(float f) {
    __hip_bfloat16 h = __float2bfloat16(f);
    return __builtin_bit_cast(short, h);
}

__device__ inline void gl_lds16(const short* g, short* l) {
    __builtin_amdgcn_global_load_lds(
        (const __attribute__((address_space(1))) void*)g,
        (__attribute__((address_space(3))) void*)l, 16, 0, 0);
}

// ---------------------------------------------------------------------------
// conv f32 -> bf16, 8 elems/thread (x only; fallback path).
// ---------------------------------------------------------------------------
__global__ __launch_bounds__(256) void convx_kernel(const float* __restrict__ x,
                                                    short* __restrict__ xb) {
    size_t off = (size_t)(blockIdx.x * 256 + threadIdx.x) * 8;
    float4 a = *(const float4*)(x + off);
    float4 b = *(const float4*)(x + off + 4);
    short8 h;
    h[0] = f2bf(a.x); h[1] = f2bf(a.y); h[2] = f2bf(a.z); h[3] = f2bf(a.w);
    h[4] = f2bf(b.x); h[5] = f2bf(b.y); h[6] = f2bf(b.z); h[7] = f2bf(b.w);
    *(short8*)(xb + off) = h;
}

// conv x (4M) + Wq/Wk/Wv/Wp (1M each) -> bf16 in ONE launch (big-ws path).
__global__ __launch_bounds__(256) void conv5_kernel(
    const float* __restrict__ x, const float* __restrict__ swq,
    const float* __restrict__ swk, const float* __restrict__ swv,
    const float* __restrict__ swp, short* __restrict__ xb,
    short* __restrict__ wqb, short* __restrict__ wkb,
    short* __restrict__ wvb, short* __restrict__ wpb) {
    int chunk = blockIdx.x >> 9;               // 0..7 (512 blocks per 1M elems)
    size_t off = (size_t)((blockIdx.x & 511) * 256 + threadIdx.x) * 8;
    const float* s;
    short* d;
    if (chunk < 4)      { s = x + (size_t)chunk * 1048576; d = xb + (size_t)chunk * 1048576; }
    else if (chunk == 4){ s = swq; d = wqb; }
    else if (chunk == 5){ s = swk; d = wkb; }
    else if (chunk == 6){ s = swv; d = wvb; }
    else                { s = swp; d = wpb; }
    float4 a = *(const float4*)(s + off);
    float4 b = *(const float4*)(s + off + 4);
    short8 h;
    h[0] = f2bf(a.x); h[1] = f2bf(a.y); h[2] = f2bf(a.z); h[3] = f2bf(a.w);
    h[4] = f2bf(b.x); h[5] = f2bf(b.y); h[6] = f2bf(b.z); h[7] = f2bf(b.w);
    *(short8*)(d + off) = h;
}

// ---------------------------------------------------------------------------
// Fused QKV GEMM, gl_lds path (m97 structure), used when workspace allows.
// ---------------------------------------------------------------------------
__global__ __launch_bounds__(256, 3) void gemm_qkv_g(
    const short* __restrict__ xb, const short* __restrict__ wqb,
    const short* __restrict__ wkb, const short* __restrict__ wvb,
    const float* __restrict__ bq, const float* __restrict__ bk,
    const float* __restrict__ bv, short* __restrict__ qws,
    short* __restrict__ kws, short* __restrict__ vtws) {
    __shared__ __attribute__((aligned(16))) short a_lds[128 * 64];
    __shared__ __attribute__((aligned(16))) short b_lds[128 * 64];

    const int tid = threadIdx.x;
    const int lane = tid & 63;
    const int wv = tid >> 6;
    const int wr = wv >> 1, wc = wv & 1;
    const int l15 = lane & 15, l4 = lane >> 4;
    const int mbase = blockIdx.x * 128;
    const int which = blockIdx.y >> 3;
    const int nbase = (blockIdx.y & 7) * 128;
    const short* Wb = which == 0 ? wqb : (which == 1 ? wkb : wvb);
    const float* bias = which == 0 ? bq : (which == 1 ? bk : bv);

    f32x4 acc[4][4];
#pragma unroll
    for (int i = 0; i < 4; ++i)
#pragma unroll
        for (int j = 0; j < 4; ++j) acc[i][j] = f32x4{0.f, 0.f, 0.f, 0.f};

    const int srow = tid >> 3;
    const int gcol = (tid & 7) ^ (srow & 7);
    const short* asrc = xb + (size_t)(mbase + srow) * CDIM + gcol * 8;
    const short* bsrc = Wb + (size_t)(nbase + srow) * CDIM + gcol * 8;
    short* adst = &a_lds[tid * 8];
    short* bdst = &b_lds[tid * 8];

    for (int k0 = 0; k0 < CDIM; k0 += 64) {
        __syncthreads();
#pragma unroll
        for (int it = 0; it < 4; ++it) {
            gl_lds16(asrc + (size_t)(it * 32) * CDIM + k0, adst + it * 2048);
            gl_lds16(bsrc + (size_t)(it * 32) * CDIM + k0, bdst + it * 2048);
        }
        __syncthreads();

#pragma unroll
        for (int kk = 0; kk < 2; ++kk) {
            short8 af[4], bfr[4];
#pragma unroll
            for (int i = 0; i < 4; ++i) {
                int R = wr * 64 + i * 16 + l15;
                af[i] = *(const short8*)&a_lds[R * 64 + ((kk * 4 + l4) ^ (R & 7)) * 8];
            }
#pragma unroll
            for (int j = 0; j < 4; ++j) {
                int R = wc * 64 + j * 16 + l15;
                bfr[j] = *(const short8*)&b_lds[R * 64 + ((kk * 4 + l4) ^ (R & 7)) * 8];
            }
#pragma unroll
            for (int i = 0; i < 4; ++i)
#pragma unroll
                for (int j = 0; j < 4; ++j)
                    acc[i][j] = mfma16(af[i], bfr[j], acc[i][j]);
        }
    }

    if (which < 2) {
        short* dst = which == 0 ? qws : kws;
        const float scale = which == 0 ? SCALE_Q : 1.0f;
#pragma unroll
        for (int i = 0; i < 4; ++i) {
            int mrow = mbase + wr * 64 + i * 16 + l4 * 4;
#pragma unroll
            for (int j = 0; j < 4; ++j) {
                int o = nbase + wc * 64 + j * 16 + l15;
                int n = o >> 6, d = o & 63;
                float bval = bias[o];
#pragma unroll
                for (int r = 0; r < 4; ++r) {
                    int mm = mrow + r;
                    int bb = mm >> 11;
                    int t = mm & (TSEQ - 1);
                    dst[(((size_t)bb * NHEADS + n) * TSEQ + t) * DHEAD + d] =
                        f2bf((acc[i][j][r] + bval) * scale);
                }
            }
        }
    } else {
#pragma unroll
        for (int i = 0; i < 4; ++i) {
            int mrow = mbase + wr * 64 + i * 16 + l4 * 4;
            int bb = mrow >> 11;
            int t = mrow & (TSEQ - 1);
#pragma unroll
            for (int j = 0; j < 4; ++j) {
                int o = nbase + wc * 64 + j * 16 + l15;
                int n = o >> 6, d = o & 63;
                float bval = bias[o];
                short4v h4;
#pragma unroll
                for (int r = 0; r < 4; ++r) h4[r] = f2bf(acc[i][j][r] + bval);
                *(short4v*)&vtws[(((size_t)bb * NHEADS + n) * DHEAD + d) * TSEQ + t] = h4;
            }
        }
    }
}

// ---------------------------------------------------------------------------
// Fused QKV GEMM, fallback path (r18-proven): f32 weights, reg staging.
// ---------------------------------------------------------------------------
__global__ __launch_bounds__(256, 3) void gemm_qkv(
    const short* __restrict__ xb, const float* __restrict__ Wq,
    const float* __restrict__ Wk, const float* __restrict__ Wv,
    const float* __restrict__ bq, const float* __restrict__ bk,
    const float* __restrict__ bv, short* __restrict__ qws,
    short* __restrict__ kws, short* __restrict__ vtws) {
    __shared__ __attribute__((aligned(16))) short a_lds[128][72];
    __shared__ __attribute__((aligned(16))) short b_lds[128][72];

    const int tid = threadIdx.x;
    const int lane = tid & 63;
    const int wv = tid >> 6;
    const int wr = wv >> 1, wc = wv & 1;
    const int l15 = lane & 15, l4 = lane >> 4;
    const int mbase = blockIdx.x * 128;
    const int which = blockIdx.y >> 3;
    const int nbase = (blockIdx.y & 7) * 128;
    const float* Wf = which == 0 ? Wq : (which == 1 ? Wk : Wv);
    const float* bias = which == 0 ? bq : (which == 1 ? bk : bv);

    f32x4 acc[4][4];
#pragma unroll
    for (int i = 0; i < 4; ++i)
#pragma unroll
        for (int j = 0; j < 4; ++j) acc[i][j] = f32x4{0.f, 0.f, 0.f, 0.f};

    const int ar = tid >> 3;
    const int ag = (tid & 7) * 8;
    const int br = tid >> 4;
    const int bg = (tid & 15) * 4;
    const short* aptr = xb + (size_t)(mbase + ar) * CDIM + ag;
    const float* bptr = Wf + (size_t)(nbase + br) * CDIM + bg;

    short8 apre[4];
    float4 bpre[8];
#pragma unroll
    for (int it = 0; it < 4; ++it)
        apre[it] = *(const short8*)(aptr + (size_t)(32 * it) * CDIM);
#pragma unroll
    for (int it = 0; it < 8; ++it)
        bpre[it] = *(const float4*)(bptr + (size_t)(16 * it) * CDIM);

    for (int k0 = 0; k0 < CDIM; k0 += 64) {
        __syncthreads();
#pragma unroll
        for (int it = 0; it < 4; ++it)
            *(short8*)&a_lds[ar + 32 * it][ag] = apre[it];
#pragma unroll
        for (int it = 0; it < 8; ++it) {
            short4v h;
            h.x = f2bf(bpre[it].x); h.y = f2bf(bpre[it].y);
            h.z = f2bf(bpre[it].z); h.w = f2bf(bpre[it].w);
            *(short4v*)&b_lds[br + 16 * it][bg] = h;
        }
        __syncthreads();
        if (k0 + 64 < CDIM) {
#pragma unroll
            for (int it = 0; it < 4; ++it)
                apre[it] = *(const short8*)(aptr + (size_t)(32 * it) * CDIM + k0 + 64);
#pragma unroll
            for (int it = 0; it < 8; ++it)
                bpre[it] = *(const float4*)(bptr + (size_t)(16 * it) * CDIM + k0 + 64);
        }

#pragma unroll
        for (int kk = 0; kk < 2; ++kk) {
            short8 af[4], bfr[4];
#pragma unroll
            for (int i = 0; i < 4; ++i)
                af[i] = *(const short8*)&a_lds[wr * 64 + i * 16 + l15][kk * 32 + l4 * 8];
#pragma unroll
            for (int j = 0; j < 4; ++j)
                bfr[j] = *(const short8*)&b_lds[wc * 64 + j * 16 + l15][kk * 32 + l4 * 8];
#pragma unroll
            for (int i = 0; i < 4; ++i)
#pragma unroll
                for (int j = 0; j < 4; ++j)
                    acc[i][j] = mfma16(af[i], bfr[j], acc[i][j]);
        }
    }

    if (which < 2) {
        short* dst = which == 0 ? qws : kws;
        const float scale = which == 0 ? SCALE_Q : 1.0f;
#pragma unroll
        for (int i = 0; i < 4; ++i) {
            int mrow = mbase + wr * 64 + i * 16 + l4 * 4;
#pragma unroll
            for (int j = 0; j < 4; ++j) {
                int o = nbase + wc * 64 + j * 16 + l15;
                int n = o >> 6, d = o & 63;
                float bval = bias[o];
#pragma unroll
                for (int r = 0; r < 4; ++r) {
                    int mm = mrow + r;
                    int bb = mm >> 11;
                    int t = mm & (TSEQ - 1);
                    dst[(((size_t)bb * NHEADS + n) * TSEQ + t) * DHEAD + d] =
                        f2bf((acc[i][j][r] + bval) * scale);
                }
            }
        }
    } else {
#pragma unroll
        for (int i = 0; i < 4; ++i) {
            int mrow = mbase + wr * 64 + i * 16 + l4 * 4;
            int bb = mrow >> 11;
            int t = mrow & (TSEQ - 1);
#pragma unroll
            for (int j = 0; j < 4; ++j) {
                int o = nbase + wc * 64 + j * 16 + l15;
                int n = o >> 6, d = o & 63;
                float bval = bias[o];
                short4v h4;
#pragma unroll
                for (int r = 0; r < 4; ++r) h4[r] = f2bf(acc[i][j][r] + bval);
                *(short4v*)&vtws[(((size_t)bb * NHEADS + n) * DHEAD + d) * TSEQ + t] = h4;
            }
        }
    }
}

// ---------------------------------------------------------------------------
// Output projection GEMM (r18-proven): BM=64, BN=128, BK=32, T14 prefetch,
// B = pre-converted bf16 Wp.
// ---------------------------------------------------------------------------
__global__ __launch_bounds__(256) void gemm_p(
    const short* __restrict__ attn, const short* __restrict__ wpb,
    const float* __restrict__ bp, float* __restrict__ out) {
    __shared__ __attribute__((aligned(16))) short a_lds[64][40];
    __shared__ __attribute__((aligned(16))) short b_lds[128][40];

    const int tid = threadIdx.x;
    const int lane = tid & 63;
    const int wv = tid >> 6;
    const int wr = wv >> 1, wc = wv & 1;
    const int l15 = lane & 15, l4 = lane >> 4;
    const int mbase = blockIdx.x * 64;
    const int nbase = blockIdx.y * 128;

    f32x4 acc[2][4];
#pragma unroll
    for (int i = 0; i < 2; ++i)
#pragma unroll
        for (int j = 0; j < 4; ++j) acc[i][j] = f32x4{0.f, 0.f, 0.f, 0.f};

    const int arow = tid >> 2;
    const int acol = (tid & 3) * 8;
    const short* aptr = attn + (size_t)(mbase + arow) * CDIM + acol;
    const short* bptr = wpb + (size_t)(nbase + arow) * CDIM + acol;

    short8 apre, bpre[2];
    apre = *(const short8*)(aptr);
    bpre[0] = *(const short8*)(bptr);
    bpre[1] = *(const short8*)(bptr + (size_t)64 * CDIM);

    for (int k0 = 0; k0 < CDIM; k0 += 32) {
        __syncthreads();
        *(short8*)&a_lds[arow][acol] = apre;
        *(short8*)&b_lds[arow][acol] = bpre[0];
        *(short8*)&b_lds[arow + 64][acol] = bpre[1];
        __syncthreads();
        if (k0 + 32 < CDIM) {
            apre = *(const short8*)(aptr + k0 + 32);
            bpre[0] = *(const short8*)(bptr + k0 + 32);
            bpre[1] = *(const short8*)(bptr + (size_t)64 * CDIM + k0 + 32);
        }

        short8 af[2], bfr[4];
#pragma unroll
        for (int i = 0; i < 2; ++i)
            af[i] = *(const short8*)&a_lds[wr * 32 + i * 16 + l15][l4 * 8];
#pragma unroll
        for (int j = 0; j < 4; ++j)
            bfr[j] = *(const short8*)&b_lds[wc * 64 + j * 16 + l15][l4 * 8];
#pragma unroll
        for (int i = 0; i < 2; ++i)
#pragma unroll
            for (int j = 0; j < 4; ++j)
                acc[i][j] = mfma16(af[i], bfr[j], acc[i][j]);
    }

#pragma unroll
    for (int i = 0; i < 2; ++i) {
        int mrow = mbase + wr * 32 + i * 16 + l4 * 4;
#pragma unroll
        for (int j = 0; j < 4; ++j) {
            int o = nbase + wc * 64 + j * 16 + l15;
            float bval = bp[o];
#pragma unroll
            for (int r = 0; r < 4; ++r)
                out[(size_t)(mrow + r) * CDIM + o] = acc[i][j][r] + bval;
        }
    }
}

// ---------------------------------------------------------------------------
// Flash attention v7: QBLK=64 (4 waves x 16 q-rows), KVBLK=128, no-max
// softmax via native exp2 (q pre-scaled), l via ones-row MFMA, TRUNCATED
// bf16 P store (l from same truncated P via MFMA: num/denom consistent).
// K/V reg-prefetch into XOR-swizzled LDS. q,k [B*N,T,D]; vt [B*N,D,T].
// ---------------------------------------------------------------------------
__global__ __launch_bounds__(256) void attn_kernel(
    const short* __restrict__ q, const short* __restrict__ k,
    const short* __restrict__ vt, short* __restrict__ attn_out) {
    __shared__ __attribute__((aligned(16))) short k_lds[128][64];
    __shared__ __attribute__((aligned(16))) short vt_lds[64][128];
    __shared__ __attribute__((aligned(16))) short p_lds[4][16][136];

    const int tid = threadIdx.x;
    const int w = tid >> 6;
    const int lane = tid & 63;
    const int l15 = lane & 15;
    const int l4 = lane >> 4;
    const int h = blockIdx.x;
    const int qtile = gridDim.y - 1 - blockIdx.y;
    const int wrow0 = qtile * 64 + w * 16;

    short8 qf[2];
#pragma unroll
    for (int kh = 0; kh < 2; ++kh)
        qf[kh] = *(const short8*)(q + ((size_t)h * TSEQ + wrow0 + l15) * DHEAD +
                                  kh * 32 + l4 * 8);

    const short onebf = (short)0x3F80;  // bf16(1.0)
    short8 vf_ones;
#pragma unroll
    for (int e = 0; e < 8; ++e) vf_ones[e] = (l15 == 0) ? onebf : (short)0;

    f32x4 o_acc[4];
    f32x4 o5 = f32x4{0.f, 0.f, 0.f, 0.f};
#pragma unroll
    for (int dt = 0; dt < 4; ++dt) o_acc[dt] = f32x4{0.f, 0.f, 0.f, 0.f};

    const int ntiles = (qtile + 2) >> 1;
    const size_t kbase = (size_t)h * TSEQ * DHEAD;
    const size_t vbase = (size_t)h * DHEAD * TSEQ;

    const int ksrow = tid >> 3, ksg = tid & 7;
    const int vsrow = tid >> 4, vsg = tid & 15;

    short8 kpre[4], vpre[4];
#pragma unroll
    for (int it = 0; it < 4; ++it) {
        kpre[it] = *(const short8*)(k + kbase + (size_t)(ksrow + it * 32) * DHEAD + ksg * 8);
        vpre[it] = *(const short8*)(vt + vbase + (size_t)(vsrow + it * 16) * TSEQ + vsg * 8);
    }

    for (int kvt = 0; kvt < ntiles; ++kvt) {
        const int kvbase = kvt * 128;
        __syncthreads();
#pragma unroll
        for (int it = 0; it < 4; ++it) {
            int krow = ksrow + it * 32;
            *(short8*)&k_lds[krow][(ksg ^ (krow & 7)) * 8] = kpre[it];
            int vrow = vsrow + it * 16;
            *(short8*)&vt_lds[vrow][((vsg ^ (vrow & 15))) * 8] = vpre[it];
        }
        __syncthreads();
        if (kvt + 1 < ntiles) {
            int kvb2 = kvbase + 128;
#pragma unroll
            for (int it = 0; it < 4; ++it) {
                kpre[it] = *(const short8*)(k + kbase + (size_t)(kvb2 + ksrow + it * 32) * DHEAD + ksg * 8);
                vpre[it] = *(const short8*)(vt + vbase + (size_t)(vsrow + it * 16) * TSEQ + kvb2 + vsg * 8);
            }
        }

        f32x4 s[8];
#pragma unroll
        for (int jt = 0; jt < 8; ++jt) {
            int row = jt * 16 + l15;
            int sw = row & 7;
            short8 kf0 = *(const short8*)&k_lds[row][(l4 ^ sw) * 8];
            short8 kf1 = *(const short8*)&k_lds[row][((4 + l4) ^ sw) * 8];
            f32x4 a = f32x4{0.f, 0.f, 0.f, 0.f};
            a = mfma16(qf[0], kf0, a);
            a = mfma16(qf[1], kf1, a);
            s[jt] = a;
        }

        // softmax: p = native exp2(s); TRUNCATED bf16 store
        const bool needmask = (kvbase + 127 > wrow0);
#pragma unroll
        for (int r = 0; r < 4; ++r) {
            int qrow = wrow0 + l4 * 4 + r;
#pragma unroll
            for (int jt = 0; jt < 8; ++jt) {
                float x = s[jt][r];
                if (needmask && (kvbase + jt * 16 + l15 > qrow)) x = -INFINITY;
                unsigned int eb = __builtin_bit_cast(unsigned int,
                                                     __builtin_amdgcn_exp2f(x));
                p_lds[w][l4 * 4 + r][jt * 16 + l15] = (short)(eb >> 16);
            }
        }

        short8 pa[4];
#pragma unroll
        for (int ks = 0; ks < 4; ++ks)
            pa[ks] = *(const short8*)&p_lds[w][l15][ks * 32 + l4 * 8];
#pragma unroll
        for (int dt = 0; dt < 4; ++dt) {
            int row = dt * 16 + l15;
            int sw = row & 15;
#pragma unroll
            for (int ks = 0; ks < 4; ++ks) {
                short8 vf = *(const short8*)&vt_lds[row][((ks * 4 + l4) ^ sw) * 8];
                o_acc[dt] = mfma16(pa[ks], vf, o_acc[dt]);
            }
        }
#pragma unroll
        for (int ks = 0; ks < 4; ++ks)
            o5 = mfma16(pa[ks], vf_ones, o5);
    }

    float inv[4];
#pragma unroll
    for (int r = 0; r < 4; ++r)
        inv[r] = 1.0f / __shfl(o5[r], lane & 48);
    const int b = h >> 4, n = h & 15;
#pragma unroll
    for (int dt = 0; dt < 4; ++dt) {
#pragma unroll
        for (int r = 0; r < 4; ++r) {
            int t = wrow0 + l4 * 4 + r;
            attn_out[((size_t)b * TSEQ + t) * CDIM + n * DHEAD + dt * 16 + l15] =
                f2bf(o_acc[dt][r] * inv[r]);
        }
    }
}

extern "C" void kernel_launch(void* const* d_in, const int* in_sizes, int n_in,
                              void* d_out, int out_size, void* d_ws, size_t ws_size,
                              hipStream_t stream) {
    const float* x  = (const float*)d_in[0];
    const float* Wq = (const float*)d_in[1];
    const float* bq = (const float*)d_in[2];
    const float* Wk = (const float*)d_in[3];
    const float* bk = (const float*)d_in[4];
    const float* Wv = (const float*)d_in[5];
    const float* bv = (const float*)d_in[6];
    const float* Wp = (const float*)d_in[7];
    const float* bp = (const float*)d_in[8];

    char* ws = (char*)d_ws;
    const size_t SZ = (size_t)MROWS * CDIM * sizeof(short);  // 8 MB
    const size_t WSZ = (size_t)CDIM * CDIM * sizeof(short);  // 2 MB
    short* qws  = (short*)(ws);
    short* kws  = (short*)(ws + SZ);
    short* vtws = (short*)(ws + 2 * SZ);
    short* xb   = (short*)(ws + 3 * SZ);
    short* attn = xb;  // alias: xb dead after QKV GEMM

    if (ws_size >= 4 * SZ + 4 * WSZ) {
        // big-ws: convert everything up front; bf16 weights stashed past slot 3
        short* wqb = (short*)(ws + 4 * SZ);
        short* wkb = wqb + (size_t)CDIM * CDIM;
        short* wvb = wkb + (size_t)CDIM * CDIM;
        short* wpb = wvb + (size_t)CDIM * CDIM;
        conv5_kernel<<<4096, 256, 0, stream>>>(x, Wq, Wk, Wv, Wp,
                                               xb, wqb, wkb, wvb, wpb);
        gemm_qkv_g<<<dim3(MROWS / 128, 24), 256, 0, stream>>>(
            xb, wqb, wkb, wvb, bq, bk, bv, qws, kws, vtws);
        attn_kernel<<<dim3(BSZ * NHEADS, TSEQ / 64), 256, 0, stream>>>(qws, kws, vtws, attn);
        gemm_p<<<dim3(MROWS / 64, CDIM / 128), 256, 0, stream>>>(attn, wpb, bp, (float*)d_out);
    } else {
        short* wpb = qws;  // alias: qws dead after attn
        convx_kernel<<<2048, 256, 0, stream>>>(x, xb);
        gemm_qkv<<<dim3(MROWS / 128, 24), 256, 0, stream>>>(
            xb, Wq, Wk, Wv, bq, bk, bv, qws, kws, vtws);
        attn_kernel<<<dim3(BSZ * NHEADS, TSEQ / 64), 256, 0, stream>>>(qws, kws, vtws, attn);
        convx_kernel<<<512, 256, 0, stream>>>(Wp, wpb);
        gemm_p<<<dim3(MROWS / 64, CDIM / 128), 256, 0, stream>>>(attn, wpb, bp, (float*)d_out);
    }
}

// Round 22
// 98.928 us; speedup vs baseline: 1.2814x; 1.0345x over previous
//
#include <hip/hip_runtime.h>
#include <hip/hip_bf16.h>
#include <math.h>

#define TSEQ 2048
#define CDIM 1024
#define NHEADS 16
#define DHEAD 64
#define BSZ 2
#define MROWS (BSZ * TSEQ)  // 4096
#define SCALE_Q 0.18033688f  // 0.125 * log2(e): softmax becomes exp2(s)

typedef __attribute__((ext_vector_type(8))) short short8;
typedef __attribute__((ext_vector_type(4))) short short4v;
typedef __attribute__((ext_vector_type(4))) float f32x4;

__device__ inline f32x4 mfma16(short8 a, short8 b, f32x4 c) {
    return __builtin_amdgcn_mfma_f32_16x16x32_bf16(a, b, c, 0, 0, 0);
}

__device__ inline short f2bf(float f) {
    __hip_bfloat16 h = __float2bfloat16(f);
    return __builtin_bit_cast(short, h);
}

__device__ inline void gl_lds16(const short* g, short* l) {
    __builtin_amdgcn_global_load_lds(
        (const __attribute__((address_space(1))) void*)g,
        (__attribute__((address_space(3))) void*)l, 16, 0, 0);
}

// ---------------------------------------------------------------------------
// conv f32 -> bf16, 8 elems/thread (x only; fallback path).
// ---------------------------------------------------------------------------
__global__ __launch_bounds__(256) void convx_kernel(const float* __restrict__ x,
                                                    short* __restrict__ xb) {
    size_t off = (size_t)(blockIdx.x * 256 + threadIdx.x) * 8;
    float4 a = *(const float4*)(x + off);
    float4 b = *(const float4*)(x + off + 4);
    short8 h;
    h[0] = f2bf(a.x); h[1] = f2bf(a.y); h[2] = f2bf(a.z); h[3] = f2bf(a.w);
    h[4] = f2bf(b.x); h[5] = f2bf(b.y); h[6] = f2bf(b.z); h[7] = f2bf(b.w);
    *(short8*)(xb + off) = h;
}

// conv x (4M) + Wq/Wk/Wv/Wp (1M each) -> bf16 in ONE launch (big-ws path).
__global__ __launch_bounds__(256) void conv5_kernel(
    const float* __restrict__ x, const float* __restrict__ swq,
    const float* __restrict__ swk, const float* __restrict__ swv,
    const float* __restrict__ swp, short* __restrict__ xb,
    short* __restrict__ wqb, short* __restrict__ wkb,
    short* __restrict__ wvb, short* __restrict__ wpb) {
    int chunk = blockIdx.x >> 9;               // 0..7 (512 blocks per 1M elems)
    size_t off = (size_t)((blockIdx.x & 511) * 256 + threadIdx.x) * 8;
    const float* s;
    short* d;
    if (chunk < 4)      { s = x + (size_t)chunk * 1048576; d = xb + (size_t)chunk * 1048576; }
    else if (chunk == 4){ s = swq; d = wqb; }
    else if (chunk == 5){ s = swk; d = wkb; }
    else if (chunk == 6){ s = swv; d = wvb; }
    else                { s = swp; d = wpb; }
    float4 a = *(const float4*)(s + off);
    float4 b = *(const float4*)(s + off + 4);
    short8 h;
    h[0] = f2bf(a.x); h[1] = f2bf(a.y); h[2] = f2bf(a.z); h[3] = f2bf(a.w);
    h[4] = f2bf(b.x); h[5] = f2bf(b.y); h[6] = f2bf(b.z); h[7] = f2bf(b.w);
    *(short8*)(d + off) = h;
}

// ---------------------------------------------------------------------------
// Fused QKV GEMM, gl_lds path (m97 structure, frozen from r19/r20).
// ---------------------------------------------------------------------------
__global__ __launch_bounds__(256, 3) void gemm_qkv_g(
    const short* __restrict__ xb, const short* __restrict__ wqb,
    const short* __restrict__ wkb, const short* __restrict__ wvb,
    const float* __restrict__ bq, const float* __restrict__ bk,
    const float* __restrict__ bv, short* __restrict__ qws,
    short* __restrict__ kws, short* __restrict__ vtws) {
    __shared__ __attribute__((aligned(16))) short a_lds[128 * 64];
    __shared__ __attribute__((aligned(16))) short b_lds[128 * 64];

    const int tid = threadIdx.x;
    const int lane = tid & 63;
    const int wv = tid >> 6;
    const int wr = wv >> 1, wc = wv & 1;
    const int l15 = lane & 15, l4 = lane >> 4;
    const int mbase = blockIdx.x * 128;
    const int which = blockIdx.y >> 3;
    const int nbase = (blockIdx.y & 7) * 128;
    const short* Wb = which == 0 ? wqb : (which == 1 ? wkb : wvb);
    const float* bias = which == 0 ? bq : (which == 1 ? bk : bv);

    f32x4 acc[4][4];
#pragma unroll
    for (int i = 0; i < 4; ++i)
#pragma unroll
        for (int j = 0; j < 4; ++j) acc[i][j] = f32x4{0.f, 0.f, 0.f, 0.f};

    const int srow = tid >> 3;
    const int gcol = (tid & 7) ^ (srow & 7);
    const short* asrc = xb + (size_t)(mbase + srow) * CDIM + gcol * 8;
    const short* bsrc = Wb + (size_t)(nbase + srow) * CDIM + gcol * 8;
    short* adst = &a_lds[tid * 8];
    short* bdst = &b_lds[tid * 8];

    for (int k0 = 0; k0 < CDIM; k0 += 64) {
        __syncthreads();
#pragma unroll
        for (int it = 0; it < 4; ++it) {
            gl_lds16(asrc + (size_t)(it * 32) * CDIM + k0, adst + it * 2048);
            gl_lds16(bsrc + (size_t)(it * 32) * CDIM + k0, bdst + it * 2048);
        }
        __syncthreads();

#pragma unroll
        for (int kk = 0; kk < 2; ++kk) {
            short8 af[4], bfr[4];
#pragma unroll
            for (int i = 0; i < 4; ++i) {
                int R = wr * 64 + i * 16 + l15;
                af[i] = *(const short8*)&a_lds[R * 64 + ((kk * 4 + l4) ^ (R & 7)) * 8];
            }
#pragma unroll
            for (int j = 0; j < 4; ++j) {
                int R = wc * 64 + j * 16 + l15;
                bfr[j] = *(const short8*)&b_lds[R * 64 + ((kk * 4 + l4) ^ (R & 7)) * 8];
            }
#pragma unroll
            for (int i = 0; i < 4; ++i)
#pragma unroll
                for (int j = 0; j < 4; ++j)
                    acc[i][j] = mfma16(af[i], bfr[j], acc[i][j]);
        }
    }

    if (which < 2) {
        short* dst = which == 0 ? qws : kws;
        const float scale = which == 0 ? SCALE_Q : 1.0f;
#pragma unroll
        for (int i = 0; i < 4; ++i) {
            int mrow = mbase + wr * 64 + i * 16 + l4 * 4;
#pragma unroll
            for (int j = 0; j < 4; ++j) {
                int o = nbase + wc * 64 + j * 16 + l15;
                int n = o >> 6, d = o & 63;
                float bval = bias[o];
#pragma unroll
                for (int r = 0; r < 4; ++r) {
                    int mm = mrow + r;
                    int bb = mm >> 11;
                    int t = mm & (TSEQ - 1);
                    dst[(((size_t)bb * NHEADS + n) * TSEQ + t) * DHEAD + d] =
                        f2bf((acc[i][j][r] + bval) * scale);
                }
            }
        }
    } else {
#pragma unroll
        for (int i = 0; i < 4; ++i) {
            int mrow = mbase + wr * 64 + i * 16 + l4 * 4;
            int bb = mrow >> 11;
            int t = mrow & (TSEQ - 1);
#pragma unroll
            for (int j = 0; j < 4; ++j) {
                int o = nbase + wc * 64 + j * 16 + l15;
                int n = o >> 6, d = o & 63;
                float bval = bias[o];
                short4v h4;
#pragma unroll
                for (int r = 0; r < 4; ++r) h4[r] = f2bf(acc[i][j][r] + bval);
                *(short4v*)&vtws[(((size_t)bb * NHEADS + n) * DHEAD + d) * TSEQ + t] = h4;
            }
        }
    }
}

// ---------------------------------------------------------------------------
// Fused QKV GEMM, fallback path (r18-proven): f32 weights, reg staging.
// ---------------------------------------------------------------------------
__global__ __launch_bounds__(256, 3) void gemm_qkv(
    const short* __restrict__ xb, const float* __restrict__ Wq,
    const float* __restrict__ Wk, const float* __restrict__ Wv,
    const float* __restrict__ bq, const float* __restrict__ bk,
    const float* __restrict__ bv, short* __restrict__ qws,
    short* __restrict__ kws, short* __restrict__ vtws) {
    __shared__ __attribute__((aligned(16))) short a_lds[128][72];
    __shared__ __attribute__((aligned(16))) short b_lds[128][72];

    const int tid = threadIdx.x;
    const int lane = tid & 63;
    const int wv = tid >> 6;
    const int wr = wv >> 1, wc = wv & 1;
    const int l15 = lane & 15, l4 = lane >> 4;
    const int mbase = blockIdx.x * 128;
    const int which = blockIdx.y >> 3;
    const int nbase = (blockIdx.y & 7) * 128;
    const float* Wf = which == 0 ? Wq : (which == 1 ? Wk : Wv);
    const float* bias = which == 0 ? bq : (which == 1 ? bk : bv);

    f32x4 acc[4][4];
#pragma unroll
    for (int i = 0; i < 4; ++i)
#pragma unroll
        for (int j = 0; j < 4; ++j) acc[i][j] = f32x4{0.f, 0.f, 0.f, 0.f};

    const int ar = tid >> 3;
    const int ag = (tid & 7) * 8;
    const int br = tid >> 4;
    const int bg = (tid & 15) * 4;
    const short* aptr = xb + (size_t)(mbase + ar) * CDIM + ag;
    const float* bptr = Wf + (size_t)(nbase + br) * CDIM + bg;

    short8 apre[4];
    float4 bpre[8];
#pragma unroll
    for (int it = 0; it < 4; ++it)
        apre[it] = *(const short8*)(aptr + (size_t)(32 * it) * CDIM);
#pragma unroll
    for (int it = 0; it < 8; ++it)
        bpre[it] = *(const float4*)(bptr + (size_t)(16 * it) * CDIM);

    for (int k0 = 0; k0 < CDIM; k0 += 64) {
        __syncthreads();
#pragma unroll
        for (int it = 0; it < 4; ++it)
            *(short8*)&a_lds[ar + 32 * it][ag] = apre[it];
#pragma unroll
        for (int it = 0; it < 8; ++it) {
            short4v h;
            h.x = f2bf(bpre[it].x); h.y = f2bf(bpre[it].y);
            h.z = f2bf(bpre[it].z); h.w = f2bf(bpre[it].w);
            *(short4v*)&b_lds[br + 16 * it][bg] = h;
        }
        __syncthreads();
        if (k0 + 64 < CDIM) {
#pragma unroll
            for (int it = 0; it < 4; ++it)
                apre[it] = *(const short8*)(aptr + (size_t)(32 * it) * CDIM + k0 + 64);
#pragma unroll
            for (int it = 0; it < 8; ++it)
                bpre[it] = *(const float4*)(bptr + (size_t)(16 * it) * CDIM + k0 + 64);
        }

#pragma unroll
        for (int kk = 0; kk < 2; ++kk) {
            short8 af[4], bfr[4];
#pragma unroll
            for (int i = 0; i < 4; ++i)
                af[i] = *(const short8*)&a_lds[wr * 64 + i * 16 + l15][kk * 32 + l4 * 8];
#pragma unroll
            for (int j = 0; j < 4; ++j)
                bfr[j] = *(const short8*)&b_lds[wc * 64 + j * 16 + l15][kk * 32 + l4 * 8];
#pragma unroll
            for (int i = 0; i < 4; ++i)
#pragma unroll
                for (int j = 0; j < 4; ++j)
                    acc[i][j] = mfma16(af[i], bfr[j], acc[i][j]);
        }
    }

    if (which < 2) {
        short* dst = which == 0 ? qws : kws;
        const float scale = which == 0 ? SCALE_Q : 1.0f;
#pragma unroll
        for (int i = 0; i < 4; ++i) {
            int mrow = mbase + wr * 64 + i * 16 + l4 * 4;
#pragma unroll
            for (int j = 0; j < 4; ++j) {
                int o = nbase + wc * 64 + j * 16 + l15;
                int n = o >> 6, d = o & 63;
                float bval = bias[o];
#pragma unroll
                for (int r = 0; r < 4; ++r) {
                    int mm = mrow + r;
                    int bb = mm >> 11;
                    int t = mm & (TSEQ - 1);
                    dst[(((size_t)bb * NHEADS + n) * TSEQ + t) * DHEAD + d] =
                        f2bf((acc[i][j][r] + bval) * scale);
                }
            }
        }
    } else {
#pragma unroll
        for (int i = 0; i < 4; ++i) {
            int mrow = mbase + wr * 64 + i * 16 + l4 * 4;
            int bb = mrow >> 11;
            int t = mrow & (TSEQ - 1);
#pragma unroll
            for (int j = 0; j < 4; ++j) {
                int o = nbase + wc * 64 + j * 16 + l15;
                int n = o >> 6, d = o & 63;
                float bval = bias[o];
                short4v h4;
#pragma unroll
                for (int r = 0; r < 4; ++r) h4[r] = f2bf(acc[i][j][r] + bval);
                *(short4v*)&vtws[(((size_t)bb * NHEADS + n) * DHEAD + d) * TSEQ + t] = h4;
            }
        }
    }
}

// ---------------------------------------------------------------------------
// Output projection GEMM, gl_lds path (big-ws): BM=64, BN=128, BK=64,
// 4 waves (2x2, per-wave 32x64, acc[2][4]). Both operands bf16 via
// global_load_lds w/ pre-swizzled source; swizzled ds_read.
// ---------------------------------------------------------------------------
__global__ __launch_bounds__(256) void gemm_p_g(
    const short* __restrict__ attn, const short* __restrict__ wpb,
    const float* __restrict__ bp, float* __restrict__ out) {
    __shared__ __attribute__((aligned(16))) short a_lds[64 * 64];
    __shared__ __attribute__((aligned(16))) short b_lds[128 * 64];

    const int tid = threadIdx.x;
    const int lane = tid & 63;
    const int wv = tid >> 6;
    const int wr = wv >> 1, wc = wv & 1;
    const int l15 = lane & 15, l4 = lane >> 4;
    const int mbase = blockIdx.x * 64;
    const int nbase = blockIdx.y * 128;

    f32x4 acc[2][4];
#pragma unroll
    for (int i = 0; i < 2; ++i)
#pragma unroll
        for (int j = 0; j < 4; ++j) acc[i][j] = f32x4{0.f, 0.f, 0.f, 0.f};

    const int srow = tid >> 3;
    const int gcol = (tid & 7) ^ (srow & 7);
    const short* asrc = attn + (size_t)(mbase + srow) * CDIM + gcol * 8;
    const short* bsrc = wpb + (size_t)(nbase + srow) * CDIM + gcol * 8;
    short* adst = &a_lds[tid * 8];
    short* bdst = &b_lds[tid * 8];

    for (int k0 = 0; k0 < CDIM; k0 += 64) {
        __syncthreads();
#pragma unroll
        for (int it = 0; it < 2; ++it)
            gl_lds16(asrc + (size_t)(it * 32) * CDIM + k0, adst + it * 2048);
#pragma unroll
        for (int it = 0; it < 4; ++it)
            gl_lds16(bsrc + (size_t)(it * 32) * CDIM + k0, bdst + it * 2048);
        __syncthreads();

#pragma unroll
        for (int kk = 0; kk < 2; ++kk) {
            short8 af[2], bfr[4];
#pragma unroll
            for (int i = 0; i < 2; ++i) {
                int R = wr * 32 + i * 16 + l15;
                af[i] = *(const short8*)&a_lds[R * 64 + ((kk * 4 + l4) ^ (R & 7)) * 8];
            }
#pragma unroll
            for (int j = 0; j < 4; ++j) {
                int R = wc * 64 + j * 16 + l15;
                bfr[j] = *(const short8*)&b_lds[R * 64 + ((kk * 4 + l4) ^ (R & 7)) * 8];
            }
#pragma unroll
            for (int i = 0; i < 2; ++i)
#pragma unroll
                for (int j = 0; j < 4; ++j)
                    acc[i][j] = mfma16(af[i], bfr[j], acc[i][j]);
        }
    }

#pragma unroll
    for (int i = 0; i < 2; ++i) {
        int mrow = mbase + wr * 32 + i * 16 + l4 * 4;
#pragma unroll
        for (int j = 0; j < 4; ++j) {
            int o = nbase + wc * 64 + j * 16 + l15;
            float bval = bp[o];
#pragma unroll
            for (int r = 0; r < 4; ++r)
                out[(size_t)(mrow + r) * CDIM + o] = acc[i][j][r] + bval;
        }
    }
}

// ---------------------------------------------------------------------------
// Output projection GEMM, fallback (r18-proven): reg staging, bf16 wpb.
// ---------------------------------------------------------------------------
__global__ __launch_bounds__(256) void gemm_p(
    const short* __restrict__ attn, const short* __restrict__ wpb,
    const float* __restrict__ bp, float* __restrict__ out) {
    __shared__ __attribute__((aligned(16))) short a_lds[64][40];
    __shared__ __attribute__((aligned(16))) short b_lds[128][40];

    const int tid = threadIdx.x;
    const int lane = tid & 63;
    const int wv = tid >> 6;
    const int wr = wv >> 1, wc = wv & 1;
    const int l15 = lane & 15, l4 = lane >> 4;
    const int mbase = blockIdx.x * 64;
    const int nbase = blockIdx.y * 128;

    f32x4 acc[2][4];
#pragma unroll
    for (int i = 0; i < 2; ++i)
#pragma unroll
        for (int j = 0; j < 4; ++j) acc[i][j] = f32x4{0.f, 0.f, 0.f, 0.f};

    const int arow = tid >> 2;
    const int acol = (tid & 3) * 8;
    const short* aptr = attn + (size_t)(mbase + arow) * CDIM + acol;
    const short* bptr = wpb + (size_t)(nbase + arow) * CDIM + acol;

    short8 apre, bpre[2];
    apre = *(const short8*)(aptr);
    bpre[0] = *(const short8*)(bptr);
    bpre[1] = *(const short8*)(bptr + (size_t)64 * CDIM);

    for (int k0 = 0; k0 < CDIM; k0 += 32) {
        __syncthreads();
        *(short8*)&a_lds[arow][acol] = apre;
        *(short8*)&b_lds[arow][acol] = bpre[0];
        *(short8*)&b_lds[arow + 64][acol] = bpre[1];
        __syncthreads();
        if (k0 + 32 < CDIM) {
            apre = *(const short8*)(aptr + k0 + 32);
            bpre[0] = *(const short8*)(bptr + k0 + 32);
            bpre[1] = *(const short8*)(bptr + (size_t)64 * CDIM + k0 + 32);
        }

        short8 af[2], bfr[4];
#pragma unroll
        for (int i = 0; i < 2; ++i)
            af[i] = *(const short8*)&a_lds[wr * 32 + i * 16 + l15][l4 * 8];
#pragma unroll
        for (int j = 0; j < 4; ++j)
            bfr[j] = *(const short8*)&b_lds[wc * 64 + j * 16 + l15][l4 * 8];
#pragma unroll
        for (int i = 0; i < 2; ++i)
#pragma unroll
            for (int j = 0; j < 4; ++j)
                acc[i][j] = mfma16(af[i], bfr[j], acc[i][j]);
    }

#pragma unroll
    for (int i = 0; i < 2; ++i) {
        int mrow = mbase + wr * 32 + i * 16 + l4 * 4;
#pragma unroll
        for (int j = 0; j < 4; ++j) {
            int o = nbase + wc * 64 + j * 16 + l15;
            float bval = bp[o];
#pragma unroll
            for (int r = 0; r < 4; ++r)
                out[(size_t)(mrow + r) * CDIM + o] = acc[i][j][r] + bval;
        }
    }
}

// ---------------------------------------------------------------------------
// Flash attention v7 (frozen from r20): QBLK=64, KVBLK=128, no-max softmax
// via native exp2, l via ones-row MFMA, truncated bf16 P, K/V reg-prefetch
// into XOR-swizzled LDS. q,k [B*N,T,D]; vt [B*N,D,T].
// ---------------------------------------------------------------------------
__global__ __launch_bounds__(256) void attn_kernel(
    const short* __restrict__ q, const short* __restrict__ k,
    const short* __restrict__ vt, short* __restrict__ attn_out) {
    __shared__ __attribute__((aligned(16))) short k_lds[128][64];
    __shared__ __attribute__((aligned(16))) short vt_lds[64][128];
    __shared__ __attribute__((aligned(16))) short p_lds[4][16][136];

    const int tid = threadIdx.x;
    const int w = tid >> 6;
    const int lane = tid & 63;
    const int l15 = lane & 15;
    const int l4 = lane >> 4;
    const int h = blockIdx.x;
    const int qtile = gridDim.y - 1 - blockIdx.y;
    const int wrow0 = qtile * 64 + w * 16;

    short8 qf[2];
#pragma unroll
    for (int kh = 0; kh < 2; ++kh)
        qf[kh] = *(const short8*)(q + ((size_t)h * TSEQ + wrow0 + l15) * DHEAD +
                                  kh * 32 + l4 * 8);

    const short onebf = (short)0x3F80;  // bf16(1.0)
    short8 vf_ones;
#pragma unroll
    for (int e = 0; e < 8; ++e) vf_ones[e] = (l15 == 0) ? onebf : (short)0;

    f32x4 o_acc[4];
    f32x4 o5 = f32x4{0.f, 0.f, 0.f, 0.f};
#pragma unroll
    for (int dt = 0; dt < 4; ++dt) o_acc[dt] = f32x4{0.f, 0.f, 0.f, 0.f};

    const int ntiles = (qtile + 2) >> 1;
    const size_t kbase = (size_t)h * TSEQ * DHEAD;
    const size_t vbase = (size_t)h * DHEAD * TSEQ;

    const int ksrow = tid >> 3, ksg = tid & 7;
    const int vsrow = tid >> 4, vsg = tid & 15;

    short8 kpre[4], vpre[4];
#pragma unroll
    for (int it = 0; it < 4; ++it) {
        kpre[it] = *(const short8*)(k + kbase + (size_t)(ksrow + it * 32) * DHEAD + ksg * 8);
        vpre[it] = *(const short8*)(vt + vbase + (size_t)(vsrow + it * 16) * TSEQ + vsg * 8);
    }

    for (int kvt = 0; kvt < ntiles; ++kvt) {
        const int kvbase = kvt * 128;
        __syncthreads();
#pragma unroll
        for (int it = 0; it < 4; ++it) {
            int krow = ksrow + it * 32;
            *(short8*)&k_lds[krow][(ksg ^ (krow & 7)) * 8] = kpre[it];
            int vrow = vsrow + it * 16;
            *(short8*)&vt_lds[vrow][((vsg ^ (vrow & 15))) * 8] = vpre[it];
        }
        __syncthreads();
        if (kvt + 1 < ntiles) {
            int kvb2 = kvbase + 128;
#pragma unroll
            for (int it = 0; it < 4; ++it) {
                kpre[it] = *(const short8*)(k + kbase + (size_t)(kvb2 + ksrow + it * 32) * DHEAD + ksg * 8);
                vpre[it] = *(const short8*)(vt + vbase + (size_t)(vsrow + it * 16) * TSEQ + kvb2 + vsg * 8);
            }
        }

        f32x4 s[8];
#pragma unroll
        for (int jt = 0; jt < 8; ++jt) {
            int row = jt * 16 + l15;
            int sw = row & 7;
            short8 kf0 = *(const short8*)&k_lds[row][(l4 ^ sw) * 8];
            short8 kf1 = *(const short8*)&k_lds[row][((4 + l4) ^ sw) * 8];
            f32x4 a = f32x4{0.f, 0.f, 0.f, 0.f};
            a = mfma16(qf[0], kf0, a);
            a = mfma16(qf[1], kf1, a);
            s[jt] = a;
        }

        const bool needmask = (kvbase + 127 > wrow0);
#pragma unroll
        for (int r = 0; r < 4; ++r) {
            int qrow = wrow0 + l4 * 4 + r;
#pragma unroll
            for (int jt = 0; jt < 8; ++jt) {
                float x = s[jt][r];
                if (needmask && (kvbase + jt * 16 + l15 > qrow)) x = -INFINITY;
                unsigned int eb = __builtin_bit_cast(unsigned int,
                                                     __builtin_amdgcn_exp2f(x));
                p_lds[w][l4 * 4 + r][jt * 16 + l15] = (short)(eb >> 16);
            }
        }

        short8 pa[4];
#pragma unroll
        for (int ks = 0; ks < 4; ++ks)
            pa[ks] = *(const short8*)&p_lds[w][l15][ks * 32 + l4 * 8];
#pragma unroll
        for (int dt = 0; dt < 4; ++dt) {
            int row = dt * 16 + l15;
            int sw = row & 15;
#pragma unroll
            for (int ks = 0; ks < 4; ++ks) {
                short8 vf = *(const short8*)&vt_lds[row][((ks * 4 + l4) ^ sw) * 8];
                o_acc[dt] = mfma16(pa[ks], vf, o_acc[dt]);
            }
        }
#pragma unroll
        for (int ks = 0; ks < 4; ++ks)
            o5 = mfma16(pa[ks], vf_ones, o5);
    }

    float inv[4];
#pragma unroll
    for (int r = 0; r < 4; ++r)
        inv[r] = 1.0f / __shfl(o5[r], lane & 48);
    const int b = h >> 4, n = h & 15;
#pragma unroll
    for (int dt = 0; dt < 4; ++dt) {
#pragma unroll
        for (int r = 0; r < 4; ++r) {
            int t = wrow0 + l4 * 4 + r;
            attn_out[((size_t)b * TSEQ + t) * CDIM + n * DHEAD + dt * 16 + l15] =
                f2bf(o_acc[dt][r] * inv[r]);
        }
    }
}

extern "C" void kernel_launch(void* const* d_in, const int* in_sizes, int n_in,
                              void* d_out, int out_size, void* d_ws, size_t ws_size,
                              hipStream_t stream) {
    const float* x  = (const float*)d_in[0];
    const float* Wq = (const float*)d_in[1];
    const float* bq = (const float*)d_in[2];
    const float* Wk = (const float*)d_in[3];
    const float* bk = (const float*)d_in[4];
    const float* Wv = (const float*)d_in[5];
    const float* bv = (const float*)d_in[6];
    const float* Wp = (const float*)d_in[7];
    const float* bp = (const float*)d_in[8];

    char* ws = (char*)d_ws;
    const size_t SZ = (size_t)MROWS * CDIM * sizeof(short);  // 8 MB
    const size_t WSZ = (size_t)CDIM * CDIM * sizeof(short);  // 2 MB
    short* qws  = (short*)(ws);
    short* kws  = (short*)(ws + SZ);
    short* vtws = (short*)(ws + 2 * SZ);
    short* xb   = (short*)(ws + 3 * SZ);
    short* attn = xb;  // alias: xb dead after QKV GEMM

    if (ws_size >= 4 * SZ + 4 * WSZ) {
        short* wqb = (short*)(ws + 4 * SZ);
        short* wkb = wqb + (size_t)CDIM * CDIM;
        short* wvb = wkb + (size_t)CDIM * CDIM;
        short* wpb = wvb + (size_t)CDIM * CDIM;
        conv5_kernel<<<4096, 256, 0, stream>>>(x, Wq, Wk, Wv, Wp,
                                               xb, wqb, wkb, wvb, wpb);
        gemm_qkv_g<<<dim3(MROWS / 128, 24), 256, 0, stream>>>(
            xb, wqb, wkb, wvb, bq, bk, bv, qws, kws, vtws);
        attn_kernel<<<dim3(BSZ * NHEADS, TSEQ / 64), 256, 0, stream>>>(qws, kws, vtws, attn);
        gemm_p_g<<<dim3(MROWS / 64, CDIM / 128), 256, 0, stream>>>(attn, wpb, bp, (float*)d_out);
    } else {
        short* wpb = qws;  // alias: qws dead after attn
        convx_kernel<<<2048, 256, 0, stream>>>(x, xb);
        gemm_qkv<<<dim3(MROWS / 128, 24), 256, 0, stream>>>(
            xb, Wq, Wk, Wv, bq, bk, bv, qws, kws, vtws);
        attn_kernel<<<dim3(BSZ * NHEADS, TSEQ / 64), 256, 0, stream>>>(qws, kws, vtws, attn);
        convx_kernel<<<512, 256, 0, stream>>>(Wp, wpb);
        gemm_p<<<dim3(MROWS / 64, CDIM / 128), 256, 0, stream>>>(attn, wpb, bp, (float*)d_out);
    }
}

// Round 23
// 96.591 us; speedup vs baseline: 1.3124x; 1.0242x over previous
//
#include <hip/hip_runtime.h>
#include <hip/hip_bf16.h>
#include <math.h>

#define TSEQ 2048
#define CDIM 1024
#define NHEADS 16
#define DHEAD 64
#define BSZ 2
#define MROWS (BSZ * TSEQ)  // 4096
#define SCALE_Q 0.18033688f  // 0.125 * log2(e): softmax becomes exp2(s)

typedef __attribute__((ext_vector_type(8))) short short8;
typedef __attribute__((ext_vector_type(4))) short short4v;
typedef __attribute__((ext_vector_type(4))) float f32x4;

__device__ inline f32x4 mfma16(short8 a, short8 b, f32x4 c) {
    return __builtin_amdgcn_mfma_f32_16x16x32_bf16(a, b, c, 0, 0, 0);
}

__device__ inline short f2bf(float f) {
    __hip_bfloat16 h = __float2bfloat16(f);
    return __builtin_bit_cast(short, h);
}

__device__ inline void gl_lds16(const short* g, short* l) {
    __builtin_amdgcn_global_load_lds(
        (const __attribute__((address_space(1))) void*)g,
        (__attribute__((address_space(3))) void*)l, 16, 0, 0);
}

// ---------------------------------------------------------------------------
// conv f32 -> bf16, 8 elems/thread (x only; fallback path).
// ---------------------------------------------------------------------------
__global__ __launch_bounds__(256) void convx_kernel(const float* __restrict__ x,
                                                    short* __restrict__ xb) {
    size_t off = (size_t)(blockIdx.x * 256 + threadIdx.x) * 8;
    float4 a = *(const float4*)(x + off);
    float4 b = *(const float4*)(x + off + 4);
    short8 h;
    h[0] = f2bf(a.x); h[1] = f2bf(a.y); h[2] = f2bf(a.z); h[3] = f2bf(a.w);
    h[4] = f2bf(b.x); h[5] = f2bf(b.y); h[6] = f2bf(b.z); h[7] = f2bf(b.w);
    *(short8*)(xb + off) = h;
}

// conv x (4M) + Wq/Wk/Wv/Wp (1M each) -> bf16 in ONE launch (big-ws path).
__global__ __launch_bounds__(256) void conv5_kernel(
    const float* __restrict__ x, const float* __restrict__ swq,
    const float* __restrict__ swk, const float* __restrict__ swv,
    const float* __restrict__ swp, short* __restrict__ xb,
    short* __restrict__ wqb, short* __restrict__ wkb,
    short* __restrict__ wvb, short* __restrict__ wpb) {
    int chunk = blockIdx.x >> 9;               // 0..7 (512 blocks per 1M elems)
    size_t off = (size_t)((blockIdx.x & 511) * 256 + threadIdx.x) * 8;
    const float* s;
    short* d;
    if (chunk < 4)      { s = x + (size_t)chunk * 1048576; d = xb + (size_t)chunk * 1048576; }
    else if (chunk == 4){ s = swq; d = wqb; }
    else if (chunk == 5){ s = swk; d = wkb; }
    else if (chunk == 6){ s = swv; d = wvb; }
    else                { s = swp; d = wpb; }
    float4 a = *(const float4*)(s + off);
    float4 b = *(const float4*)(s + off + 4);
    short8 h;
    h[0] = f2bf(a.x); h[1] = f2bf(a.y); h[2] = f2bf(a.z); h[3] = f2bf(a.w);
    h[4] = f2bf(b.x); h[5] = f2bf(b.y); h[6] = f2bf(b.z); h[7] = f2bf(b.w);
    *(short8*)(d + off) = h;
}

// ---------------------------------------------------------------------------
// Fused QKV GEMM, gl_lds path (m97 structure, frozen).
// ---------------------------------------------------------------------------
__global__ __launch_bounds__(256, 3) void gemm_qkv_g(
    const short* __restrict__ xb, const short* __restrict__ wqb,
    const short* __restrict__ wkb, const short* __restrict__ wvb,
    const float* __restrict__ bq, const float* __restrict__ bk,
    const float* __restrict__ bv, short* __restrict__ qws,
    short* __restrict__ kws, short* __restrict__ vtws) {
    __shared__ __attribute__((aligned(16))) short a_lds[128 * 64];
    __shared__ __attribute__((aligned(16))) short b_lds[128 * 64];

    const int tid = threadIdx.x;
    const int lane = tid & 63;
    const int wv = tid >> 6;
    const int wr = wv >> 1, wc = wv & 1;
    const int l15 = lane & 15, l4 = lane >> 4;
    const int mbase = blockIdx.x * 128;
    const int which = blockIdx.y >> 3;
    const int nbase = (blockIdx.y & 7) * 128;
    const short* Wb = which == 0 ? wqb : (which == 1 ? wkb : wvb);
    const float* bias = which == 0 ? bq : (which == 1 ? bk : bv);

    f32x4 acc[4][4];
#pragma unroll
    for (int i = 0; i < 4; ++i)
#pragma unroll
        for (int j = 0; j < 4; ++j) acc[i][j] = f32x4{0.f, 0.f, 0.f, 0.f};

    const int srow = tid >> 3;
    const int gcol = (tid & 7) ^ (srow & 7);
    const short* asrc = xb + (size_t)(mbase + srow) * CDIM + gcol * 8;
    const short* bsrc = Wb + (size_t)(nbase + srow) * CDIM + gcol * 8;
    short* adst = &a_lds[tid * 8];
    short* bdst = &b_lds[tid * 8];

    for (int k0 = 0; k0 < CDIM; k0 += 64) {
        __syncthreads();
#pragma unroll
        for (int it = 0; it < 4; ++it) {
            gl_lds16(asrc + (size_t)(it * 32) * CDIM + k0, adst + it * 2048);
            gl_lds16(bsrc + (size_t)(it * 32) * CDIM + k0, bdst + it * 2048);
        }
        __syncthreads();

#pragma unroll
        for (int kk = 0; kk < 2; ++kk) {
            short8 af[4], bfr[4];
#pragma unroll
            for (int i = 0; i < 4; ++i) {
                int R = wr * 64 + i * 16 + l15;
                af[i] = *(const short8*)&a_lds[R * 64 + ((kk * 4 + l4) ^ (R & 7)) * 8];
            }
#pragma unroll
            for (int j = 0; j < 4; ++j) {
                int R = wc * 64 + j * 16 + l15;
                bfr[j] = *(const short8*)&b_lds[R * 64 + ((kk * 4 + l4) ^ (R & 7)) * 8];
            }
#pragma unroll
            for (int i = 0; i < 4; ++i)
#pragma unroll
                for (int j = 0; j < 4; ++j)
                    acc[i][j] = mfma16(af[i], bfr[j], acc[i][j]);
        }
    }

    if (which < 2) {
        short* dst = which == 0 ? qws : kws;
        const float scale = which == 0 ? SCALE_Q : 1.0f;
#pragma unroll
        for (int i = 0; i < 4; ++i) {
            int mrow = mbase + wr * 64 + i * 16 + l4 * 4;
#pragma unroll
            for (int j = 0; j < 4; ++j) {
                int o = nbase + wc * 64 + j * 16 + l15;
                int n = o >> 6, d = o & 63;
                float bval = bias[o];
#pragma unroll
                for (int r = 0; r < 4; ++r) {
                    int mm = mrow + r;
                    int bb = mm >> 11;
                    int t = mm & (TSEQ - 1);
                    dst[(((size_t)bb * NHEADS + n) * TSEQ + t) * DHEAD + d] =
                        f2bf((acc[i][j][r] + bval) * scale);
                }
            }
        }
    } else {
#pragma unroll
        for (int i = 0; i < 4; ++i) {
            int mrow = mbase + wr * 64 + i * 16 + l4 * 4;
            int bb = mrow >> 11;
            int t = mrow & (TSEQ - 1);
#pragma unroll
            for (int j = 0; j < 4; ++j) {
                int o = nbase + wc * 64 + j * 16 + l15;
                int n = o >> 6, d = o & 63;
                float bval = bias[o];
                short4v h4;
#pragma unroll
                for (int r = 0; r < 4; ++r) h4[r] = f2bf(acc[i][j][r] + bval);
                *(short4v*)&vtws[(((size_t)bb * NHEADS + n) * DHEAD + d) * TSEQ + t] = h4;
            }
        }
    }
}

// ---------------------------------------------------------------------------
// Fused QKV GEMM, fallback path (r18-proven): f32 weights, reg staging.
// ---------------------------------------------------------------------------
__global__ __launch_bounds__(256, 3) void gemm_qkv(
    const short* __restrict__ xb, const float* __restrict__ Wq,
    const float* __restrict__ Wk, const float* __restrict__ Wv,
    const float* __restrict__ bq, const float* __restrict__ bk,
    const float* __restrict__ bv, short* __restrict__ qws,
    short* __restrict__ kws, short* __restrict__ vtws) {
    __shared__ __attribute__((aligned(16))) short a_lds[128][72];
    __shared__ __attribute__((aligned(16))) short b_lds[128][72];

    const int tid = threadIdx.x;
    const int lane = tid & 63;
    const int wv = tid >> 6;
    const int wr = wv >> 1, wc = wv & 1;
    const int l15 = lane & 15, l4 = lane >> 4;
    const int mbase = blockIdx.x * 128;
    const int which = blockIdx.y >> 3;
    const int nbase = (blockIdx.y & 7) * 128;
    const float* Wf = which == 0 ? Wq : (which == 1 ? Wk : Wv);
    const float* bias = which == 0 ? bq : (which == 1 ? bk : bv);

    f32x4 acc[4][4];
#pragma unroll
    for (int i = 0; i < 4; ++i)
#pragma unroll
        for (int j = 0; j < 4; ++j) acc[i][j] = f32x4{0.f, 0.f, 0.f, 0.f};

    const int ar = tid >> 3;
    const int ag = (tid & 7) * 8;
    const int br = tid >> 4;
    const int bg = (tid & 15) * 4;
    const short* aptr = xb + (size_t)(mbase + ar) * CDIM + ag;
    const float* bptr = Wf + (size_t)(nbase + br) * CDIM + bg;

    short8 apre[4];
    float4 bpre[8];
#pragma unroll
    for (int it = 0; it < 4; ++it)
        apre[it] = *(const short8*)(aptr + (size_t)(32 * it) * CDIM);
#pragma unroll
    for (int it = 0; it < 8; ++it)
        bpre[it] = *(const float4*)(bptr + (size_t)(16 * it) * CDIM);

    for (int k0 = 0; k0 < CDIM; k0 += 64) {
        __syncthreads();
#pragma unroll
        for (int it = 0; it < 4; ++it)
            *(short8*)&a_lds[ar + 32 * it][ag] = apre[it];
#pragma unroll
        for (int it = 0; it < 8; ++it) {
            short4v h;
            h.x = f2bf(bpre[it].x); h.y = f2bf(bpre[it].y);
            h.z = f2bf(bpre[it].z); h.w = f2bf(bpre[it].w);
            *(short4v*)&b_lds[br + 16 * it][bg] = h;
        }
        __syncthreads();
        if (k0 + 64 < CDIM) {
#pragma unroll
            for (int it = 0; it < 4; ++it)
                apre[it] = *(const short8*)(aptr + (size_t)(32 * it) * CDIM + k0 + 64);
#pragma unroll
            for (int it = 0; it < 8; ++it)
                bpre[it] = *(const float4*)(bptr + (size_t)(16 * it) * CDIM + k0 + 64);
        }

#pragma unroll
        for (int kk = 0; kk < 2; ++kk) {
            short8 af[4], bfr[4];
#pragma unroll
            for (int i = 0; i < 4; ++i)
                af[i] = *(const short8*)&a_lds[wr * 64 + i * 16 + l15][kk * 32 + l4 * 8];
#pragma unroll
            for (int j = 0; j < 4; ++j)
                bfr[j] = *(const short8*)&b_lds[wc * 64 + j * 16 + l15][kk * 32 + l4 * 8];
#pragma unroll
            for (int i = 0; i < 4; ++i)
#pragma unroll
                for (int j = 0; j < 4; ++j)
                    acc[i][j] = mfma16(af[i], bfr[j], acc[i][j]);
        }
    }

    if (which < 2) {
        short* dst = which == 0 ? qws : kws;
        const float scale = which == 0 ? SCALE_Q : 1.0f;
#pragma unroll
        for (int i = 0; i < 4; ++i) {
            int mrow = mbase + wr * 64 + i * 16 + l4 * 4;
#pragma unroll
            for (int j = 0; j < 4; ++j) {
                int o = nbase + wc * 64 + j * 16 + l15;
                int n = o >> 6, d = o & 63;
                float bval = bias[o];
#pragma unroll
                for (int r = 0; r < 4; ++r) {
                    int mm = mrow + r;
                    int bb = mm >> 11;
                    int t = mm & (TSEQ - 1);
                    dst[(((size_t)bb * NHEADS + n) * TSEQ + t) * DHEAD + d] =
                        f2bf((acc[i][j][r] + bval) * scale);
                }
            }
        }
    } else {
#pragma unroll
        for (int i = 0; i < 4; ++i) {
            int mrow = mbase + wr * 64 + i * 16 + l4 * 4;
            int bb = mrow >> 11;
            int t = mrow & (TSEQ - 1);
#pragma unroll
            for (int j = 0; j < 4; ++j) {
                int o = nbase + wc * 64 + j * 16 + l15;
                int n = o >> 6, d = o & 63;
                float bval = bias[o];
                short4v h4;
#pragma unroll
                for (int r = 0; r < 4; ++r) h4[r] = f2bf(acc[i][j][r] + bval);
                *(short4v*)&vtws[(((size_t)bb * NHEADS + n) * DHEAD + d) * TSEQ + t] = h4;
            }
        }
    }
}

// ---------------------------------------------------------------------------
// Output projection GEMM, gl_lds path (frozen from r22).
// ---------------------------------------------------------------------------
__global__ __launch_bounds__(256) void gemm_p_g(
    const short* __restrict__ attn, const short* __restrict__ wpb,
    const float* __restrict__ bp, float* __restrict__ out) {
    __shared__ __attribute__((aligned(16))) short a_lds[64 * 64];
    __shared__ __attribute__((aligned(16))) short b_lds[128 * 64];

    const int tid = threadIdx.x;
    const int lane = tid & 63;
    const int wv = tid >> 6;
    const int wr = wv >> 1, wc = wv & 1;
    const int l15 = lane & 15, l4 = lane >> 4;
    const int mbase = blockIdx.x * 64;
    const int nbase = blockIdx.y * 128;

    f32x4 acc[2][4];
#pragma unroll
    for (int i = 0; i < 2; ++i)
#pragma unroll
        for (int j = 0; j < 4; ++j) acc[i][j] = f32x4{0.f, 0.f, 0.f, 0.f};

    const int srow = tid >> 3;
    const int gcol = (tid & 7) ^ (srow & 7);
    const short* asrc = attn + (size_t)(mbase + srow) * CDIM + gcol * 8;
    const short* bsrc = wpb + (size_t)(nbase + srow) * CDIM + gcol * 8;
    short* adst = &a_lds[tid * 8];
    short* bdst = &b_lds[tid * 8];

    for (int k0 = 0; k0 < CDIM; k0 += 64) {
        __syncthreads();
#pragma unroll
        for (int it = 0; it < 2; ++it)
            gl_lds16(asrc + (size_t)(it * 32) * CDIM + k0, adst + it * 2048);
#pragma unroll
        for (int it = 0; it < 4; ++it)
            gl_lds16(bsrc + (size_t)(it * 32) * CDIM + k0, bdst + it * 2048);
        __syncthreads();

#pragma unroll
        for (int kk = 0; kk < 2; ++kk) {
            short8 af[2], bfr[4];
#pragma unroll
            for (int i = 0; i < 2; ++i) {
                int R = wr * 32 + i * 16 + l15;
                af[i] = *(const short8*)&a_lds[R * 64 + ((kk * 4 + l4) ^ (R & 7)) * 8];
            }
#pragma unroll
            for (int j = 0; j < 4; ++j) {
                int R = wc * 64 + j * 16 + l15;
                bfr[j] = *(const short8*)&b_lds[R * 64 + ((kk * 4 + l4) ^ (R & 7)) * 8];
            }
#pragma unroll
            for (int i = 0; i < 2; ++i)
#pragma unroll
                for (int j = 0; j < 4; ++j)
                    acc[i][j] = mfma16(af[i], bfr[j], acc[i][j]);
        }
    }

#pragma unroll
    for (int i = 0; i < 2; ++i) {
        int mrow = mbase + wr * 32 + i * 16 + l4 * 4;
#pragma unroll
        for (int j = 0; j < 4; ++j) {
            int o = nbase + wc * 64 + j * 16 + l15;
            float bval = bp[o];
#pragma unroll
            for (int r = 0; r < 4; ++r)
                out[(size_t)(mrow + r) * CDIM + o] = acc[i][j][r] + bval;
        }
    }
}

// ---------------------------------------------------------------------------
// Output projection GEMM, fallback (r18-proven): reg staging, bf16 wpb.
// ---------------------------------------------------------------------------
__global__ __launch_bounds__(256) void gemm_p(
    const short* __restrict__ attn, const short* __restrict__ wpb,
    const float* __restrict__ bp, float* __restrict__ out) {
    __shared__ __attribute__((aligned(16))) short a_lds[64][40];
    __shared__ __attribute__((aligned(16))) short b_lds[128][40];

    const int tid = threadIdx.x;
    const int lane = tid & 63;
    const int wv = tid >> 6;
    const int wr = wv >> 1, wc = wv & 1;
    const int l15 = lane & 15, l4 = lane >> 4;
    const int mbase = blockIdx.x * 64;
    const int nbase = blockIdx.y * 128;

    f32x4 acc[2][4];
#pragma unroll
    for (int i = 0; i < 2; ++i)
#pragma unroll
        for (int j = 0; j < 4; ++j) acc[i][j] = f32x4{0.f, 0.f, 0.f, 0.f};

    const int arow = tid >> 2;
    const int acol = (tid & 3) * 8;
    const short* aptr = attn + (size_t)(mbase + arow) * CDIM + acol;
    const short* bptr = wpb + (size_t)(nbase + arow) * CDIM + acol;

    short8 apre, bpre[2];
    apre = *(const short8*)(aptr);
    bpre[0] = *(const short8*)(bptr);
    bpre[1] = *(const short8*)(bptr + (size_t)64 * CDIM);

    for (int k0 = 0; k0 < CDIM; k0 += 32) {
        __syncthreads();
        *(short8*)&a_lds[arow][acol] = apre;
        *(short8*)&b_lds[arow][acol] = bpre[0];
        *(short8*)&b_lds[arow + 64][acol] = bpre[1];
        __syncthreads();
        if (k0 + 32 < CDIM) {
            apre = *(const short8*)(aptr + k0 + 32);
            bpre[0] = *(const short8*)(bptr + k0 + 32);
            bpre[1] = *(const short8*)(bptr + (size_t)64 * CDIM + k0 + 32);
        }

        short8 af[2], bfr[4];
#pragma unroll
        for (int i = 0; i < 2; ++i)
            af[i] = *(const short8*)&a_lds[wr * 32 + i * 16 + l15][l4 * 8];
#pragma unroll
        for (int j = 0; j < 4; ++j)
            bfr[j] = *(const short8*)&b_lds[wc * 64 + j * 16 + l15][l4 * 8];
#pragma unroll
        for (int i = 0; i < 2; ++i)
#pragma unroll
            for (int j = 0; j < 4; ++j)
                acc[i][j] = mfma16(af[i], bfr[j], acc[i][j]);
    }

#pragma unroll
    for (int i = 0; i < 2; ++i) {
        int mrow = mbase + wr * 32 + i * 16 + l4 * 4;
#pragma unroll
        for (int j = 0; j < 4; ++j) {
            int o = nbase + wc * 64 + j * 16 + l15;
            float bval = bp[o];
#pragma unroll
            for (int r = 0; r < 4; ++r)
                out[(size_t)(mrow + r) * CDIM + o] = acc[i][j][r] + bval;
        }
    }
}

// ---------------------------------------------------------------------------
// Flash attention v8: v7 + T5 setprio around MFMA clusters + hoisted
// wave-uniform causal-mask branch (mask-free softmax on non-diagonal tiles).
// ---------------------------------------------------------------------------
__global__ __launch_bounds__(256) void attn_kernel(
    const short* __restrict__ q, const short* __restrict__ k,
    const short* __restrict__ vt, short* __restrict__ attn_out) {
    __shared__ __attribute__((aligned(16))) short k_lds[128][64];
    __shared__ __attribute__((aligned(16))) short vt_lds[64][128];
    __shared__ __attribute__((aligned(16))) short p_lds[4][16][136];

    const int tid = threadIdx.x;
    const int w = tid >> 6;
    const int lane = tid & 63;
    const int l15 = lane & 15;
    const int l4 = lane >> 4;
    const int h = blockIdx.x;
    const int qtile = gridDim.y - 1 - blockIdx.y;
    const int wrow0 = qtile * 64 + w * 16;

    short8 qf[2];
#pragma unroll
    for (int kh = 0; kh < 2; ++kh)
        qf[kh] = *(const short8*)(q + ((size_t)h * TSEQ + wrow0 + l15) * DHEAD +
                                  kh * 32 + l4 * 8);

    const short onebf = (short)0x3F80;  // bf16(1.0)
    short8 vf_ones;
#pragma unroll
    for (int e = 0; e < 8; ++e) vf_ones[e] = (l15 == 0) ? onebf : (short)0;

    f32x4 o_acc[4];
    f32x4 o5 = f32x4{0.f, 0.f, 0.f, 0.f};
#pragma unroll
    for (int dt = 0; dt < 4; ++dt) o_acc[dt] = f32x4{0.f, 0.f, 0.f, 0.f};

    const int ntiles = (qtile + 2) >> 1;
    const size_t kbase = (size_t)h * TSEQ * DHEAD;
    const size_t vbase = (size_t)h * DHEAD * TSEQ;

    const int ksrow = tid >> 3, ksg = tid & 7;
    const int vsrow = tid >> 4, vsg = tid & 15;

    short8 kpre[4], vpre[4];
#pragma unroll
    for (int it = 0; it < 4; ++it) {
        kpre[it] = *(const short8*)(k + kbase + (size_t)(ksrow + it * 32) * DHEAD + ksg * 8);
        vpre[it] = *(const short8*)(vt + vbase + (size_t)(vsrow + it * 16) * TSEQ + vsg * 8);
    }

    for (int kvt = 0; kvt < ntiles; ++kvt) {
        const int kvbase = kvt * 128;
        __syncthreads();
#pragma unroll
        for (int it = 0; it < 4; ++it) {
            int krow = ksrow + it * 32;
            *(short8*)&k_lds[krow][(ksg ^ (krow & 7)) * 8] = kpre[it];
            int vrow = vsrow + it * 16;
            *(short8*)&vt_lds[vrow][((vsg ^ (vrow & 15))) * 8] = vpre[it];
        }
        __syncthreads();
        if (kvt + 1 < ntiles) {
            int kvb2 = kvbase + 128;
#pragma unroll
            for (int it = 0; it < 4; ++it) {
                kpre[it] = *(const short8*)(k + kbase + (size_t)(kvb2 + ksrow + it * 32) * DHEAD + ksg * 8);
                vpre[it] = *(const short8*)(vt + vbase + (size_t)(vsrow + it * 16) * TSEQ + kvb2 + vsg * 8);
            }
        }

        f32x4 s[8];
        __builtin_amdgcn_s_setprio(1);
#pragma unroll
        for (int jt = 0; jt < 8; ++jt) {
            int row = jt * 16 + l15;
            int sw = row & 7;
            short8 kf0 = *(const short8*)&k_lds[row][(l4 ^ sw) * 8];
            short8 kf1 = *(const short8*)&k_lds[row][((4 + l4) ^ sw) * 8];
            f32x4 a = f32x4{0.f, 0.f, 0.f, 0.f};
            a = mfma16(qf[0], kf0, a);
            a = mfma16(qf[1], kf1, a);
            s[jt] = a;
        }
        __builtin_amdgcn_s_setprio(0);

        // softmax: p = native exp2(s); truncated bf16 store.
        // Wave-uniform mask branch: only the diagonal tile pays mask cost.
        if (kvbase + 127 > wrow0) {
#pragma unroll
            for (int r = 0; r < 4; ++r) {
                int qrow = wrow0 + l4 * 4 + r;
#pragma unroll
                for (int jt = 0; jt < 8; ++jt) {
                    float x = s[jt][r];
                    if (kvbase + jt * 16 + l15 > qrow) x = -INFINITY;
                    unsigned int eb = __builtin_bit_cast(unsigned int,
                                                         __builtin_amdgcn_exp2f(x));
                    p_lds[w][l4 * 4 + r][jt * 16 + l15] = (short)(eb >> 16);
                }
            }
        } else {
#pragma unroll
            for (int r = 0; r < 4; ++r) {
#pragma unroll
                for (int jt = 0; jt < 8; ++jt) {
                    unsigned int eb = __builtin_bit_cast(unsigned int,
                                                         __builtin_amdgcn_exp2f(s[jt][r]));
                    p_lds[w][l4 * 4 + r][jt * 16 + l15] = (short)(eb >> 16);
                }
            }
        }

        short8 pa[4];
#pragma unroll
        for (int ks = 0; ks < 4; ++ks)
            pa[ks] = *(const short8*)&p_lds[w][l15][ks * 32 + l4 * 8];
        __builtin_amdgcn_s_setprio(1);
#pragma unroll
        for (int dt = 0; dt < 4; ++dt) {
            int row = dt * 16 + l15;
            int sw = row & 15;
#pragma unroll
            for (int ks = 0; ks < 4; ++ks) {
                short8 vf = *(const short8*)&vt_lds[row][((ks * 4 + l4) ^ sw) * 8];
                o_acc[dt] = mfma16(pa[ks], vf, o_acc[dt]);
            }
        }
#pragma unroll
        for (int ks = 0; ks < 4; ++ks)
            o5 = mfma16(pa[ks], vf_ones, o5);
        __builtin_amdgcn_s_setprio(0);
    }

    float inv[4];
#pragma unroll
    for (int r = 0; r < 4; ++r)
        inv[r] = 1.0f / __shfl(o5[r], lane & 48);
    const int b = h >> 4, n = h & 15;
#pragma unroll
    for (int dt = 0; dt < 4; ++dt) {
#pragma unroll
        for (int r = 0; r < 4; ++r) {
            int t = wrow0 + l4 * 4 + r;
            attn_out[((size_t)b * TSEQ + t) * CDIM + n * DHEAD + dt * 16 + l15] =
                f2bf(o_acc[dt][r] * inv[r]);
        }
    }
}

extern "C" void kernel_launch(void* const* d_in, const int* in_sizes, int n_in,
                              void* d_out, int out_size, void* d_ws, size_t ws_size,
                              hipStream_t stream) {
    const float* x  = (const float*)d_in[0];
    const float* Wq = (const float*)d_in[1];
    const float* bq = (const float*)d_in[2];
    const float* Wk = (const float*)d_in[3];
    const float* bk = (const float*)d_in[4];
    const float* Wv = (const float*)d_in[5];
    const float* bv = (const float*)d_in[6];
    const float* Wp = (const float*)d_in[7];
    const float* bp = (const float*)d_in[8];

    char* ws = (char*)d_ws;
    const size_t SZ = (size_t)MROWS * CDIM * sizeof(short);  // 8 MB
    const size_t WSZ = (size_t)CDIM * CDIM * sizeof(short);  // 2 MB
    short* qws  = (short*)(ws);
    short* kws  = (short*)(ws + SZ);
    short* vtws = (short*)(ws + 2 * SZ);
    short* xb   = (short*)(ws + 3 * SZ);
    short* attn = xb;  // alias: xb dead after QKV GEMM

    if (ws_size >= 4 * SZ + 4 * WSZ) {
        short* wqb = (short*)(ws + 4 * SZ);
        short* wkb = wqb + (size_t)CDIM * CDIM;
        short* wvb = wkb + (size_t)CDIM * CDIM;
        short* wpb = wvb + (size_t)CDIM * CDIM;
        conv5_kernel<<<4096, 256, 0, stream>>>(x, Wq, Wk, Wv, Wp,
                                               xb, wqb, wkb, wvb, wpb);
        gemm_qkv_g<<<dim3(MROWS / 128, 24), 256, 0, stream>>>(
            xb, wqb, wkb, wvb, bq, bk, bv, qws, kws, vtws);
        attn_kernel<<<dim3(BSZ * NHEADS, TSEQ / 64), 256, 0, stream>>>(qws, kws, vtws, attn);
        gemm_p_g<<<dim3(MROWS / 64, CDIM / 128), 256, 0, stream>>>(attn, wpb, bp, (float*)d_out);
    } else {
        short* wpb = qws;  // alias: qws dead after attn
        convx_kernel<<<2048, 256, 0, stream>>>(x, xb);
        gemm_qkv<<<dim3(MROWS / 128, 24), 256, 0, stream>>>(
            xb, Wq, Wk, Wv, bq, bk, bv, qws, kws, vtws);
        attn_kernel<<<dim3(BSZ * NHEADS, TSEQ / 64), 256, 0, stream>>>(qws, kws, vtws, attn);
        convx_kernel<<<512, 256, 0, stream>>>(Wp, wpb);
        gemm_p<<<dim3(MROWS / 64, CDIM / 128), 256, 0, stream>>>(attn, wpb, bp, (float*)d_out);
    }
}